// Round 4
// baseline (1666.701 us; speedup 1.0000x reference)
//
#include <hip/hip_runtime.h>

// Nystrom attention, MI355X round 10: pinv chain fused into ONE kernel.
//  - 25 bgemm launches (~450 us incl. launch gaps) -> 1 launch, 32 blocks
//    (one per bh), 512 threads. Right operand transposed in LDS (256x264 bf16,
//    135 KB); left operands in per-bh L2-resident scratch. Iteration uses the
//    polynomial form s3 = 13I - 15 xz + 7 xz^2 - xz^3 (3 GEMMs + elementwise
//    epilogue + z' = 0.25 z@s3), final WMT = (z @ W3V)^T fused at the end.
//  - outheads stays round-6 structure (83 us, verified round 9).
// b=4, n=8192, dim=512, h=8, dh=64, m=256 landmarks, pinv iters=6, conv k=33.

#define N_SEQ 8192
#define DMODEL 512
#define NHEAD 8
#define DHEAD 64
#define NLAND 256
#define BH 32

typedef unsigned short u16;
typedef __attribute__((ext_vector_type(8))) short bh8;
typedef __attribute__((ext_vector_type(4))) float fx4;

__device__ __forceinline__ float bf2f(u16 u) { return __uint_as_float(((unsigned)u) << 16); }
__device__ __forceinline__ u16 f2bf(float f) {
    unsigned x = __float_as_uint(f);
    return (u16)((x + 0x7fffu + ((x >> 16) & 1u)) >> 16);
}
__device__ __forceinline__ fx4 mfma16(bh8 a, bh8 b, fx4 c) {
    return __builtin_amdgcn_mfma_f32_16x16x32_bf16(a, b, c, 0, 0, 0);
}
__device__ __forceinline__ void gload16(u16* lds, const u16* g) {
    __builtin_amdgcn_global_load_lds(
        (const __attribute__((address_space(1))) unsigned int*)g,
        (__attribute__((address_space(3))) unsigned int*)lds, 16, 0, 0);
}

// ---------------- dtype probe -----------------------------------------------------
__global__ void detect_kernel(const u16* __restrict__ X, unsigned* flag_out)
{
    __shared__ int cnt;
    if (threadIdx.x == 0) cnt = 0;
    __syncthreads();
    u16 u = X[threadIdx.x * 2];
    int e = (u >> 7) & 0xFF;
    int insane = (u != 0) && (e < 90 || e > 140);
    atomicAdd(&cnt, insane);
    __syncthreads();
    if (threadIdx.x == 0) flag_out[0] = (cnt > 64) ? 1u : 0u;
}

// vectorized convert: n4 = elements/4 (all our sizes are /4)
__global__ __launch_bounds__(256) void convert4_kernel(
    const void* __restrict__ in, u16* __restrict__ out, int n4, const unsigned* __restrict__ flag)
{
    int i = blockIdx.x * 256 + threadIdx.x;
    if (i >= n4) return;
    if (flag[0]) {
        float4 v = ((const float4*)in)[i];
        ushort4 o;
        o.x = f2bf(v.x); o.y = f2bf(v.y); o.z = f2bf(v.z); o.w = f2bf(v.w);
        ((ushort4*)out)[i] = o;
    } else {
        ((ushort4*)out)[i] = ((const ushort4*)in)[i];
    }
}

__global__ __launch_bounds__(256) void wtrans_kernel(
    const void* __restrict__ in, u16* __restrict__ out, int rows, int cols,
    const unsigned* __restrict__ flag)
{
    int idx = blockIdx.x * 256 + threadIdx.x;
    if (idx >= rows * cols) return;
    int r = idx / cols, c = idx % cols;
    float v = flag[0] ? ((const float*)in)[idx] : bf2f(((const u16*)in)[idx]);
    out[(size_t)c * rows + r] = f2bf(v);
}

// ---------------- QKV MFMA GEMM (async staging + xor swizzle) ---------------------
__global__ __launch_bounds__(256) void qkv_mfma_kernel(
    const u16* __restrict__ X, const u16* __restrict__ WT,
    u16* __restrict__ Q, u16* __restrict__ K, u16* __restrict__ VT)
{
    __shared__ u16 Xs[128 * 64];
    __shared__ u16 Ws[128 * 64];
    const int tid = threadIdx.x;
    const int wave = tid >> 6, lane = tid & 63;
    const int wrow = (wave >> 1) * 64, wcol = (wave & 1) * 64;
    const int i0 = blockIdx.x * 128;
    const int j0 = blockIdx.y * 128;
    const int la = lane >> 3, lb = lane & 7;
    const int lm = lane & 15, lq = lane >> 4;
    const int sw = lm & 7;
    const int sc = (lb ^ la) * 8;
    fx4 acc[4][4];
#pragma unroll
    for (int a = 0; a < 4; ++a)
#pragma unroll
        for (int b = 0; b < 4; ++b) acc[a][b] = (fx4){0.f, 0.f, 0.f, 0.f};

    for (int k0 = 0; k0 < DMODEL; k0 += 64) {
        __syncthreads();
#pragma unroll
        for (int jj = 0; jj < 4; ++jj) {
            int rb = wave * 32 + jj * 8;
            gload16(Xs + rb * 64, X + (size_t)(i0 + rb + la) * DMODEL + k0 + sc);
            gload16(Ws + rb * 64, WT + (size_t)(j0 + rb + la) * DMODEL + k0 + sc);
        }
        __syncthreads();
#pragma unroll
        for (int ks = 0; ks < 2; ++ks) {
            const int po = ((ks * 4 + lq) ^ sw) * 8;
            bh8 xf[4], wf[4];
#pragma unroll
            for (int im = 0; im < 4; ++im)
                xf[im] = *(const bh8*)(Xs + (wrow + im * 16 + lm) * 64 + po);
#pragma unroll
            for (int in = 0; in < 4; ++in)
                wf[in] = *(const bh8*)(Ws + (wcol + in * 16 + lm) * 64 + po);
#pragma unroll
            for (int im = 0; im < 4; ++im)
#pragma unroll
                for (int in = 0; in < 4; ++in)
                    acc[im][in] = mfma16(wf[in], xf[im], acc[im][in]);
        }
    }
#pragma unroll
    for (int im = 0; im < 4; ++im) {
        int m = i0 + wrow + im * 16 + lm;
        int bb = m >> 13, ns = m & (N_SEQ - 1);
#pragma unroll
        for (int in = 0; in < 4; ++in) {
            int nn = j0 + wcol + in * 16 + (lq << 2);
            int which = nn >> 9;
            int h = (nn >> 6) & 7;
            int d = nn & 63;
            if (which == 2) {
                size_t vb = (size_t)(bb * NHEAD + h) * DHEAD;
#pragma unroll
                for (int cc = 0; cc < 4; ++cc)
                    VT[(vb + d + cc) * N_SEQ + ns] = f2bf(acc[im][in][cc]);
            } else {
                u16* dst = (which == 0) ? Q : K;
                float s = (which == 0) ? 0.125f : 1.f;
                ushort4 o;
                o.x = f2bf(acc[im][in][0] * s); o.y = f2bf(acc[im][in][1] * s);
                o.z = f2bf(acc[im][in][2] * s); o.w = f2bf(acc[im][in][3] * s);
                *(ushort4*)(dst + ((size_t)(bb * NHEAD + h) * N_SEQ + ns) * DHEAD + d) = o;
            }
        }
    }
}

// ---------------- landmark pooling ------------------------------------------------
__global__ __launch_bounds__(64) void pool_kernel(
    const u16* __restrict__ Q, const u16* __restrict__ K,
    float* __restrict__ QL, float* __restrict__ KL,
    u16* __restrict__ QLb, u16* __restrict__ KLb)
{
    int m = blockIdx.x, bh = blockIdx.y, d = threadIdx.x;
    size_t base = ((size_t)bh * N_SEQ + m * 32) * DHEAD + d;
    float sq = 0.f, sk = 0.f;
#pragma unroll
    for (int i = 0; i < 32; ++i) {
        sq += bf2f(Q[base + i * DHEAD]);
        sk += bf2f(K[base + i * DHEAD]);
    }
    size_t ob = ((size_t)bh * NLAND + m) * DHEAD + d;
    sq *= (1.f / 32.f); sk *= (1.f / 32.f);
    QL[ob] = sq; KL[ob] = sk;
    QLb[ob] = f2bf(sq); KLb[ob] = f2bf(sk);
}

// ---------------- attn2 = softmax(q_l @ k_l^T) ------------------------------------
__global__ __launch_bounds__(256) void attn2_kernel(
    const float* __restrict__ QL, const float* __restrict__ KL, float* __restrict__ A2)
{
    __shared__ float qrow[64];
    __shared__ float red[256];
    int i = blockIdx.x, bh = blockIdx.y, j = threadIdx.x;
    if (j < 64) qrow[j] = QL[((size_t)bh * NLAND + i) * DHEAD + j];
    __syncthreads();
    const float* kr = KL + ((size_t)bh * NLAND + j) * DHEAD;
    float lg = 0.f;
#pragma unroll
    for (int d = 0; d < 64; ++d) lg += qrow[d] * kr[d];
    red[j] = lg; __syncthreads();
    for (int s = 128; s > 0; s >>= 1) { if (j < s) red[j] = fmaxf(red[j], red[j + s]); __syncthreads(); }
    float mx = red[0]; __syncthreads();
    float p = __expf(lg - mx);
    red[j] = p; __syncthreads();
    for (int s = 128; s > 0; s >>= 1) { if (j < s) red[j] += red[j + s]; __syncthreads(); }
    float sum = red[0];
    A2[((size_t)bh * NLAND + i) * NLAND + j] = p / sum;
}

__global__ void init_scal_kernel(unsigned* scal) { if (threadIdx.x < 2) scal[threadIdx.x] = 0u; }

__global__ __launch_bounds__(256) void absmax_kernel(const float* __restrict__ A2, unsigned* scal)
{
    __shared__ float red[256];
    int bh = blockIdx.x, t = threadIdx.x;
    const float* Ab = A2 + (size_t)bh * 65536;
    float cs = 0.f, rs = 0.f;
    for (int j = 0; j < 256; ++j) cs += fabsf(Ab[t * 256 + j]);
    for (int i = 0; i < 256; ++i) rs += fabsf(Ab[i * 256 + t]);
    red[t] = cs; __syncthreads();
    for (int s = 128; s > 0; s >>= 1) { if (t < s) red[t] = fmaxf(red[t], red[t + s]); __syncthreads(); }
    if (t == 0) atomicMax(scal + 0, __float_as_uint(red[0]));
    __syncthreads();
    red[t] = rs; __syncthreads();
    for (int s = 128; s > 0; s >>= 1) { if (t < s) red[t] = fmaxf(red[t], red[t + s]); __syncthreads(); }
    if (t == 0) atomicMax(scal + 1, __float_as_uint(red[0]));
}

// z0 + A2->bf16 in one pass
__global__ __launch_bounds__(256) void z0_kernel(
    const float* __restrict__ A2, const unsigned* __restrict__ scal,
    u16* __restrict__ zb, u16* __restrict__ zbT, u16* __restrict__ A2b)
{
    float inv = 1.f / (__uint_as_float(scal[0]) * __uint_as_float(scal[1]));
    size_t idx = (size_t)blockIdx.x * 256 + threadIdx.x;
    size_t bh = idx >> 16;
    int r = (int)(idx & 65535);
    int i = r >> 8, j = r & 255;
    float a = A2[idx];
    zb[idx]  = f2bf(A2[(bh << 16) + (size_t)j * 256 + i] * inv);
    zbT[idx] = f2bf(a * inv);
    A2b[idx] = f2bf(a);
}

// ---------------- fused pinv chain: 1 block per bh, whole Newton-Schulz -----------
// LDS TB = transposed right operand (stride 264 u16). Global per-bh scratch:
// XZrow, Yrow, Zrow (row-major, L2-resident). Per iteration:
//   m0: xz = x @ z      (a=A2b,  b=TB=zT)   -> XZrow + TB<-xzT
//   m1: y  = xz @ xz    (a=XZrow, b=TB=xzT) -> Yrow
//   m2: w  = y @ xz     (a=Yrow,  b=TB=xzT) -> TB <- s3T = 13I -15xzT +7yT -wT
//   m3: z' = 0.25 z@s3  (a=Zrow,  b=TB=s3T) -> Zrow + TB<-z'T
// Final: WMT[d][m] = (z @ W3V)^T, b-frags straight from W3VT global.
__global__ __launch_bounds__(512, 2) void pinv_chain_kernel(
    const u16* __restrict__ A2b, u16* __restrict__ Zrow,
    const u16* __restrict__ Z0T, u16* __restrict__ XZrow, u16* __restrict__ Yrow,
    const u16* __restrict__ W3VT, u16* __restrict__ WMT)
{
    __shared__ u16 TB[256 * 264];
    const int tid = threadIdx.x;
    const int wave = tid >> 6, lane = tid & 63;
    const int q = lane >> 4, l15 = lane & 15;
    const int bh = blockIdx.x;
    const int row0 = (wave >> 2) * 128;      // 2 row strips of 128
    const int col0 = (wave & 3) * 64;        // 4 col strips of 64
    const size_t mb = (size_t)bh * 65536;
    const u16* Xp = A2b + mb;
    u16* XZp = XZrow + mb;
    u16* Yp  = Yrow + mb;
    u16* Zp  = Zrow + mb;

    // init TB = z0T (straight row-major copy of zAT)
#pragma unroll
    for (int i = 0; i < 16; ++i) {
        int c = tid + 512 * i;               // 8192 chunks of 8 u16
        int r = c >> 5, cc = (c & 31) * 8;
        *(bh8*)(TB + r * 264 + cc) = *(const bh8*)(Z0T + mb + (size_t)r * 256 + cc);
    }
    __syncthreads();

#pragma unroll 1
    for (int it = 0; it < 6; ++it) {
#pragma unroll 1
        for (int step = 0; step < 4; ++step) {
            const u16* ap = (step == 0) ? Xp : (step == 1) ? XZp : (step == 2) ? Yp : Zp;
            fx4 acc[8][4];
#pragma unroll
            for (int im = 0; im < 8; ++im)
#pragma unroll
                for (int nt = 0; nt < 4; ++nt) acc[im][nt] = (fx4){0.f, 0.f, 0.f, 0.f};

#pragma unroll
            for (int kc = 0; kc < 4; ++kc) {
                const int k0 = kc * 64;
                bh8 bf[4][2];
#pragma unroll
                for (int nt = 0; nt < 4; ++nt) {
                    const u16* tb = TB + (col0 + nt * 16 + l15) * 264 + k0 + q * 8;
                    bf[nt][0] = *(const bh8*)(tb);
                    bf[nt][1] = *(const bh8*)(tb + 32);
                }
                const u16* ar = ap + (size_t)(row0 + l15) * 256 + k0 + q * 8;
                bh8 a0 = *(const bh8*)(ar);
                bh8 a1 = *(const bh8*)(ar + 32);
#pragma unroll
                for (int im = 0; im < 8; ++im) {
                    bh8 n0, n1;
                    if (im < 7) {
                        const u16* an = ap + (size_t)(row0 + (im + 1) * 16 + l15) * 256 + k0 + q * 8;
                        n0 = *(const bh8*)(an);
                        n1 = *(const bh8*)(an + 32);
                    }
#pragma unroll
                    for (int nt = 0; nt < 4; ++nt) {
                        acc[im][nt] = mfma16(a0, bf[nt][0], acc[im][nt]);
                        acc[im][nt] = mfma16(a1, bf[nt][1], acc[im][nt]);
                    }
                    a0 = n0; a1 = n1;
                }
            }
            __syncthreads();   // TB reads + a-reads complete before overwrite

            if (step == 0 || step == 1) {
                u16* outp = (step == 0) ? XZp : Yp;
#pragma unroll
                for (int im = 0; im < 8; ++im)
#pragma unroll
                    for (int nt = 0; nt < 4; ++nt) {
                        int col = col0 + nt * 16 + l15;
                        ushort4 t;
#pragma unroll
                        for (int r = 0; r < 4; ++r) {
                            int row = row0 + im * 16 + q * 4 + r;
                            u16 v = f2bf(acc[im][nt][r]);
                            outp[(size_t)row * 256 + col] = v;
                            ((u16*)&t)[r] = v;
                        }
                        if (step == 0)
                            *(ushort4*)(TB + (size_t)col * 264 + row0 + im * 16 + q * 4) = t;
                    }
            } else if (step == 2) {
#pragma unroll
                for (int im = 0; im < 8; ++im)
#pragma unroll
                    for (int nt = 0; nt < 4; ++nt) {
                        int col = col0 + nt * 16 + l15;
                        ushort4 t;
#pragma unroll
                        for (int r = 0; r < 4; ++r) {
                            int row = row0 + im * 16 + q * 4 + r;
                            float xzv = bf2f(XZp[(size_t)row * 256 + col]);
                            float yv  = bf2f(Yp[(size_t)row * 256 + col]);
                            float s = 7.f * yv - 15.f * xzv - acc[im][nt][r]
                                      + ((row == col) ? 13.f : 0.f);
                            ((u16*)&t)[r] = f2bf(s);
                        }
                        *(ushort4*)(TB + (size_t)col * 264 + row0 + im * 16 + q * 4) = t;
                    }
            } else {
#pragma unroll
                for (int im = 0; im < 8; ++im)
#pragma unroll
                    for (int nt = 0; nt < 4; ++nt) {
                        int col = col0 + nt * 16 + l15;
                        ushort4 t;
#pragma unroll
                        for (int r = 0; r < 4; ++r) {
                            int row = row0 + im * 16 + q * 4 + r;
                            u16 v = f2bf(0.25f * acc[im][nt][r]);
                            Zp[(size_t)row * 256 + col] = v;
                            ((u16*)&t)[r] = v;
                        }
                        *(ushort4*)(TB + (size_t)col * 264 + row0 + im * 16 + q * 4) = t;
                    }
            }
            __syncthreads();   // writes visible before next step
        }
    }

    // final: WMT[d][m] = (z @ W3V)^T. Wave handles rows wave*32..+31, cols 0..63.
    {
        const int frow0 = wave * 32;
        const u16* wp = W3VT + (size_t)bh * 16384;
        fx4 facc[2][4];
#pragma unroll
        for (int im = 0; im < 2; ++im)
#pragma unroll
            for (int nt = 0; nt < 4; ++nt) facc[im][nt] = (fx4){0.f, 0.f, 0.f, 0.f};
#pragma unroll
        for (int kc = 0; kc < 4; ++kc) {
            const int k0 = kc * 64;
            bh8 bf[4][2];
#pragma unroll
            for (int nt = 0; nt < 4; ++nt) {
                const u16* bp = wp + (size_t)(nt * 16 + l15) * 256 + k0 + q * 8;
                bf[nt][0] = *(const bh8*)(bp);
                bf[nt][1] = *(const bh8*)(bp + 32);
            }
#pragma unroll
            for (int im = 0; im < 2; ++im) {
                const u16* ar = Zp + (size_t)(frow0 + im * 16 + l15) * 256 + k0 + q * 8;
                bh8 a0 = *(const bh8*)(ar);
                bh8 a1 = *(const bh8*)(ar + 32);
#pragma unroll
                for (int nt = 0; nt < 4; ++nt) {
                    facc[im][nt] = mfma16(a0, bf[nt][0], facc[im][nt]);
                    facc[im][nt] = mfma16(a1, bf[nt][1], facc[im][nt]);
                }
            }
        }
#pragma unroll
        for (int im = 0; im < 2; ++im)
#pragma unroll
            for (int nt = 0; nt < 4; ++nt) {
                int d = nt * 16 + l15;
                ushort4 t;
#pragma unroll
                for (int r = 0; r < 4; ++r) ((u16*)&t)[r] = f2bf(facc[im][nt][r]);
                *(ushort4*)(WMT + (size_t)bh * 16384 + (size_t)d * 256 + frow0 + im * 16 + q * 4) = t;
            }
    }
}

// ---------------- attn3@v flash MFMA: fetch-once, 4 waves share K/VT chunks -------
// grid (16 nparts, 32 bh); wave w handles m = w*64..w*64+63 over its 512-n slice.
__global__ __launch_bounds__(256, 2) void attn3v_mfma_kernel(
    const u16* __restrict__ QLb, const u16* __restrict__ Kb,
    const u16* __restrict__ VTb, u16* __restrict__ PO, float* __restrict__ ML)
{
    __shared__ u16 Ks[64 * 72];
    __shared__ u16 Vs[64 * 72];
    __shared__ u16 Pw[4][64 * 72];
    const int tid = threadIdx.x;
    const int wave = tid >> 6, lane = tid & 63;
    const int q = lane >> 4, l15 = lane & 15;
    const int part = blockIdx.x;
    const int bh = blockIdx.y;
    const int nbase = part * 512;
    const int srow = tid >> 2, scol = (tid & 3) * 16;
    u16* Pp = Pw[wave];
    bh8 qf[4][2];
#pragma unroll
    for (int mt = 0; mt < 4; ++mt)
#pragma unroll
        for (int ks = 0; ks < 2; ++ks)
            qf[mt][ks] = *(const bh8*)(QLb + ((size_t)bh * NLAND + wave * 64 + mt * 16 + l15) * DHEAD + ks * 32 + q * 8);
    float M[4] = {-1e30f, -1e30f, -1e30f, -1e30f};
    float L[4] = {0.f, 0.f, 0.f, 0.f};
    fx4 O[4][4];
#pragma unroll
    for (int mt = 0; mt < 4; ++mt)
#pragma unroll
        for (int dt = 0; dt < 4; ++dt) O[mt][dt] = (fx4){0.f, 0.f, 0.f, 0.f};

    for (int c = 0; c < 8; ++c) {
        const int n0 = nbase + c * 64;
        uint4 k0v = *(const uint4*)(Kb + ((size_t)bh * N_SEQ + n0 + srow) * DHEAD + scol);
        uint4 k1v = *(const uint4*)(Kb + ((size_t)bh * N_SEQ + n0 + srow) * DHEAD + scol + 8);
        uint4 v0v = *(const uint4*)(VTb + ((size_t)bh * DHEAD + srow) * N_SEQ + n0 + scol);
        uint4 v1v = *(const uint4*)(VTb + ((size_t)bh * DHEAD + srow) * N_SEQ + n0 + scol + 8);
        __syncthreads();
        *(uint4*)(Ks + srow * 72 + scol) = k0v;
        *(uint4*)(Ks + srow * 72 + scol + 8) = k1v;
        *(uint4*)(Vs + srow * 72 + scol) = v0v;
        *(uint4*)(Vs + srow * 72 + scol + 8) = v1v;
        __syncthreads();
        fx4 S[4][4];   // [nt][mt]
#pragma unroll
        for (int nt = 0; nt < 4; ++nt)
#pragma unroll
            for (int mt = 0; mt < 4; ++mt) S[nt][mt] = (fx4){0.f, 0.f, 0.f, 0.f};
#pragma unroll
        for (int ks = 0; ks < 2; ++ks) {
            bh8 kf[4];
#pragma unroll
            for (int nt = 0; nt < 4; ++nt)
                kf[nt] = *(const bh8*)(Ks + (nt * 16 + l15) * 72 + ks * 32 + q * 8);
#pragma unroll
            for (int nt = 0; nt < 4; ++nt)
#pragma unroll
                for (int mt = 0; mt < 4; ++mt)
                    S[nt][mt] = mfma16(kf[nt], qf[mt][ks], S[nt][mt]);   // D[n][m]
        }
#pragma unroll
        for (int mt = 0; mt < 4; ++mt) {
            float cm = -1e30f;
#pragma unroll
            for (int nt = 0; nt < 4; ++nt)
#pragma unroll
                for (int r = 0; r < 4; ++r) cm = fmaxf(cm, S[nt][mt][r]);
            cm = fmaxf(cm, __shfl_xor(cm, 16));
            cm = fmaxf(cm, __shfl_xor(cm, 32));
            float Mn = fmaxf(M[mt], cm);
            float al = __expf(M[mt] - Mn);
            M[mt] = Mn;
            L[mt] *= al;
#pragma unroll
            for (int dt = 0; dt < 4; ++dt) {
                O[mt][dt][0] *= al; O[mt][dt][1] *= al;
                O[mt][dt][2] *= al; O[mt][dt][3] *= al;
            }
            float ps = 0.f;
#pragma unroll
            for (int nt = 0; nt < 4; ++nt)
#pragma unroll
                for (int r = 0; r < 4; ++r) {
                    float p = __expf(S[nt][mt][r] - Mn);
                    ps += p;
                    Pp[(mt * 16 + l15) * 72 + nt * 16 + q * 4 + r] = f2bf(p);
                }
            ps += __shfl_xor(ps, 16);
            ps += __shfl_xor(ps, 32);
            L[mt] += ps;
        }
#pragma unroll
        for (int ks = 0; ks < 2; ++ks) {
            bh8 pf[4];
#pragma unroll
            for (int mt = 0; mt < 4; ++mt)
                pf[mt] = *(const bh8*)(Pp + (mt * 16 + l15) * 72 + ks * 32 + q * 8);
#pragma unroll
            for (int dt = 0; dt < 4; ++dt) {
                bh8 vf = *(const bh8*)(Vs + (dt * 16 + l15) * 72 + ks * 32 + q * 8);
#pragma unroll
                for (int mt = 0; mt < 4; ++mt)
                    O[mt][dt] = mfma16(vf, pf[mt], O[mt][dt]);   // D[d][m]
            }
        }
    }
#pragma unroll
    for (int mt = 0; mt < 4; ++mt) {
        size_t mrow = (size_t)(bh * 16 + part) * NLAND + wave * 64 + mt * 16 + l15;
#pragma unroll
        for (int dt = 0; dt < 4; ++dt) {
            ushort4 o;
            o.x = f2bf(O[mt][dt][0]); o.y = f2bf(O[mt][dt][1]);
            o.z = f2bf(O[mt][dt][2]); o.w = f2bf(O[mt][dt][3]);
            *(ushort4*)(PO + mrow * DHEAD + dt * 16 + q * 4) = o;
        }
        if (q == 0) { ML[mrow * 2] = M[mt]; ML[mrow * 2 + 1] = L[mt]; }
    }
}

__global__ __launch_bounds__(64) void combine_kernel(
    const u16* __restrict__ PO, const float* __restrict__ ML, u16* __restrict__ W3VT)
{
    int m = blockIdx.x, bh = blockIdx.y, d = threadIdx.x;
    float Mg = -1e30f;
#pragma unroll
    for (int p = 0; p < 16; ++p)
        Mg = fmaxf(Mg, ML[((size_t)(bh * 16 + p) * NLAND + m) * 2]);
    float denom = 0.f, o = 0.f;
#pragma unroll
    for (int p = 0; p < 16; ++p) {
        size_t ix = (size_t)(bh * 16 + p) * NLAND + m;
        float w = __expf(ML[ix * 2] - Mg);
        denom += ML[ix * 2 + 1] * w;
        o += bf2f(PO[ix * DHEAD + d]) * w;
    }
    W3VT[((size_t)bh * DHEAD + d) * NLAND + m] = f2bf(o / denom);
}

// ---------------- depthwise conv residual: RT[bh*64+d][n] from VT -----------------
__global__ __launch_bounds__(256) void conv_kernel(
    const u16* __restrict__ VT, const u16* __restrict__ CW, u16* __restrict__ RT)
{
    __shared__ float vl[2080];
    __shared__ float cws[33];
    const int tid = threadIdx.x;
    const int c0 = blockIdx.x * 2048;
    const int row = blockIdx.y;
    const int h = (row >> 6) & 7;
    const u16* src = VT + (size_t)row * N_SEQ;
    for (int i = tid; i < 2080; i += 256) {
        int gn = c0 - 16 + i;
        vl[i] = (gn >= 0 && gn < N_SEQ) ? bf2f(src[gn]) : 0.f;
    }
    if (tid < 33) cws[tid] = bf2f(CW[h * 33 + tid]);
    __syncthreads();
    float v[40];
    const int base = tid * 8;
#pragma unroll
    for (int i = 0; i < 40; ++i) v[i] = vl[base + i];
    float s[8];
#pragma unroll
    for (int j = 0; j < 8; ++j) {
        float a = 0.f;
#pragma unroll
        for (int t = 0; t < 33; ++t) a += cws[t] * v[j + t];
        s[j] = a;
    }
    u16* dst = RT + (size_t)row * N_SEQ + c0 + base;
    ushort4 o0, o1;
    o0.x = f2bf(s[0]); o0.y = f2bf(s[1]); o0.z = f2bf(s[2]); o0.w = f2bf(s[3]);
    o1.x = f2bf(s[4]); o1.y = f2bf(s[5]); o1.z = f2bf(s[6]); o1.w = f2bf(s[7]);
    *(ushort4*)dst = o0;
    *(ushort4*)(dst + 4) = o1;
}

// ---------------- outheads: attn1 softmax + @WM + RT residual, 64 n/block ---------
__global__ __launch_bounds__(256) void outheads_mfma_kernel(
    const u16* __restrict__ Qb, const u16* __restrict__ KLb,
    const u16* __restrict__ WMT, const u16* __restrict__ RT,
    u16* __restrict__ Y)
{
    __shared__ u16 Pl[64 * 264];
    __shared__ float wmax[4][64];
    __shared__ float wsum[4][64];
    const int tid = threadIdx.x;
    const int wave = tid >> 6, lane = tid & 63;
    const int q = lane >> 4, l15 = lane & 15;
    const int bh = blockIdx.y;
    const int bb = bh >> 3, h = bh & 7;
    const int n0 = blockIdx.x * 64;
    fx4 S[4][4];
#pragma unroll
    for (int a = 0; a < 4; ++a)
#pragma unroll
        for (int b = 0; b < 4; ++b) S[a][b] = (fx4){0.f, 0.f, 0.f, 0.f};
#pragma unroll
    for (int ks = 0; ks < 2; ++ks) {
        bh8 qfr[4];
#pragma unroll
        for (int nt = 0; nt < 4; ++nt)
            qfr[nt] = *(const bh8*)(Qb + ((size_t)bh * N_SEQ + n0 + nt * 16 + l15) * DHEAD + ks * 32 + q * 8);
#pragma unroll
        for (int mt = 0; mt < 4; ++mt) {
            bh8 kf = *(const bh8*)(KLb + ((size_t)bh * NLAND + wave * 64 + mt * 16 + l15) * DHEAD + ks * 32 + q * 8);
#pragma unroll
            for (int nt = 0; nt < 4; ++nt)
                S[nt][mt] = mfma16(qfr[nt], kf, S[nt][mt]);
        }
    }
#pragma unroll
    for (int nt = 0; nt < 4; ++nt)
#pragma unroll
        for (int r = 0; r < 4; ++r) {
            float pm = fmaxf(fmaxf(S[nt][0][r], S[nt][1][r]), fmaxf(S[nt][2][r], S[nt][3][r]));
            pm = fmaxf(pm, __shfl_xor(pm, 1));
            pm = fmaxf(pm, __shfl_xor(pm, 2));
            pm = fmaxf(pm, __shfl_xor(pm, 4));
            pm = fmaxf(pm, __shfl_xor(pm, 8));
            if (l15 == 0) wmax[wave][nt * 16 + q * 4 + r] = pm;
        }
    __syncthreads();
#pragma unroll
    for (int nt = 0; nt < 4; ++nt)
#pragma unroll
        for (int r = 0; r < 4; ++r) {
            int nl = nt * 16 + q * 4 + r;
            float Mf = fmaxf(fmaxf(wmax[0][nl], wmax[1][nl]), fmaxf(wmax[2][nl], wmax[3][nl]));
            float ps = 0.f;
#pragma unroll
            for (int mt = 0; mt < 4; ++mt) {
                float p = __expf(S[nt][mt][r] - Mf);
                ps += p;
                Pl[nl * 264 + wave * 64 + mt * 16 + l15] = f2bf(p);
            }
            ps += __shfl_xor(ps, 1);
            ps += __shfl_xor(ps, 2);
            ps += __shfl_xor(ps, 4);
            ps += __shfl_xor(ps, 8);
            if (l15 == 0) wsum[wave][nl] = ps;
        }
    __syncthreads();
    fx4 O[4];
#pragma unroll
    for (int nt = 0; nt < 4; ++nt) O[nt] = (fx4){0.f, 0.f, 0.f, 0.f};
#pragma unroll
    for (int ks = 0; ks < 8; ++ks) {
        bh8 af = *(const bh8*)(WMT + ((size_t)bh * DHEAD + wave * 16 + l15) * NLAND + ks * 32 + q * 8);
#pragma unroll
        for (int nt = 0; nt < 4; ++nt) {
            bh8 pf = *(const bh8*)(Pl + (size_t)(nt * 16 + l15) * 264 + ks * 32 + q * 8);
            O[nt] = mfma16(af, pf, O[nt]);
        }
    }
#pragma unroll
    for (int nt = 0; nt < 4; ++nt) {
        int nl = nt * 16 + l15;
        float inv = 1.f / (wsum[0][nl] + wsum[1][nl] + wsum[2][nl] + wsum[3][nl]);
        int d0 = wave * 16 + (q << 2);
        fx4 v = O[nt];
#pragma unroll
        for (int c = 0; c < 4; ++c)
            v[c] = v[c] * inv + bf2f(RT[(size_t)(bh * DHEAD + d0 + c) * N_SEQ + n0 + nl]);
        ushort4 o;
        o.x = f2bf(v[0]); o.y = f2bf(v[1]); o.z = f2bf(v[2]); o.w = f2bf(v[3]);
        *(ushort4*)(Y + ((size_t)bb * N_SEQ + n0 + nl) * DMODEL + h * DHEAD + d0) = o;
    }
}

// ---------------- final MFMA GEMM (async staging + swizzle) -----------------------
__global__ __launch_bounds__(256) void final_mfma_kernel(
    const u16* __restrict__ Y, const u16* __restrict__ WT,
    const u16* __restrict__ Bias, const u16* __restrict__ X, void* __restrict__ Out,
    const unsigned* __restrict__ flag)
{
    __shared__ u16 Xs[128 * 64];
    __shared__ u16 Ws[128 * 64];
    const int tid = threadIdx.x;
    const int wave = tid >> 6, lane = tid & 63;
    const int wrow = (wave >> 1) * 64, wcol = (wave & 1) * 64;
    const int i0 = blockIdx.x * 128;
    const int j0 = blockIdx.y * 128;
    const int la = lane >> 3, lb = lane & 7;
    const int lm = lane & 15, lq = lane >> 4;
    const int sw = lm & 7;
    const int sc = (lb ^ la) * 8;
    const unsigned isf32 = flag[0];
    fx4 acc[4][4];
#pragma unroll
    for (int a = 0; a < 4; ++a)
#pragma unroll
        for (int b = 0; b < 4; ++b) acc[a][b] = (fx4){0.f, 0.f, 0.f, 0.f};

    for (int k0 = 0; k0 < DMODEL; k0 += 64) {
        __syncthreads();
#pragma unroll
        for (int jj = 0; jj < 4; ++jj) {
            int rb = wave * 32 + jj * 8;
            gload16(Xs + rb * 64, Y + (size_t)(i0 + rb + la) * DMODEL + k0 + sc);
            gload16(Ws + rb * 64, WT + (size_t)(j0 + rb + la) * DMODEL + k0 + sc);
        }
        __syncthreads();
#pragma unroll
        for (int ks = 0; ks < 2; ++ks) {
            const int po = ((ks * 4 + lq) ^ sw) * 8;
            bh8 xf[4], wf[4];
#pragma unroll
            for (int im = 0; im < 4; ++im)
                xf[im] = *(const bh8*)(Xs + (wrow + im * 16 + lm) * 64 + po);
#pragma unroll
            for (int in = 0; in < 4; ++in)
                wf[in] = *(const bh8*)(Ws + (wcol + in * 16 + lm) * 64 + po);
#pragma unroll
            for (int im = 0; im < 4; ++im)
#pragma unroll
                for (int in = 0; in < 4; ++in)
                    acc[im][in] = mfma16(wf[in], xf[im], acc[im][in]);
        }
    }
#pragma unroll
    for (int im = 0; im < 4; ++im) {
        int m = i0 + wrow + im * 16 + lm;
#pragma unroll
        for (int in = 0; in < 4; ++in) {
            int nn = j0 + wcol + in * 16 + (lq << 2);
            ushort4 b4 = *(const ushort4*)(Bias + nn);
            ushort4 x4 = *(const ushort4*)(X + (size_t)m * DMODEL + nn);
            float c0 = acc[im][in][0] + bf2f(b4.x) + bf2f(x4.x);
            float c1 = acc[im][in][1] + bf2f(b4.y) + bf2f(x4.y);
            float c2 = acc[im][in][2] + bf2f(b4.z) + bf2f(x4.z);
            float c3 = acc[im][in][3] + bf2f(b4.w) + bf2f(x4.w);
            if (isf32) {
                *(float4*)((float*)Out + (size_t)m * DMODEL + nn) = make_float4(c0, c1, c2, c3);
            } else {
                ushort4 o;
                o.x = f2bf(c0); o.y = f2bf(c1); o.z = f2bf(c2); o.w = f2bf(c3);
                *(ushort4*)((u16*)Out + (size_t)m * DMODEL + nn) = o;
            }
        }
    }
}

extern "C" void kernel_launch(void* const* d_in, const int* in_sizes, int n_in,
                              void* d_out, int out_size, void* d_ws, size_t ws_size,
                              hipStream_t stream)
{
    (void)in_sizes; (void)n_in; (void)out_size; (void)ws_size;
    char* ws = (char*)d_ws;
    u16*   Xc    = (u16*)(ws + 0);            // 33,554,432
    u16*   WqkvT = (u16*)(ws + 33554432);     //  1,572,864
    u16*   WoutT = (u16*)(ws + 35127296);     //    524,288
    u16*   Boutc = (u16*)(ws + 35651584);     //      1,024
    u16*   CWc   = (u16*)(ws + 35652608);     //      1,024
    u16*   Qb    = (u16*)(ws + 35653632);     // 33,554,432  [bh][n][d]
    u16*   Kb    = (u16*)(ws + 69208064);     // 33,554,432  [bh][n][d]; dead after attn3v
    u16*   RT    = (u16*)(ws + 69208064);     // overlays Kb post-attn3v
    u16*   VTb   = (u16*)(ws + 102762496);    // 33,554,432  [bh][d][n]
    float* QL    = (float*)(ws + 136316928);  //  2,097,152
    float* KL    = (float*)(ws + 138414080);  //  2,097,152
    u16*   QLb   = (u16*)(ws + 140511232);    //  1,048,576
    u16*   KLb   = (u16*)(ws + 141559808);    //  1,048,576
    u16*   W3VT  = (u16*)(ws + 142608384);    //  1,048,576
    u16*   WMT   = (u16*)(ws + 143656960);    //  1,048,576
    u16*   A2b   = (u16*)(ws + 144705536);    //  4,194,304
    u16*   zA    = (u16*)(ws + 148899840);    //  4,194,304  (Zrow scratch)
    u16*   zAT   = (u16*)(ws + 153094144);    //  4,194,304  (z0T, read-only init)
    float* A2    = (float*)(ws + 157288448);  // overlay region
    u16*   PO    = (u16*)(ws + 157288448);
    float* ML    = (float*)(ws + 174065664);
    u16*   XZrow = (u16*)(ws + 174065664);    // overlays ML (dead after combine)
    u16*   Yrow  = (u16*)(ws + 182454272);    // old t2T slot
    u16*   Yb    = (u16*)(ws + 157288448);
    unsigned* SCAL = (unsigned*)(ws + 190842880);

    detect_kernel<<<1, 256, 0, stream>>>((const u16*)d_in[0], SCAL + 2);
    convert4_kernel<<<16384, 256, 0, stream>>>(d_in[0], Xc, 4194304, SCAL + 2);
    wtrans_kernel<<<3072, 256, 0, stream>>>(d_in[1], WqkvT, 512, 1536, SCAL + 2);
    wtrans_kernel<<<1024, 256, 0, stream>>>(d_in[2], WoutT, 512, 512, SCAL + 2);
    convert4_kernel<<<1, 256, 0, stream>>>(d_in[3], Boutc, 128, SCAL + 2);
    convert4_kernel<<<1, 256, 0, stream>>>(d_in[4], CWc, 66, SCAL + 2);

    qkv_mfma_kernel<<<dim3(256, 12), 256, 0, stream>>>(Xc, WqkvT, Qb, Kb, VTb);
    pool_kernel<<<dim3(256, BH), 64, 0, stream>>>(Qb, Kb, QL, KL, QLb, KLb);
    attn2_kernel<<<dim3(256, BH), 256, 0, stream>>>(QL, KL, A2);
    init_scal_kernel<<<1, 64, 0, stream>>>(SCAL);
    absmax_kernel<<<32, 256, 0, stream>>>(A2, SCAL);
    z0_kernel<<<8192, 256, 0, stream>>>(A2, SCAL, zA, zAT, A2b);

    // flash attn3@v (fetch-once), combine, conv into Kb slot
    attn3v_mfma_kernel<<<dim3(16, BH), 256, 0, stream>>>(QLb, Kb, VTb, PO, ML);
    combine_kernel<<<dim3(256, BH), 64, 0, stream>>>(PO, ML, W3VT);
    conv_kernel<<<dim3(4, 2048), 256, 0, stream>>>(VTb, CWc, RT);

    // fused Newton-Schulz pinv chain + final WMT GEMM: ONE launch
    pinv_chain_kernel<<<32, 512, 0, stream>>>(A2b, zA, zAT, XZrow, Yrow, W3VT, WMT);

    outheads_mfma_kernel<<<dim3(128, BH), 256, 0, stream>>>(Qb, KLb, WMT, RT, Yb);
    final_mfma_kernel<<<dim3(256, 4), 256, 0, stream>>>(Yb, WoutT, Boutc, Xc, d_out, SCAL + 2);
}

// Round 5
// 1366.721 us; speedup vs baseline: 1.2195x; 1.2195x over previous
//
#include <hip/hip_runtime.h>

// Nystrom attention, MI355X round 11: pinv chain as ONE persistent kernel with
// manual grid barriers (round-10 fusion retried with the round-6 bgemm body).
//  - 256 blocks x 256 threads (>=4 blocks/CU capacity -> co-residency safe),
//    each block does 2 of the 512 64x64 tiles per GEMM step, LDS-staged exactly
//    like the proven round-6 bgemm; 24 device-scope barriers replace 24 launch
//    gaps; final WMT GEMM fused on blocks 0..127.
//  - everything else unchanged from round 9 (outheads = round-6 struct, 83 us).
// b=4, n=8192, dim=512, h=8, dh=64, m=256 landmarks, pinv iters=6, conv k=33.

#define N_SEQ 8192
#define DMODEL 512
#define NHEAD 8
#define DHEAD 64
#define NLAND 256
#define BH 32

typedef unsigned short u16;
typedef __attribute__((ext_vector_type(8))) short bh8;
typedef __attribute__((ext_vector_type(4))) float fx4;

__device__ __forceinline__ float bf2f(u16 u) { return __uint_as_float(((unsigned)u) << 16); }
__device__ __forceinline__ u16 f2bf(float f) {
    unsigned x = __float_as_uint(f);
    return (u16)((x + 0x7fffu + ((x >> 16) & 1u)) >> 16);
}
__device__ __forceinline__ fx4 mfma16(bh8 a, bh8 b, fx4 c) {
    return __builtin_amdgcn_mfma_f32_16x16x32_bf16(a, b, c, 0, 0, 0);
}
__device__ __forceinline__ void gload16(u16* lds, const u16* g) {
    __builtin_amdgcn_global_load_lds(
        (const __attribute__((address_space(1))) unsigned int*)g,
        (__attribute__((address_space(3))) unsigned int*)lds, 16, 0, 0);
}

// ---------------- dtype probe -----------------------------------------------------
__global__ void detect_kernel(const u16* __restrict__ X, unsigned* flag_out)
{
    __shared__ int cnt;
    if (threadIdx.x == 0) cnt = 0;
    __syncthreads();
    u16 u = X[threadIdx.x * 2];
    int e = (u >> 7) & 0xFF;
    int insane = (u != 0) && (e < 90 || e > 140);
    atomicAdd(&cnt, insane);
    __syncthreads();
    if (threadIdx.x == 0) flag_out[0] = (cnt > 64) ? 1u : 0u;
}

// vectorized convert: n4 = elements/4 (all our sizes are /4)
__global__ __launch_bounds__(256) void convert4_kernel(
    const void* __restrict__ in, u16* __restrict__ out, int n4, const unsigned* __restrict__ flag)
{
    int i = blockIdx.x * 256 + threadIdx.x;
    if (i >= n4) return;
    if (flag[0]) {
        float4 v = ((const float4*)in)[i];
        ushort4 o;
        o.x = f2bf(v.x); o.y = f2bf(v.y); o.z = f2bf(v.z); o.w = f2bf(v.w);
        ((ushort4*)out)[i] = o;
    } else {
        ((ushort4*)out)[i] = ((const ushort4*)in)[i];
    }
}

__global__ __launch_bounds__(256) void wtrans_kernel(
    const void* __restrict__ in, u16* __restrict__ out, int rows, int cols,
    const unsigned* __restrict__ flag)
{
    int idx = blockIdx.x * 256 + threadIdx.x;
    if (idx >= rows * cols) return;
    int r = idx / cols, c = idx % cols;
    float v = flag[0] ? ((const float*)in)[idx] : bf2f(((const u16*)in)[idx]);
    out[(size_t)c * rows + r] = f2bf(v);
}

// ---------------- QKV MFMA GEMM (async staging + xor swizzle) ---------------------
__global__ __launch_bounds__(256) void qkv_mfma_kernel(
    const u16* __restrict__ X, const u16* __restrict__ WT,
    u16* __restrict__ Q, u16* __restrict__ K, u16* __restrict__ VT)
{
    __shared__ u16 Xs[128 * 64];
    __shared__ u16 Ws[128 * 64];
    const int tid = threadIdx.x;
    const int wave = tid >> 6, lane = tid & 63;
    const int wrow = (wave >> 1) * 64, wcol = (wave & 1) * 64;
    const int i0 = blockIdx.x * 128;
    const int j0 = blockIdx.y * 128;
    const int la = lane >> 3, lb = lane & 7;
    const int lm = lane & 15, lq = lane >> 4;
    const int sw = lm & 7;
    const int sc = (lb ^ la) * 8;
    fx4 acc[4][4];
#pragma unroll
    for (int a = 0; a < 4; ++a)
#pragma unroll
        for (int b = 0; b < 4; ++b) acc[a][b] = (fx4){0.f, 0.f, 0.f, 0.f};

    for (int k0 = 0; k0 < DMODEL; k0 += 64) {
        __syncthreads();
#pragma unroll
        for (int jj = 0; jj < 4; ++jj) {
            int rb = wave * 32 + jj * 8;
            gload16(Xs + rb * 64, X + (size_t)(i0 + rb + la) * DMODEL + k0 + sc);
            gload16(Ws + rb * 64, WT + (size_t)(j0 + rb + la) * DMODEL + k0 + sc);
        }
        __syncthreads();
#pragma unroll
        for (int ks = 0; ks < 2; ++ks) {
            const int po = ((ks * 4 + lq) ^ sw) * 8;
            bh8 xf[4], wf[4];
#pragma unroll
            for (int im = 0; im < 4; ++im)
                xf[im] = *(const bh8*)(Xs + (wrow + im * 16 + lm) * 64 + po);
#pragma unroll
            for (int in = 0; in < 4; ++in)
                wf[in] = *(const bh8*)(Ws + (wcol + in * 16 + lm) * 64 + po);
#pragma unroll
            for (int im = 0; im < 4; ++im)
#pragma unroll
                for (int in = 0; in < 4; ++in)
                    acc[im][in] = mfma16(wf[in], xf[im], acc[im][in]);
        }
    }
#pragma unroll
    for (int im = 0; im < 4; ++im) {
        int m = i0 + wrow + im * 16 + lm;
        int bb = m >> 13, ns = m & (N_SEQ - 1);
#pragma unroll
        for (int in = 0; in < 4; ++in) {
            int nn = j0 + wcol + in * 16 + (lq << 2);
            int which = nn >> 9;
            int h = (nn >> 6) & 7;
            int d = nn & 63;
            if (which == 2) {
                size_t vb = (size_t)(bb * NHEAD + h) * DHEAD;
#pragma unroll
                for (int cc = 0; cc < 4; ++cc)
                    VT[(vb + d + cc) * N_SEQ + ns] = f2bf(acc[im][in][cc]);
            } else {
                u16* dst = (which == 0) ? Q : K;
                float s = (which == 0) ? 0.125f : 1.f;
                ushort4 o;
                o.x = f2bf(acc[im][in][0] * s); o.y = f2bf(acc[im][in][1] * s);
                o.z = f2bf(acc[im][in][2] * s); o.w = f2bf(acc[im][in][3] * s);
                *(ushort4*)(dst + ((size_t)(bb * NHEAD + h) * N_SEQ + ns) * DHEAD + d) = o;
            }
        }
    }
}

// ---------------- landmark pooling ------------------------------------------------
__global__ __launch_bounds__(64) void pool_kernel(
    const u16* __restrict__ Q, const u16* __restrict__ K,
    float* __restrict__ QL, float* __restrict__ KL,
    u16* __restrict__ QLb, u16* __restrict__ KLb)
{
    int m = blockIdx.x, bh = blockIdx.y, d = threadIdx.x;
    size_t base = ((size_t)bh * N_SEQ + m * 32) * DHEAD + d;
    float sq = 0.f, sk = 0.f;
#pragma unroll
    for (int i = 0; i < 32; ++i) {
        sq += bf2f(Q[base + i * DHEAD]);
        sk += bf2f(K[base + i * DHEAD]);
    }
    size_t ob = ((size_t)bh * NLAND + m) * DHEAD + d;
    sq *= (1.f / 32.f); sk *= (1.f / 32.f);
    QL[ob] = sq; KL[ob] = sk;
    QLb[ob] = f2bf(sq); KLb[ob] = f2bf(sk);
}

// ---------------- attn2 = softmax(q_l @ k_l^T) ------------------------------------
__global__ __launch_bounds__(256) void attn2_kernel(
    const float* __restrict__ QL, const float* __restrict__ KL, float* __restrict__ A2)
{
    __shared__ float qrow[64];
    __shared__ float red[256];
    int i = blockIdx.x, bh = blockIdx.y, j = threadIdx.x;
    if (j < 64) qrow[j] = QL[((size_t)bh * NLAND + i) * DHEAD + j];
    __syncthreads();
    const float* kr = KL + ((size_t)bh * NLAND + j) * DHEAD;
    float lg = 0.f;
#pragma unroll
    for (int d = 0; d < 64; ++d) lg += qrow[d] * kr[d];
    red[j] = lg; __syncthreads();
    for (int s = 128; s > 0; s >>= 1) { if (j < s) red[j] = fmaxf(red[j], red[j + s]); __syncthreads(); }
    float mx = red[0]; __syncthreads();
    float p = __expf(lg - mx);
    red[j] = p; __syncthreads();
    for (int s = 128; s > 0; s >>= 1) { if (j < s) red[j] += red[j + s]; __syncthreads(); }
    float sum = red[0];
    A2[((size_t)bh * NLAND + i) * NLAND + j] = p / sum;
}

__global__ void init_scal_kernel(unsigned* scal)
{
    if (threadIdx.x < 2) scal[threadIdx.x] = 0u;
    if (threadIdx.x == 2) scal[3] = 0u;   // grid-barrier counter (reset每 replay)
}

__global__ __launch_bounds__(256) void absmax_kernel(const float* __restrict__ A2, unsigned* scal)
{
    __shared__ float red[256];
    int bh = blockIdx.x, t = threadIdx.x;
    const float* Ab = A2 + (size_t)bh * 65536;
    float cs = 0.f, rs = 0.f;
    for (int j = 0; j < 256; ++j) cs += fabsf(Ab[t * 256 + j]);
    for (int i = 0; i < 256; ++i) rs += fabsf(Ab[i * 256 + t]);
    red[t] = cs; __syncthreads();
    for (int s = 128; s > 0; s >>= 1) { if (t < s) red[t] = fmaxf(red[t], red[t + s]); __syncthreads(); }
    if (t == 0) atomicMax(scal + 0, __float_as_uint(red[0]));
    __syncthreads();
    red[t] = rs; __syncthreads();
    for (int s = 128; s > 0; s >>= 1) { if (t < s) red[t] = fmaxf(red[t], red[t + s]); __syncthreads(); }
    if (t == 0) atomicMax(scal + 1, __float_as_uint(red[0]));
}

// z0 + A2->bf16 in one pass
__global__ __launch_bounds__(256) void z0_kernel(
    const float* __restrict__ A2, const unsigned* __restrict__ scal,
    u16* __restrict__ zb, u16* __restrict__ zbT, u16* __restrict__ A2b)
{
    float inv = 1.f / (__uint_as_float(scal[0]) * __uint_as_float(scal[1]));
    size_t idx = (size_t)blockIdx.x * 256 + threadIdx.x;
    size_t bh = idx >> 16;
    int r = (int)(idx & 65535);
    int i = r >> 8, j = r & 255;
    float a = A2[idx];
    zb[idx]  = f2bf(A2[(bh << 16) + (size_t)j * 256 + i] * inv);
    zbT[idx] = f2bf(a * inv);
    A2b[idx] = f2bf(a);
}

// ---------------- pinv: one 64x64x256 tile, round-6 LDS-staged bgemm body ---------
__device__ __forceinline__ void bgemm_tile(
    u16* As, u16* Bs,
    const u16* __restrict__ A, const u16* __restrict__ BT,
    u16* __restrict__ Cn, u16* __restrict__ Ct, const u16* __restrict__ E,
    int N, long sB, long sCn, long sCt,
    float sc, float alpha, float beta, int wn, int wt,
    int i0, int j0, int bh)
{
    const int tid = threadIdx.x;
    const int wave = tid >> 6, lane = tid & 63;
    const int wm = (wave >> 1) * 32, wnn = (wave & 1) * 32;
    const u16* Ab = A + (size_t)bh * 65536;
    const u16* Bb = BT + (size_t)bh * sB;
    const int srow = tid >> 2, scol = (tid & 3) * 16;
    const int lm = lane & 15, lq = lane >> 4;
    fx4 acc[2][2];
#pragma unroll
    for (int a = 0; a < 2; ++a)
#pragma unroll
        for (int b = 0; b < 2; ++b) acc[a][b] = (fx4){0.f, 0.f, 0.f, 0.f};

    for (int k0 = 0; k0 < 256; k0 += 64) {
        uint4 a0 = *(const uint4*)(Ab + (size_t)(i0 + srow) * 256 + k0 + scol);
        uint4 a1 = *(const uint4*)(Ab + (size_t)(i0 + srow) * 256 + k0 + scol + 8);
        uint4 b0 = *(const uint4*)(Bb + (size_t)(j0 + srow) * 256 + k0 + scol);
        uint4 b1 = *(const uint4*)(Bb + (size_t)(j0 + srow) * 256 + k0 + scol + 8);
        __syncthreads();
        *(uint4*)(As + srow * 72 + scol) = a0;
        *(uint4*)(As + srow * 72 + scol + 8) = a1;
        *(uint4*)(Bs + srow * 72 + scol) = b0;
        *(uint4*)(Bs + srow * 72 + scol + 8) = b1;
        __syncthreads();
#pragma unroll
        for (int ks = 0; ks < 2; ++ks) {
            bh8 lf[2], rf[2];
#pragma unroll
            for (int im = 0; im < 2; ++im)
                lf[im] = *(const bh8*)(As + (wm + im * 16 + lm) * 72 + ks * 32 + lq * 8);
#pragma unroll
            for (int in = 0; in < 2; ++in)
                rf[in] = *(const bh8*)(Bs + (wnn + in * 16 + lm) * 72 + ks * 32 + lq * 8);
#pragma unroll
            for (int im = 0; im < 2; ++im)
#pragma unroll
                for (int in = 0; in < 2; ++in)
                    acc[im][in] = mfma16(lf[im], rf[in], acc[im][in]);
        }
    }
#pragma unroll
    for (int im = 0; im < 2; ++im) {
#pragma unroll
        for (int in = 0; in < 2; ++in) {
            int n = j0 + wnn + in * 16 + lm;
            int m0 = i0 + wm + im * 16 + (lq << 2);
            float c[4];
#pragma unroll
            for (int r = 0; r < 4; ++r) {
                int m = m0 + r;
                float x = beta * acc[im][in][r];
                if (alpha != 0.f)
                    x += alpha * bf2f(E[(size_t)bh * 65536 + (size_t)m * 256 + n]);
                if (m == n) x += sc;
                c[r] = x;
            }
            if (wn) {
#pragma unroll
                for (int r = 0; r < 4; ++r)
                    Cn[(size_t)bh * sCn + (size_t)(m0 + r) * N + n] = f2bf(c[r]);
            }
            if (wt) {
                ushort4 o;
                o.x = f2bf(c[0]); o.y = f2bf(c[1]); o.z = f2bf(c[2]); o.w = f2bf(c[3]);
                *(ushort4*)(Ct + (size_t)bh * sCt + (size_t)n * 256 + m0) = o;
            }
        }
    }
}

// monotonic device-scope grid barrier (256 blocks): release-fence, arrive,
// atomic-spin, acquire-fence. Counter zeroed by init_scal each graph replay.
__device__ __forceinline__ void gsync(unsigned* bar, unsigned* phase)
{
    __syncthreads();
    if (threadIdx.x == 0) {
        __threadfence();
        unsigned ph = ++(*phase);
        atomicAdd(bar, 1u);
        while (atomicAdd(bar, 0u) < ph * 256u) {}
        __threadfence();
    }
    __syncthreads();
}

// persistent pinv chain: 256 blocks, each owns 2 of 512 64x64 tiles per step.
// 6 iters x 4 GEMM steps with grid barriers; final WMT GEMM on blocks 0..127.
__global__ __launch_bounds__(256, 2) void pinv_sync_kernel(
    const u16* __restrict__ A2b,
    u16* zA, u16* zAT, u16* zB, u16* zBT,
    u16* xz, u16* xzT, u16* t2T, u16* t3T,
    const u16* __restrict__ W3VT, u16* __restrict__ WMT,
    unsigned* bar)
{
    __shared__ u16 As[64 * 72];
    __shared__ u16 Bs[64 * 72];
    const int bid = blockIdx.x;
    const int bh = bid >> 3;
    const int tt0 = (bid & 7) * 2;
    unsigned phase = 0;
    u16 *z = zA, *zT = zAT, *zn = zB, *znT = zBT;
#pragma unroll 1
    for (int it = 0; it < 6; ++it) {
#pragma unroll 1
        for (int t = 0; t < 2; ++t) {
            const int tt = tt0 + t, i0 = (tt >> 2) * 64, j0 = (tt & 3) * 64;
            bgemm_tile(As, Bs, A2b, zT, xz, xzT, A2b, 256, 65536, 65536, 65536,
                       0.f, 0.f, 1.f, 1, 1, i0, j0, bh);
        }
        gsync(bar, &phase);
#pragma unroll 1
        for (int t = 0; t < 2; ++t) {
            const int tt = tt0 + t, i0 = (tt >> 2) * 64, j0 = (tt & 3) * 64;
            bgemm_tile(As, Bs, xz, xzT, xz, t2T, xz, 256, 65536, 65536, 65536,
                       15.f, -7.f, 1.f, 0, 1, i0, j0, bh);
        }
        gsync(bar, &phase);
#pragma unroll 1
        for (int t = 0; t < 2; ++t) {
            const int tt = tt0 + t, i0 = (tt >> 2) * 64, j0 = (tt & 3) * 64;
            bgemm_tile(As, Bs, xz, t2T, xz, t3T, xz, 256, 65536, 65536, 65536,
                       13.f, 0.f, -1.f, 0, 1, i0, j0, bh);
        }
        gsync(bar, &phase);
#pragma unroll 1
        for (int t = 0; t < 2; ++t) {
            const int tt = tt0 + t, i0 = (tt >> 2) * 64, j0 = (tt & 3) * 64;
            bgemm_tile(As, Bs, z, t3T, zn, znT, xz, 256, 65536, 65536, 65536,
                       0.f, 0.f, 0.25f, 1, 1, i0, j0, bh);
        }
        gsync(bar, &phase);
        u16* tp;
        tp = z;  z = zn;   zn = tp;
        tp = zT; zT = znT; znT = tp;
    }
    if (bid < 128) {
        const int fh = bid >> 2, fi = (bid & 3) * 64;
        bgemm_tile(As, Bs, z, W3VT, WMT, WMT, A2b, 64, 16384, 16384, 16384,
                   0.f, 0.f, 1.f, 0, 1, fi, 0, fh);
    }
}

// ---------------- attn3@v flash MFMA: fetch-once, 4 waves share K/VT chunks -------
__global__ __launch_bounds__(256, 2) void attn3v_mfma_kernel(
    const u16* __restrict__ QLb, const u16* __restrict__ Kb,
    const u16* __restrict__ VTb, u16* __restrict__ PO, float* __restrict__ ML)
{
    __shared__ u16 Ks[64 * 72];
    __shared__ u16 Vs[64 * 72];
    __shared__ u16 Pw[4][64 * 72];
    const int tid = threadIdx.x;
    const int wave = tid >> 6, lane = tid & 63;
    const int q = lane >> 4, l15 = lane & 15;
    const int part = blockIdx.x;
    const int bh = blockIdx.y;
    const int nbase = part * 512;
    const int srow = tid >> 2, scol = (tid & 3) * 16;
    u16* Pp = Pw[wave];
    bh8 qf[4][2];
#pragma unroll
    for (int mt = 0; mt < 4; ++mt)
#pragma unroll
        for (int ks = 0; ks < 2; ++ks)
            qf[mt][ks] = *(const bh8*)(QLb + ((size_t)bh * NLAND + wave * 64 + mt * 16 + l15) * DHEAD + ks * 32 + q * 8);
    float M[4] = {-1e30f, -1e30f, -1e30f, -1e30f};
    float L[4] = {0.f, 0.f, 0.f, 0.f};
    fx4 O[4][4];
#pragma unroll
    for (int mt = 0; mt < 4; ++mt)
#pragma unroll
        for (int dt = 0; dt < 4; ++dt) O[mt][dt] = (fx4){0.f, 0.f, 0.f, 0.f};

    for (int c = 0; c < 8; ++c) {
        const int n0 = nbase + c * 64;
        uint4 k0v = *(const uint4*)(Kb + ((size_t)bh * N_SEQ + n0 + srow) * DHEAD + scol);
        uint4 k1v = *(const uint4*)(Kb + ((size_t)bh * N_SEQ + n0 + srow) * DHEAD + scol + 8);
        uint4 v0v = *(const uint4*)(VTb + ((size_t)bh * DHEAD + srow) * N_SEQ + n0 + scol);
        uint4 v1v = *(const uint4*)(VTb + ((size_t)bh * DHEAD + srow) * N_SEQ + n0 + scol + 8);
        __syncthreads();
        *(uint4*)(Ks + srow * 72 + scol) = k0v;
        *(uint4*)(Ks + srow * 72 + scol + 8) = k1v;
        *(uint4*)(Vs + srow * 72 + scol) = v0v;
        *(uint4*)(Vs + srow * 72 + scol + 8) = v1v;
        __syncthreads();
        fx4 S[4][4];   // [nt][mt]
#pragma unroll
        for (int nt = 0; nt < 4; ++nt)
#pragma unroll
            for (int mt = 0; mt < 4; ++mt) S[nt][mt] = (fx4){0.f, 0.f, 0.f, 0.f};
#pragma unroll
        for (int ks = 0; ks < 2; ++ks) {
            bh8 kf[4];
#pragma unroll
            for (int nt = 0; nt < 4; ++nt)
                kf[nt] = *(const bh8*)(Ks + (nt * 16 + l15) * 72 + ks * 32 + q * 8);
#pragma unroll
            for (int nt = 0; nt < 4; ++nt)
#pragma unroll
                for (int mt = 0; mt < 4; ++mt)
                    S[nt][mt] = mfma16(kf[nt], qf[mt][ks], S[nt][mt]);   // D[n][m]
        }
#pragma unroll
        for (int mt = 0; mt < 4; ++mt) {
            float cm = -1e30f;
#pragma unroll
            for (int nt = 0; nt < 4; ++nt)
#pragma unroll
                for (int r = 0; r < 4; ++r) cm = fmaxf(cm, S[nt][mt][r]);
            cm = fmaxf(cm, __shfl_xor(cm, 16));
            cm = fmaxf(cm, __shfl_xor(cm, 32));
            float Mn = fmaxf(M[mt], cm);
            float al = __expf(M[mt] - Mn);
            M[mt] = Mn;
            L[mt] *= al;
#pragma unroll
            for (int dt = 0; dt < 4; ++dt) {
                O[mt][dt][0] *= al; O[mt][dt][1] *= al;
                O[mt][dt][2] *= al; O[mt][dt][3] *= al;
            }
            float ps = 0.f;
#pragma unroll
            for (int nt = 0; nt < 4; ++nt)
#pragma unroll
                for (int r = 0; r < 4; ++r) {
                    float p = __expf(S[nt][mt][r] - Mn);
                    ps += p;
                    Pp[(mt * 16 + l15) * 72 + nt * 16 + q * 4 + r] = f2bf(p);
                }
            ps += __shfl_xor(ps, 16);
            ps += __shfl_xor(ps, 32);
            L[mt] += ps;
        }
#pragma unroll
        for (int ks = 0; ks < 2; ++ks) {
            bh8 pf[4];
#pragma unroll
            for (int mt = 0; mt < 4; ++mt)
                pf[mt] = *(const bh8*)(Pp + (mt * 16 + l15) * 72 + ks * 32 + q * 8);
#pragma unroll
            for (int dt = 0; dt < 4; ++dt) {
                bh8 vf = *(const bh8*)(Vs + (dt * 16 + l15) * 72 + ks * 32 + q * 8);
#pragma unroll
                for (int mt = 0; mt < 4; ++mt)
                    O[mt][dt] = mfma16(vf, pf[mt], O[mt][dt]);   // D[d][m]
            }
        }
    }
#pragma unroll
    for (int mt = 0; mt < 4; ++mt) {
        size_t mrow = (size_t)(bh * 16 + part) * NLAND + wave * 64 + mt * 16 + l15;
#pragma unroll
        for (int dt = 0; dt < 4; ++dt) {
            ushort4 o;
            o.x = f2bf(O[mt][dt][0]); o.y = f2bf(O[mt][dt][1]);
            o.z = f2bf(O[mt][dt][2]); o.w = f2bf(O[mt][dt][3]);
            *(ushort4*)(PO + mrow * DHEAD + dt * 16 + q * 4) = o;
        }
        if (q == 0) { ML[mrow * 2] = M[mt]; ML[mrow * 2 + 1] = L[mt]; }
    }
}

__global__ __launch_bounds__(64) void combine_kernel(
    const u16* __restrict__ PO, const float* __restrict__ ML, u16* __restrict__ W3VT)
{
    int m = blockIdx.x, bh = blockIdx.y, d = threadIdx.x;
    float Mg = -1e30f;
#pragma unroll
    for (int p = 0; p < 16; ++p)
        Mg = fmaxf(Mg, ML[((size_t)(bh * 16 + p) * NLAND + m) * 2]);
    float denom = 0.f, o = 0.f;
#pragma unroll
    for (int p = 0; p < 16; ++p) {
        size_t ix = (size_t)(bh * 16 + p) * NLAND + m;
        float w = __expf(ML[ix * 2] - Mg);
        denom += ML[ix * 2 + 1] * w;
        o += bf2f(PO[ix * DHEAD + d]) * w;
    }
    W3VT[((size_t)bh * DHEAD + d) * NLAND + m] = f2bf(o / denom);
}

// ---------------- depthwise conv residual: RT[bh*64+d][n] from VT -----------------
__global__ __launch_bounds__(256) void conv_kernel(
    const u16* __restrict__ VT, const u16* __restrict__ CW, u16* __restrict__ RT)
{
    __shared__ float vl[2080];
    __shared__ float cws[33];
    const int tid = threadIdx.x;
    const int c0 = blockIdx.x * 2048;
    const int row = blockIdx.y;
    const int h = (row >> 6) & 7;
    const u16* src = VT + (size_t)row * N_SEQ;
    for (int i = tid; i < 2080; i += 256) {
        int gn = c0 - 16 + i;
        vl[i] = (gn >= 0 && gn < N_SEQ) ? bf2f(src[gn]) : 0.f;
    }
    if (tid < 33) cws[tid] = bf2f(CW[h * 33 + tid]);
    __syncthreads();
    float v[40];
    const int base = tid * 8;
#pragma unroll
    for (int i = 0; i < 40; ++i) v[i] = vl[base + i];
    float s[8];
#pragma unroll
    for (int j = 0; j < 8; ++j) {
        float a = 0.f;
#pragma unroll
        for (int t = 0; t < 33; ++t) a += cws[t] * v[j + t];
        s[j] = a;
    }
    u16* dst = RT + (size_t)row * N_SEQ + c0 + base;
    ushort4 o0, o1;
    o0.x = f2bf(s[0]); o0.y = f2bf(s[1]); o0.z = f2bf(s[2]); o0.w = f2bf(s[3]);
    o1.x = f2bf(s[4]); o1.y = f2bf(s[5]); o1.z = f2bf(s[6]); o1.w = f2bf(s[7]);
    *(ushort4*)dst = o0;
    *(ushort4*)(dst + 4) = o1;
}

// ---------------- outheads: attn1 softmax + @WM + RT residual, 64 n/block ---------
__global__ __launch_bounds__(256) void outheads_mfma_kernel(
    const u16* __restrict__ Qb, const u16* __restrict__ KLb,
    const u16* __restrict__ WMT, const u16* __restrict__ RT,
    u16* __restrict__ Y)
{
    __shared__ u16 Pl[64 * 264];
    __shared__ float wmax[4][64];
    __shared__ float wsum[4][64];
    const int tid = threadIdx.x;
    const int wave = tid >> 6, lane = tid & 63;
    const int q = lane >> 4, l15 = lane & 15;
    const int bh = blockIdx.y;
    const int bb = bh >> 3, h = bh & 7;
    const int n0 = blockIdx.x * 64;
    fx4 S[4][4];
#pragma unroll
    for (int a = 0; a < 4; ++a)
#pragma unroll
        for (int b = 0; b < 4; ++b) S[a][b] = (fx4){0.f, 0.f, 0.f, 0.f};
#pragma unroll
    for (int ks = 0; ks < 2; ++ks) {
        bh8 qfr[4];
#pragma unroll
        for (int nt = 0; nt < 4; ++nt)
            qfr[nt] = *(const bh8*)(Qb + ((size_t)bh * N_SEQ + n0 + nt * 16 + l15) * DHEAD + ks * 32 + q * 8);
#pragma unroll
        for (int mt = 0; mt < 4; ++mt) {
            bh8 kf = *(const bh8*)(KLb + ((size_t)bh * NLAND + wave * 64 + mt * 16 + l15) * DHEAD + ks * 32 + q * 8);
#pragma unroll
            for (int nt = 0; nt < 4; ++nt)
                S[nt][mt] = mfma16(qfr[nt], kf, S[nt][mt]);
        }
    }
#pragma unroll
    for (int nt = 0; nt < 4; ++nt)
#pragma unroll
        for (int r = 0; r < 4; ++r) {
            float pm = fmaxf(fmaxf(S[nt][0][r], S[nt][1][r]), fmaxf(S[nt][2][r], S[nt][3][r]));
            pm = fmaxf(pm, __shfl_xor(pm, 1));
            pm = fmaxf(pm, __shfl_xor(pm, 2));
            pm = fmaxf(pm, __shfl_xor(pm, 4));
            pm = fmaxf(pm, __shfl_xor(pm, 8));
            if (l15 == 0) wmax[wave][nt * 16 + q * 4 + r] = pm;
        }
    __syncthreads();
#pragma unroll
    for (int nt = 0; nt < 4; ++nt)
#pragma unroll
        for (int r = 0; r < 4; ++r) {
            int nl = nt * 16 + q * 4 + r;
            float Mf = fmaxf(fmaxf(wmax[0][nl], wmax[1][nl]), fmaxf(wmax[2][nl], wmax[3][nl]));
            float ps = 0.f;
#pragma unroll
            for (int mt = 0; mt < 4; ++mt) {
                float p = __expf(S[nt][mt][r] - Mf);
                ps += p;
                Pl[nl * 264 + wave * 64 + mt * 16 + l15] = f2bf(p);
            }
            ps += __shfl_xor(ps, 1);
            ps += __shfl_xor(ps, 2);
            ps += __shfl_xor(ps, 4);
            ps += __shfl_xor(ps, 8);
            if (l15 == 0) wsum[wave][nl] = ps;
        }
    __syncthreads();
    fx4 O[4];
#pragma unroll
    for (int nt = 0; nt < 4; ++nt) O[nt] = (fx4){0.f, 0.f, 0.f, 0.f};
#pragma unroll
    for (int ks = 0; ks < 8; ++ks) {
        bh8 af = *(const bh8*)(WMT + ((size_t)bh * DHEAD + wave * 16 + l15) * NLAND + ks * 32 + q * 8);
#pragma unroll
        for (int nt = 0; nt < 4; ++nt) {
            bh8 pf = *(const bh8*)(Pl + (size_t)(nt * 16 + l15) * 264 + ks * 32 + q * 8);
            O[nt] = mfma16(af, pf, O[nt]);
        }
    }
#pragma unroll
    for (int nt = 0; nt < 4; ++nt) {
        int nl = nt * 16 + l15;
        float inv = 1.f / (wsum[0][nl] + wsum[1][nl] + wsum[2][nl] + wsum[3][nl]);
        int d0 = wave * 16 + (q << 2);
        fx4 v = O[nt];
#pragma unroll
        for (int c = 0; c < 4; ++c)
            v[c] = v[c] * inv + bf2f(RT[(size_t)(bh * DHEAD + d0 + c) * N_SEQ + n0 + nl]);
        ushort4 o;
        o.x = f2bf(v[0]); o.y = f2bf(v[1]); o.z = f2bf(v[2]); o.w = f2bf(v[3]);
        *(ushort4*)(Y + ((size_t)bb * N_SEQ + n0 + nl) * DMODEL + h * DHEAD + d0) = o;
    }
}

// ---------------- final MFMA GEMM (async staging + swizzle) -----------------------
__global__ __launch_bounds__(256) void final_mfma_kernel(
    const u16* __restrict__ Y, const u16* __restrict__ WT,
    const u16* __restrict__ Bias, const u16* __restrict__ X, void* __restrict__ Out,
    const unsigned* __restrict__ flag)
{
    __shared__ u16 Xs[128 * 64];
    __shared__ u16 Ws[128 * 64];
    const int tid = threadIdx.x;
    const int wave = tid >> 6, lane = tid & 63;
    const int wrow = (wave >> 1) * 64, wcol = (wave & 1) * 64;
    const int i0 = blockIdx.x * 128;
    const int j0 = blockIdx.y * 128;
    const int la = lane >> 3, lb = lane & 7;
    const int lm = lane & 15, lq = lane >> 4;
    const int sw = lm & 7;
    const int sc = (lb ^ la) * 8;
    const unsigned isf32 = flag[0];
    fx4 acc[4][4];
#pragma unroll
    for (int a = 0; a < 4; ++a)
#pragma unroll
        for (int b = 0; b < 4; ++b) acc[a][b] = (fx4){0.f, 0.f, 0.f, 0.f};

    for (int k0 = 0; k0 < DMODEL; k0 += 64) {
        __syncthreads();
#pragma unroll
        for (int jj = 0; jj < 4; ++jj) {
            int rb = wave * 32 + jj * 8;
            gload16(Xs + rb * 64, Y + (size_t)(i0 + rb + la) * DMODEL + k0 + sc);
            gload16(Ws + rb * 64, WT + (size_t)(j0 + rb + la) * DMODEL + k0 + sc);
        }
        __syncthreads();
#pragma unroll
        for (int ks = 0; ks < 2; ++ks) {
            const int po = ((ks * 4 + lq) ^ sw) * 8;
            bh8 xf[4], wf[4];
#pragma unroll
            for (int im = 0; im < 4; ++im)
                xf[im] = *(const bh8*)(Xs + (wrow + im * 16 + lm) * 64 + po);
#pragma unroll
            for (int in = 0; in < 4; ++in)
                wf[in] = *(const bh8*)(Ws + (wcol + in * 16 + lm) * 64 + po);
#pragma unroll
            for (int im = 0; im < 4; ++im)
#pragma unroll
                for (int in = 0; in < 4; ++in)
                    acc[im][in] = mfma16(wf[in], xf[im], acc[im][in]);
        }
    }
#pragma unroll
    for (int im = 0; im < 4; ++im) {
        int m = i0 + wrow + im * 16 + lm;
#pragma unroll
        for (int in = 0; in < 4; ++in) {
            int nn = j0 + wcol + in * 16 + (lq << 2);
            ushort4 b4 = *(const ushort4*)(Bias + nn);
            ushort4 x4 = *(const ushort4*)(X + (size_t)m * DMODEL + nn);
            float c0 = acc[im][in][0] + bf2f(b4.x) + bf2f(x4.x);
            float c1 = acc[im][in][1] + bf2f(b4.y) + bf2f(x4.y);
            float c2 = acc[im][in][2] + bf2f(b4.z) + bf2f(x4.z);
            float c3 = acc[im][in][3] + bf2f(b4.w) + bf2f(x4.w);
            if (isf32) {
                *(float4*)((float*)Out + (size_t)m * DMODEL + nn) = make_float4(c0, c1, c2, c3);
            } else {
                ushort4 o;
                o.x = f2bf(c0); o.y = f2bf(c1); o.z = f2bf(c2); o.w = f2bf(c3);
                *(ushort4*)((u16*)Out + (size_t)m * DMODEL + nn) = o;
            }
        }
    }
}

extern "C" void kernel_launch(void* const* d_in, const int* in_sizes, int n_in,
                              void* d_out, int out_size, void* d_ws, size_t ws_size,
                              hipStream_t stream)
{
    (void)in_sizes; (void)n_in; (void)out_size; (void)ws_size;
    char* ws = (char*)d_ws;
    u16*   Xc    = (u16*)(ws + 0);            // 33,554,432
    u16*   WqkvT = (u16*)(ws + 33554432);     //  1,572,864
    u16*   WoutT = (u16*)(ws + 35127296);     //    524,288
    u16*   Boutc = (u16*)(ws + 35651584);     //      1,024
    u16*   CWc   = (u16*)(ws + 35652608);     //      1,024
    u16*   Qb    = (u16*)(ws + 35653632);     // 33,554,432  [bh][n][d]
    u16*   Kb    = (u16*)(ws + 69208064);     // 33,554,432  [bh][n][d]; dead after attn3v
    u16*   RT    = (u16*)(ws + 69208064);     // overlays Kb post-attn3v
    u16*   VTb   = (u16*)(ws + 102762496);    // 33,554,432  [bh][d][n]
    float* QL    = (float*)(ws + 136316928);  //  2,097,152
    float* KL    = (float*)(ws + 138414080);  //  2,097,152
    u16*   QLb   = (u16*)(ws + 140511232);    //  1,048,576
    u16*   KLb   = (u16*)(ws + 141559808);    //  1,048,576
    u16*   W3VT  = (u16*)(ws + 142608384);    //  1,048,576
    u16*   WMT   = (u16*)(ws + 143656960);    //  1,048,576
    u16*   A2b   = (u16*)(ws + 144705536);    //  4,194,304
    u16*   zA    = (u16*)(ws + 148899840);    //  4,194,304
    u16*   zAT   = (u16*)(ws + 153094144);    //  4,194,304
    float* A2    = (float*)(ws + 157288448);  // overlay region
    u16*   PO    = (u16*)(ws + 157288448);
    float* ML    = (float*)(ws + 174065664);
    u16*   zB    = (u16*)(ws + 165677056);
    u16*   zBT   = (u16*)(ws + 169871360);
    u16*   xz    = (u16*)(ws + 174065664);    // overlays ML (dead after combine)
    u16*   xzT   = (u16*)(ws + 178259968);
    u16*   t2T   = (u16*)(ws + 182454272);
    u16*   t3T   = (u16*)(ws + 186648576);
    u16*   Yb    = (u16*)(ws + 157288448);
    unsigned* SCAL = (unsigned*)(ws + 190842880);

    detect_kernel<<<1, 256, 0, stream>>>((const u16*)d_in[0], SCAL + 2);
    convert4_kernel<<<16384, 256, 0, stream>>>(d_in[0], Xc, 4194304, SCAL + 2);
    wtrans_kernel<<<3072, 256, 0, stream>>>(d_in[1], WqkvT, 512, 1536, SCAL + 2);
    wtrans_kernel<<<1024, 256, 0, stream>>>(d_in[2], WoutT, 512, 512, SCAL + 2);
    convert4_kernel<<<1, 256, 0, stream>>>(d_in[3], Boutc, 128, SCAL + 2);
    convert4_kernel<<<1, 256, 0, stream>>>(d_in[4], CWc, 66, SCAL + 2);

    qkv_mfma_kernel<<<dim3(256, 12), 256, 0, stream>>>(Xc, WqkvT, Qb, Kb, VTb);
    pool_kernel<<<dim3(256, BH), 64, 0, stream>>>(Qb, Kb, QL, KL, QLb, KLb);
    attn2_kernel<<<dim3(256, BH), 256, 0, stream>>>(QL, KL, A2);
    init_scal_kernel<<<1, 64, 0, stream>>>(SCAL);
    absmax_kernel<<<32, 256, 0, stream>>>(A2, SCAL);
    z0_kernel<<<8192, 256, 0, stream>>>(A2, SCAL, zA, zAT, A2b);

    // flash attn3@v (fetch-once), combine, conv into Kb slot
    attn3v_mfma_kernel<<<dim3(16, BH), 256, 0, stream>>>(QLb, Kb, VTb, PO, ML);
    combine_kernel<<<dim3(256, BH), 64, 0, stream>>>(PO, ML, W3VT);
    conv_kernel<<<dim3(4, 2048), 256, 0, stream>>>(VTb, CWc, RT);

    // whole pinv chain + final WMT GEMM: ONE persistent launch with grid barriers
    pinv_sync_kernel<<<256, 256, 0, stream>>>(
        A2b, zA, zAT, zB, zBT, xz, xzT, t2T, t3T, W3VT, WMT, SCAL + 3);

    outheads_mfma_kernel<<<dim3(128, BH), 256, 0, stream>>>(Qb, KLb, WMT, RT, Yb);
    final_mfma_kernel<<<dim3(256, 4), 256, 0, stream>>>(Yb, WoutT, Boutc, Xc, d_out, SCAL + 2);
}

// Round 6
// 1070.615 us; speedup vs baseline: 1.5568x; 1.2766x over previous
//
#include <hip/hip_runtime.h>

// Nystrom attention, MI355X round 12: persistent pinv chain, barrier fixed.
//  - round-11's global RMW-spin barrier (atomic storm, 833 us) replaced by
//    32 independent PER-BH barriers (8 blocks each): one fetch_add arrive +
//    release-store flag by last arriver + RMW-free atomic-load spin with
//    s_sleep backoff. Final WMT GEMM reassigned to same-group blocks so the
//    per-group barrier orders it (old mapping would race).
//  - everything else unchanged (outheads = round-6 struct, 83 us).
// b=4, n=8192, dim=512, h=8, dh=64, m=256 landmarks, pinv iters=6, conv k=33.

#define N_SEQ 8192
#define DMODEL 512
#define NHEAD 8
#define DHEAD 64
#define NLAND 256
#define BH 32

typedef unsigned short u16;
typedef __attribute__((ext_vector_type(8))) short bh8;
typedef __attribute__((ext_vector_type(4))) float fx4;

__device__ __forceinline__ float bf2f(u16 u) { return __uint_as_float(((unsigned)u) << 16); }
__device__ __forceinline__ u16 f2bf(float f) {
    unsigned x = __float_as_uint(f);
    return (u16)((x + 0x7fffu + ((x >> 16) & 1u)) >> 16);
}
__device__ __forceinline__ fx4 mfma16(bh8 a, bh8 b, fx4 c) {
    return __builtin_amdgcn_mfma_f32_16x16x32_bf16(a, b, c, 0, 0, 0);
}
__device__ __forceinline__ void gload16(u16* lds, const u16* g) {
    __builtin_amdgcn_global_load_lds(
        (const __attribute__((address_space(1))) unsigned int*)g,
        (__attribute__((address_space(3))) unsigned int*)lds, 16, 0, 0);
}

// ---------------- dtype probe -----------------------------------------------------
__global__ void detect_kernel(const u16* __restrict__ X, unsigned* flag_out)
{
    __shared__ int cnt;
    if (threadIdx.x == 0) cnt = 0;
    __syncthreads();
    u16 u = X[threadIdx.x * 2];
    int e = (u >> 7) & 0xFF;
    int insane = (u != 0) && (e < 90 || e > 140);
    atomicAdd(&cnt, insane);
    __syncthreads();
    if (threadIdx.x == 0) flag_out[0] = (cnt > 64) ? 1u : 0u;
}

// vectorized convert: n4 = elements/4 (all our sizes are /4)
__global__ __launch_bounds__(256) void convert4_kernel(
    const void* __restrict__ in, u16* __restrict__ out, int n4, const unsigned* __restrict__ flag)
{
    int i = blockIdx.x * 256 + threadIdx.x;
    if (i >= n4) return;
    if (flag[0]) {
        float4 v = ((const float4*)in)[i];
        ushort4 o;
        o.x = f2bf(v.x); o.y = f2bf(v.y); o.z = f2bf(v.z); o.w = f2bf(v.w);
        ((ushort4*)out)[i] = o;
    } else {
        ((ushort4*)out)[i] = ((const ushort4*)in)[i];
    }
}

__global__ __launch_bounds__(256) void wtrans_kernel(
    const void* __restrict__ in, u16* __restrict__ out, int rows, int cols,
    const unsigned* __restrict__ flag)
{
    int idx = blockIdx.x * 256 + threadIdx.x;
    if (idx >= rows * cols) return;
    int r = idx / cols, c = idx % cols;
    float v = flag[0] ? ((const float*)in)[idx] : bf2f(((const u16*)in)[idx]);
    out[(size_t)c * rows + r] = f2bf(v);
}

// ---------------- QKV MFMA GEMM (async staging + xor swizzle) ---------------------
__global__ __launch_bounds__(256) void qkv_mfma_kernel(
    const u16* __restrict__ X, const u16* __restrict__ WT,
    u16* __restrict__ Q, u16* __restrict__ K, u16* __restrict__ VT)
{
    __shared__ u16 Xs[128 * 64];
    __shared__ u16 Ws[128 * 64];
    const int tid = threadIdx.x;
    const int wave = tid >> 6, lane = tid & 63;
    const int wrow = (wave >> 1) * 64, wcol = (wave & 1) * 64;
    const int i0 = blockIdx.x * 128;
    const int j0 = blockIdx.y * 128;
    const int la = lane >> 3, lb = lane & 7;
    const int lm = lane & 15, lq = lane >> 4;
    const int sw = lm & 7;
    const int sc = (lb ^ la) * 8;
    fx4 acc[4][4];
#pragma unroll
    for (int a = 0; a < 4; ++a)
#pragma unroll
        for (int b = 0; b < 4; ++b) acc[a][b] = (fx4){0.f, 0.f, 0.f, 0.f};

    for (int k0 = 0; k0 < DMODEL; k0 += 64) {
        __syncthreads();
#pragma unroll
        for (int jj = 0; jj < 4; ++jj) {
            int rb = wave * 32 + jj * 8;
            gload16(Xs + rb * 64, X + (size_t)(i0 + rb + la) * DMODEL + k0 + sc);
            gload16(Ws + rb * 64, WT + (size_t)(j0 + rb + la) * DMODEL + k0 + sc);
        }
        __syncthreads();
#pragma unroll
        for (int ks = 0; ks < 2; ++ks) {
            const int po = ((ks * 4 + lq) ^ sw) * 8;
            bh8 xf[4], wf[4];
#pragma unroll
            for (int im = 0; im < 4; ++im)
                xf[im] = *(const bh8*)(Xs + (wrow + im * 16 + lm) * 64 + po);
#pragma unroll
            for (int in = 0; in < 4; ++in)
                wf[in] = *(const bh8*)(Ws + (wcol + in * 16 + lm) * 64 + po);
#pragma unroll
            for (int im = 0; im < 4; ++im)
#pragma unroll
                for (int in = 0; in < 4; ++in)
                    acc[im][in] = mfma16(wf[in], xf[im], acc[im][in]);
        }
    }
#pragma unroll
    for (int im = 0; im < 4; ++im) {
        int m = i0 + wrow + im * 16 + lm;
        int bb = m >> 13, ns = m & (N_SEQ - 1);
#pragma unroll
        for (int in = 0; in < 4; ++in) {
            int nn = j0 + wcol + in * 16 + (lq << 2);
            int which = nn >> 9;
            int h = (nn >> 6) & 7;
            int d = nn & 63;
            if (which == 2) {
                size_t vb = (size_t)(bb * NHEAD + h) * DHEAD;
#pragma unroll
                for (int cc = 0; cc < 4; ++cc)
                    VT[(vb + d + cc) * N_SEQ + ns] = f2bf(acc[im][in][cc]);
            } else {
                u16* dst = (which == 0) ? Q : K;
                float s = (which == 0) ? 0.125f : 1.f;
                ushort4 o;
                o.x = f2bf(acc[im][in][0] * s); o.y = f2bf(acc[im][in][1] * s);
                o.z = f2bf(acc[im][in][2] * s); o.w = f2bf(acc[im][in][3] * s);
                *(ushort4*)(dst + ((size_t)(bb * NHEAD + h) * N_SEQ + ns) * DHEAD + d) = o;
            }
        }
    }
}

// ---------------- landmark pooling ------------------------------------------------
__global__ __launch_bounds__(64) void pool_kernel(
    const u16* __restrict__ Q, const u16* __restrict__ K,
    float* __restrict__ QL, float* __restrict__ KL,
    u16* __restrict__ QLb, u16* __restrict__ KLb)
{
    int m = blockIdx.x, bh = blockIdx.y, d = threadIdx.x;
    size_t base = ((size_t)bh * N_SEQ + m * 32) * DHEAD + d;
    float sq = 0.f, sk = 0.f;
#pragma unroll
    for (int i = 0; i < 32; ++i) {
        sq += bf2f(Q[base + i * DHEAD]);
        sk += bf2f(K[base + i * DHEAD]);
    }
    size_t ob = ((size_t)bh * NLAND + m) * DHEAD + d;
    sq *= (1.f / 32.f); sk *= (1.f / 32.f);
    QL[ob] = sq; KL[ob] = sk;
    QLb[ob] = f2bf(sq); KLb[ob] = f2bf(sk);
}

// ---------------- attn2 = softmax(q_l @ k_l^T) ------------------------------------
__global__ __launch_bounds__(256) void attn2_kernel(
    const float* __restrict__ QL, const float* __restrict__ KL, float* __restrict__ A2)
{
    __shared__ float qrow[64];
    __shared__ float red[256];
    int i = blockIdx.x, bh = blockIdx.y, j = threadIdx.x;
    if (j < 64) qrow[j] = QL[((size_t)bh * NLAND + i) * DHEAD + j];
    __syncthreads();
    const float* kr = KL + ((size_t)bh * NLAND + j) * DHEAD;
    float lg = 0.f;
#pragma unroll
    for (int d = 0; d < 64; ++d) lg += qrow[d] * kr[d];
    red[j] = lg; __syncthreads();
    for (int s = 128; s > 0; s >>= 1) { if (j < s) red[j] = fmaxf(red[j], red[j + s]); __syncthreads(); }
    float mx = red[0]; __syncthreads();
    float p = __expf(lg - mx);
    red[j] = p; __syncthreads();
    for (int s = 128; s > 0; s >>= 1) { if (j < s) red[j] += red[j + s]; __syncthreads(); }
    float sum = red[0];
    A2[((size_t)bh * NLAND + i) * NLAND + j] = p / sum;
}

__global__ void init_scal_kernel(unsigned* scal, unsigned* bars)
{
    if (threadIdx.x < 2) scal[threadIdx.x] = 0u;
    for (int i = threadIdx.x; i < 1024; i += 256) bars[i] = 0u;
}

__global__ __launch_bounds__(256) void absmax_kernel(const float* __restrict__ A2, unsigned* scal)
{
    __shared__ float red[256];
    int bh = blockIdx.x, t = threadIdx.x;
    const float* Ab = A2 + (size_t)bh * 65536;
    float cs = 0.f, rs = 0.f;
    for (int j = 0; j < 256; ++j) cs += fabsf(Ab[t * 256 + j]);
    for (int i = 0; i < 256; ++i) rs += fabsf(Ab[i * 256 + t]);
    red[t] = cs; __syncthreads();
    for (int s = 128; s > 0; s >>= 1) { if (t < s) red[t] = fmaxf(red[t], red[t + s]); __syncthreads(); }
    if (t == 0) atomicMax(scal + 0, __float_as_uint(red[0]));
    __syncthreads();
    red[t] = rs; __syncthreads();
    for (int s = 128; s > 0; s >>= 1) { if (t < s) red[t] = fmaxf(red[t], red[t + s]); __syncthreads(); }
    if (t == 0) atomicMax(scal + 1, __float_as_uint(red[0]));
}

// z0 + A2->bf16 in one pass
__global__ __launch_bounds__(256) void z0_kernel(
    const float* __restrict__ A2, const unsigned* __restrict__ scal,
    u16* __restrict__ zb, u16* __restrict__ zbT, u16* __restrict__ A2b)
{
    float inv = 1.f / (__uint_as_float(scal[0]) * __uint_as_float(scal[1]));
    size_t idx = (size_t)blockIdx.x * 256 + threadIdx.x;
    size_t bh = idx >> 16;
    int r = (int)(idx & 65535);
    int i = r >> 8, j = r & 255;
    float a = A2[idx];
    zb[idx]  = f2bf(A2[(bh << 16) + (size_t)j * 256 + i] * inv);
    zbT[idx] = f2bf(a * inv);
    A2b[idx] = f2bf(a);
}

// ---------------- pinv: one 64x64x256 tile, round-6 LDS-staged bgemm body ---------
__device__ __forceinline__ void bgemm_tile(
    u16* As, u16* Bs,
    const u16* __restrict__ A, const u16* __restrict__ BT,
    u16* __restrict__ Cn, u16* __restrict__ Ct, const u16* __restrict__ E,
    int N, long sB, long sCn, long sCt,
    float sc, float alpha, float beta, int wn, int wt,
    int i0, int j0, int bh)
{
    const int tid = threadIdx.x;
    const int wave = tid >> 6, lane = tid & 63;
    const int wm = (wave >> 1) * 32, wnn = (wave & 1) * 32;
    const u16* Ab = A + (size_t)bh * 65536;
    const u16* Bb = BT + (size_t)bh * sB;
    const int srow = tid >> 2, scol = (tid & 3) * 16;
    const int lm = lane & 15, lq = lane >> 4;
    fx4 acc[2][2];
#pragma unroll
    for (int a = 0; a < 2; ++a)
#pragma unroll
        for (int b = 0; b < 2; ++b) acc[a][b] = (fx4){0.f, 0.f, 0.f, 0.f};

    for (int k0 = 0; k0 < 256; k0 += 64) {
        uint4 a0 = *(const uint4*)(Ab + (size_t)(i0 + srow) * 256 + k0 + scol);
        uint4 a1 = *(const uint4*)(Ab + (size_t)(i0 + srow) * 256 + k0 + scol + 8);
        uint4 b0 = *(const uint4*)(Bb + (size_t)(j0 + srow) * 256 + k0 + scol);
        uint4 b1 = *(const uint4*)(Bb + (size_t)(j0 + srow) * 256 + k0 + scol + 8);
        __syncthreads();
        *(uint4*)(As + srow * 72 + scol) = a0;
        *(uint4*)(As + srow * 72 + scol + 8) = a1;
        *(uint4*)(Bs + srow * 72 + scol) = b0;
        *(uint4*)(Bs + srow * 72 + scol + 8) = b1;
        __syncthreads();
#pragma unroll
        for (int ks = 0; ks < 2; ++ks) {
            bh8 lf[2], rf[2];
#pragma unroll
            for (int im = 0; im < 2; ++im)
                lf[im] = *(const bh8*)(As + (wm + im * 16 + lm) * 72 + ks * 32 + lq * 8);
#pragma unroll
            for (int in = 0; in < 2; ++in)
                rf[in] = *(const bh8*)(Bs + (wnn + in * 16 + lm) * 72 + ks * 32 + lq * 8);
#pragma unroll
            for (int im = 0; im < 2; ++im)
#pragma unroll
                for (int in = 0; in < 2; ++in)
                    acc[im][in] = mfma16(lf[im], rf[in], acc[im][in]);
        }
    }
#pragma unroll
    for (int im = 0; im < 2; ++im) {
#pragma unroll
        for (int in = 0; in < 2; ++in) {
            int n = j0 + wnn + in * 16 + lm;
            int m0 = i0 + wm + im * 16 + (lq << 2);
            float c[4];
#pragma unroll
            for (int r = 0; r < 4; ++r) {
                int m = m0 + r;
                float x = beta * acc[im][in][r];
                if (alpha != 0.f)
                    x += alpha * bf2f(E[(size_t)bh * 65536 + (size_t)m * 256 + n]);
                if (m == n) x += sc;
                c[r] = x;
            }
            if (wn) {
#pragma unroll
                for (int r = 0; r < 4; ++r)
                    Cn[(size_t)bh * sCn + (size_t)(m0 + r) * N + n] = f2bf(c[r]);
            }
            if (wt) {
                ushort4 o;
                o.x = f2bf(c[0]); o.y = f2bf(c[1]); o.z = f2bf(c[2]); o.w = f2bf(c[3]);
                *(ushort4*)(Ct + (size_t)bh * sCt + (size_t)n * 256 + m0) = o;
            }
        }
    }
}

// per-bh barrier: 8 blocks. Single RMW arrive; last arriver release-stores the
// monotonic flag; others spin on an RMW-free atomic load with s_sleep backoff.
__device__ __forceinline__ void bhsync(unsigned* ctr, unsigned* flg, unsigned& ph)
{
    ++ph;
    __syncthreads();
    if (threadIdx.x == 0) {
        unsigned old = __hip_atomic_fetch_add(ctr, 1u, __ATOMIC_ACQ_REL,
                                              __HIP_MEMORY_SCOPE_AGENT);
        if (old == ph * 8u - 1u) {
            __hip_atomic_store(flg, ph, __ATOMIC_RELEASE, __HIP_MEMORY_SCOPE_AGENT);
        } else {
            while (__hip_atomic_load(flg, __ATOMIC_ACQUIRE,
                                     __HIP_MEMORY_SCOPE_AGENT) < ph)
                __builtin_amdgcn_s_sleep(8);
        }
    }
    __syncthreads();
}

// persistent pinv chain: 256 blocks = 32 bh-groups x 8; each block does 2 of the
// 16 64x64 tiles per step; per-bh barriers between the 24 dependent GEMM steps;
// final WMT GEMM on the first 4 blocks of each group (same-group ordering).
__global__ __launch_bounds__(256, 2) void pinv_sync_kernel(
    const u16* __restrict__ A2b,
    u16* zA, u16* zAT, u16* zB, u16* zBT,
    u16* xz, u16* xzT, u16* t2T, u16* t3T,
    const u16* __restrict__ W3VT, u16* __restrict__ WMT,
    unsigned* bars)
{
    __shared__ u16 As[64 * 72];
    __shared__ u16 Bs[64 * 72];
    const int bid = blockIdx.x;
    const int bh = bid >> 3;
    const int tt0 = (bid & 7) * 2;
    unsigned* ctr = bars + bh * 32;
    unsigned* flg = bars + bh * 32 + 16;
    unsigned phase = 0;
    u16 *z = zA, *zT = zAT, *zn = zB, *znT = zBT;
#pragma unroll 1
    for (int it = 0; it < 6; ++it) {
#pragma unroll 1
        for (int t = 0; t < 2; ++t) {
            const int tt = tt0 + t, i0 = (tt >> 2) * 64, j0 = (tt & 3) * 64;
            bgemm_tile(As, Bs, A2b, zT, xz, xzT, A2b, 256, 65536, 65536, 65536,
                       0.f, 0.f, 1.f, 1, 1, i0, j0, bh);
        }
        bhsync(ctr, flg, phase);
#pragma unroll 1
        for (int t = 0; t < 2; ++t) {
            const int tt = tt0 + t, i0 = (tt >> 2) * 64, j0 = (tt & 3) * 64;
            bgemm_tile(As, Bs, xz, xzT, xz, t2T, xz, 256, 65536, 65536, 65536,
                       15.f, -7.f, 1.f, 0, 1, i0, j0, bh);
        }
        bhsync(ctr, flg, phase);
#pragma unroll 1
        for (int t = 0; t < 2; ++t) {
            const int tt = tt0 + t, i0 = (tt >> 2) * 64, j0 = (tt & 3) * 64;
            bgemm_tile(As, Bs, xz, t2T, xz, t3T, xz, 256, 65536, 65536, 65536,
                       13.f, 0.f, -1.f, 0, 1, i0, j0, bh);
        }
        bhsync(ctr, flg, phase);
#pragma unroll 1
        for (int t = 0; t < 2; ++t) {
            const int tt = tt0 + t, i0 = (tt >> 2) * 64, j0 = (tt & 3) * 64;
            bgemm_tile(As, Bs, z, t3T, zn, znT, xz, 256, 65536, 65536, 65536,
                       0.f, 0.f, 0.25f, 1, 1, i0, j0, bh);
        }
        bhsync(ctr, flg, phase);
        u16* tp;
        tp = z;  z = zn;   zn = tp;
        tp = zT; zT = znT; znT = tp;
    }
    // final WMT = (z @ W3V)^T: first 4 blocks of THIS bh's group (same barrier
    // domain as the z-writers, so the last bhsync orders it).
    if ((bid & 7) < 4) {
        const int fi = (bid & 7) * 64;
        bgemm_tile(As, Bs, z, W3VT, WMT, WMT, A2b, 64, 16384, 16384, 16384,
                   0.f, 0.f, 1.f, 0, 1, fi, 0, bh);
    }
}

// ---------------- attn3@v flash MFMA: fetch-once, 4 waves share K/VT chunks -------
__global__ __launch_bounds__(256, 2) void attn3v_mfma_kernel(
    const u16* __restrict__ QLb, const u16* __restrict__ Kb,
    const u16* __restrict__ VTb, u16* __restrict__ PO, float* __restrict__ ML)
{
    __shared__ u16 Ks[64 * 72];
    __shared__ u16 Vs[64 * 72];
    __shared__ u16 Pw[4][64 * 72];
    const int tid = threadIdx.x;
    const int wave = tid >> 6, lane = tid & 63;
    const int q = lane >> 4, l15 = lane & 15;
    const int part = blockIdx.x;
    const int bh = blockIdx.y;
    const int nbase = part * 512;
    const int srow = tid >> 2, scol = (tid & 3) * 16;
    u16* Pp = Pw[wave];
    bh8 qf[4][2];
#pragma unroll
    for (int mt = 0; mt < 4; ++mt)
#pragma unroll
        for (int ks = 0; ks < 2; ++ks)
            qf[mt][ks] = *(const bh8*)(QLb + ((size_t)bh * NLAND + wave * 64 + mt * 16 + l15) * DHEAD + ks * 32 + q * 8);
    float M[4] = {-1e30f, -1e30f, -1e30f, -1e30f};
    float L[4] = {0.f, 0.f, 0.f, 0.f};
    fx4 O[4][4];
#pragma unroll
    for (int mt = 0; mt < 4; ++mt)
#pragma unroll
        for (int dt = 0; dt < 4; ++dt) O[mt][dt] = (fx4){0.f, 0.f, 0.f, 0.f};

    for (int c = 0; c < 8; ++c) {
        const int n0 = nbase + c * 64;
        uint4 k0v = *(const uint4*)(Kb + ((size_t)bh * N_SEQ + n0 + srow) * DHEAD + scol);
        uint4 k1v = *(const uint4*)(Kb + ((size_t)bh * N_SEQ + n0 + srow) * DHEAD + scol + 8);
        uint4 v0v = *(const uint4*)(VTb + ((size_t)bh * DHEAD + srow) * N_SEQ + n0 + scol);
        uint4 v1v = *(const uint4*)(VTb + ((size_t)bh * DHEAD + srow) * N_SEQ + n0 + scol + 8);
        __syncthreads();
        *(uint4*)(Ks + srow * 72 + scol) = k0v;
        *(uint4*)(Ks + srow * 72 + scol + 8) = k1v;
        *(uint4*)(Vs + srow * 72 + scol) = v0v;
        *(uint4*)(Vs + srow * 72 + scol + 8) = v1v;
        __syncthreads();
        fx4 S[4][4];   // [nt][mt]
#pragma unroll
        for (int nt = 0; nt < 4; ++nt)
#pragma unroll
            for (int mt = 0; mt < 4; ++mt) S[nt][mt] = (fx4){0.f, 0.f, 0.f, 0.f};
#pragma unroll
        for (int ks = 0; ks < 2; ++ks) {
            bh8 kf[4];
#pragma unroll
            for (int nt = 0; nt < 4; ++nt)
                kf[nt] = *(const bh8*)(Ks + (nt * 16 + l15) * 72 + ks * 32 + q * 8);
#pragma unroll
            for (int nt = 0; nt < 4; ++nt)
#pragma unroll
                for (int mt = 0; mt < 4; ++mt)
                    S[nt][mt] = mfma16(kf[nt], qf[mt][ks], S[nt][mt]);   // D[n][m]
        }
#pragma unroll
        for (int mt = 0; mt < 4; ++mt) {
            float cm = -1e30f;
#pragma unroll
            for (int nt = 0; nt < 4; ++nt)
#pragma unroll
                for (int r = 0; r < 4; ++r) cm = fmaxf(cm, S[nt][mt][r]);
            cm = fmaxf(cm, __shfl_xor(cm, 16));
            cm = fmaxf(cm, __shfl_xor(cm, 32));
            float Mn = fmaxf(M[mt], cm);
            float al = __expf(M[mt] - Mn);
            M[mt] = Mn;
            L[mt] *= al;
#pragma unroll
            for (int dt = 0; dt < 4; ++dt) {
                O[mt][dt][0] *= al; O[mt][dt][1] *= al;
                O[mt][dt][2] *= al; O[mt][dt][3] *= al;
            }
            float ps = 0.f;
#pragma unroll
            for (int nt = 0; nt < 4; ++nt)
#pragma unroll
                for (int r = 0; r < 4; ++r) {
                    float p = __expf(S[nt][mt][r] - Mn);
                    ps += p;
                    Pp[(mt * 16 + l15) * 72 + nt * 16 + q * 4 + r] = f2bf(p);
                }
            ps += __shfl_xor(ps, 16);
            ps += __shfl_xor(ps, 32);
            L[mt] += ps;
        }
#pragma unroll
        for (int ks = 0; ks < 2; ++ks) {
            bh8 pf[4];
#pragma unroll
            for (int mt = 0; mt < 4; ++mt)
                pf[mt] = *(const bh8*)(Pp + (mt * 16 + l15) * 72 + ks * 32 + q * 8);
#pragma unroll
            for (int dt = 0; dt < 4; ++dt) {
                bh8 vf = *(const bh8*)(Vs + (dt * 16 + l15) * 72 + ks * 32 + q * 8);
#pragma unroll
                for (int mt = 0; mt < 4; ++mt)
                    O[mt][dt] = mfma16(vf, pf[mt], O[mt][dt]);   // D[d][m]
            }
        }
    }
#pragma unroll
    for (int mt = 0; mt < 4; ++mt) {
        size_t mrow = (size_t)(bh * 16 + part) * NLAND + wave * 64 + mt * 16 + l15;
#pragma unroll
        for (int dt = 0; dt < 4; ++dt) {
            ushort4 o;
            o.x = f2bf(O[mt][dt][0]); o.y = f2bf(O[mt][dt][1]);
            o.z = f2bf(O[mt][dt][2]); o.w = f2bf(O[mt][dt][3]);
            *(ushort4*)(PO + mrow * DHEAD + dt * 16 + q * 4) = o;
        }
        if (q == 0) { ML[mrow * 2] = M[mt]; ML[mrow * 2 + 1] = L[mt]; }
    }
}

__global__ __launch_bounds__(64) void combine_kernel(
    const u16* __restrict__ PO, const float* __restrict__ ML, u16* __restrict__ W3VT)
{
    int m = blockIdx.x, bh = blockIdx.y, d = threadIdx.x;
    float Mg = -1e30f;
#pragma unroll
    for (int p = 0; p < 16; ++p)
        Mg = fmaxf(Mg, ML[((size_t)(bh * 16 + p) * NLAND + m) * 2]);
    float denom = 0.f, o = 0.f;
#pragma unroll
    for (int p = 0; p < 16; ++p) {
        size_t ix = (size_t)(bh * 16 + p) * NLAND + m;
        float w = __expf(ML[ix * 2] - Mg);
        denom += ML[ix * 2 + 1] * w;
        o += bf2f(PO[ix * DHEAD + d]) * w;
    }
    W3VT[((size_t)bh * DHEAD + d) * NLAND + m] = f2bf(o / denom);
}

// ---------------- depthwise conv residual: RT[bh*64+d][n] from VT -----------------
__global__ __launch_bounds__(256) void conv_kernel(
    const u16* __restrict__ VT, const u16* __restrict__ CW, u16* __restrict__ RT)
{
    __shared__ float vl[2080];
    __shared__ float cws[33];
    const int tid = threadIdx.x;
    const int c0 = blockIdx.x * 2048;
    const int row = blockIdx.y;
    const int h = (row >> 6) & 7;
    const u16* src = VT + (size_t)row * N_SEQ;
    for (int i = tid; i < 2080; i += 256) {
        int gn = c0 - 16 + i;
        vl[i] = (gn >= 0 && gn < N_SEQ) ? bf2f(src[gn]) : 0.f;
    }
    if (tid < 33) cws[tid] = bf2f(CW[h * 33 + tid]);
    __syncthreads();
    float v[40];
    const int base = tid * 8;
#pragma unroll
    for (int i = 0; i < 40; ++i) v[i] = vl[base + i];
    float s[8];
#pragma unroll
    for (int j = 0; j < 8; ++j) {
        float a = 0.f;
#pragma unroll
        for (int t = 0; t < 33; ++t) a += cws[t] * v[j + t];
        s[j] = a;
    }
    u16* dst = RT + (size_t)row * N_SEQ + c0 + base;
    ushort4 o0, o1;
    o0.x = f2bf(s[0]); o0.y = f2bf(s[1]); o0.z = f2bf(s[2]); o0.w = f2bf(s[3]);
    o1.x = f2bf(s[4]); o1.y = f2bf(s[5]); o1.z = f2bf(s[6]); o1.w = f2bf(s[7]);
    *(ushort4*)dst = o0;
    *(ushort4*)(dst + 4) = o1;
}

// ---------------- outheads: attn1 softmax + @WM + RT residual, 64 n/block ---------
__global__ __launch_bounds__(256) void outheads_mfma_kernel(
    const u16* __restrict__ Qb, const u16* __restrict__ KLb,
    const u16* __restrict__ WMT, const u16* __restrict__ RT,
    u16* __restrict__ Y)
{
    __shared__ u16 Pl[64 * 264];
    __shared__ float wmax[4][64];
    __shared__ float wsum[4][64];
    const int tid = threadIdx.x;
    const int wave = tid >> 6, lane = tid & 63;
    const int q = lane >> 4, l15 = lane & 15;
    const int bh = blockIdx.y;
    const int bb = bh >> 3, h = bh & 7;
    const int n0 = blockIdx.x * 64;
    fx4 S[4][4];
#pragma unroll
    for (int a = 0; a < 4; ++a)
#pragma unroll
        for (int b = 0; b < 4; ++b) S[a][b] = (fx4){0.f, 0.f, 0.f, 0.f};
#pragma unroll
    for (int ks = 0; ks < 2; ++ks) {
        bh8 qfr[4];
#pragma unroll
        for (int nt = 0; nt < 4; ++nt)
            qfr[nt] = *(const bh8*)(Qb + ((size_t)bh * N_SEQ + n0 + nt * 16 + l15) * DHEAD + ks * 32 + q * 8);
#pragma unroll
        for (int mt = 0; mt < 4; ++mt) {
            bh8 kf = *(const bh8*)(KLb + ((size_t)bh * NLAND + wave * 64 + mt * 16 + l15) * DHEAD + ks * 32 + q * 8);
#pragma unroll
            for (int nt = 0; nt < 4; ++nt)
                S[nt][mt] = mfma16(qfr[nt], kf, S[nt][mt]);
        }
    }
#pragma unroll
    for (int nt = 0; nt < 4; ++nt)
#pragma unroll
        for (int r = 0; r < 4; ++r) {
            float pm = fmaxf(fmaxf(S[nt][0][r], S[nt][1][r]), fmaxf(S[nt][2][r], S[nt][3][r]));
            pm = fmaxf(pm, __shfl_xor(pm, 1));
            pm = fmaxf(pm, __shfl_xor(pm, 2));
            pm = fmaxf(pm, __shfl_xor(pm, 4));
            pm = fmaxf(pm, __shfl_xor(pm, 8));
            if (l15 == 0) wmax[wave][nt * 16 + q * 4 + r] = pm;
        }
    __syncthreads();
#pragma unroll
    for (int nt = 0; nt < 4; ++nt)
#pragma unroll
        for (int r = 0; r < 4; ++r) {
            int nl = nt * 16 + q * 4 + r;
            float Mf = fmaxf(fmaxf(wmax[0][nl], wmax[1][nl]), fmaxf(wmax[2][nl], wmax[3][nl]));
            float ps = 0.f;
#pragma unroll
            for (int mt = 0; mt < 4; ++mt) {
                float p = __expf(S[nt][mt][r] - Mf);
                ps += p;
                Pl[nl * 264 + wave * 64 + mt * 16 + l15] = f2bf(p);
            }
            ps += __shfl_xor(ps, 1);
            ps += __shfl_xor(ps, 2);
            ps += __shfl_xor(ps, 4);
            ps += __shfl_xor(ps, 8);
            if (l15 == 0) wsum[wave][nl] = ps;
        }
    __syncthreads();
    fx4 O[4];
#pragma unroll
    for (int nt = 0; nt < 4; ++nt) O[nt] = (fx4){0.f, 0.f, 0.f, 0.f};
#pragma unroll
    for (int ks = 0; ks < 8; ++ks) {
        bh8 af = *(const bh8*)(WMT + ((size_t)bh * DHEAD + wave * 16 + l15) * NLAND + ks * 32 + q * 8);
#pragma unroll
        for (int nt = 0; nt < 4; ++nt) {
            bh8 pf = *(const bh8*)(Pl + (size_t)(nt * 16 + l15) * 264 + ks * 32 + q * 8);
            O[nt] = mfma16(af, pf, O[nt]);
        }
    }
#pragma unroll
    for (int nt = 0; nt < 4; ++nt) {
        int nl = nt * 16 + l15;
        float inv = 1.f / (wsum[0][nl] + wsum[1][nl] + wsum[2][nl] + wsum[3][nl]);
        int d0 = wave * 16 + (q << 2);
        fx4 v = O[nt];
#pragma unroll
        for (int c = 0; c < 4; ++c)
            v[c] = v[c] * inv + bf2f(RT[(size_t)(bh * DHEAD + d0 + c) * N_SEQ + n0 + nl]);
        ushort4 o;
        o.x = f2bf(v[0]); o.y = f2bf(v[1]); o.z = f2bf(v[2]); o.w = f2bf(v[3]);
        *(ushort4*)(Y + ((size_t)bb * N_SEQ + n0 + nl) * DMODEL + h * DHEAD + d0) = o;
    }
}

// ---------------- final MFMA GEMM (async staging + swizzle) -----------------------
__global__ __launch_bounds__(256) void final_mfma_kernel(
    const u16* __restrict__ Y, const u16* __restrict__ WT,
    const u16* __restrict__ Bias, const u16* __restrict__ X, void* __restrict__ Out,
    const unsigned* __restrict__ flag)
{
    __shared__ u16 Xs[128 * 64];
    __shared__ u16 Ws[128 * 64];
    const int tid = threadIdx.x;
    const int wave = tid >> 6, lane = tid & 63;
    const int wrow = (wave >> 1) * 64, wcol = (wave & 1) * 64;
    const int i0 = blockIdx.x * 128;
    const int j0 = blockIdx.y * 128;
    const int la = lane >> 3, lb = lane & 7;
    const int lm = lane & 15, lq = lane >> 4;
    const int sw = lm & 7;
    const int sc = (lb ^ la) * 8;
    const unsigned isf32 = flag[0];
    fx4 acc[4][4];
#pragma unroll
    for (int a = 0; a < 4; ++a)
#pragma unroll
        for (int b = 0; b < 4; ++b) acc[a][b] = (fx4){0.f, 0.f, 0.f, 0.f};

    for (int k0 = 0; k0 < DMODEL; k0 += 64) {
        __syncthreads();
#pragma unroll
        for (int jj = 0; jj < 4; ++jj) {
            int rb = wave * 32 + jj * 8;
            gload16(Xs + rb * 64, Y + (size_t)(i0 + rb + la) * DMODEL + k0 + sc);
            gload16(Ws + rb * 64, WT + (size_t)(j0 + rb + la) * DMODEL + k0 + sc);
        }
        __syncthreads();
#pragma unroll
        for (int ks = 0; ks < 2; ++ks) {
            const int po = ((ks * 4 + lq) ^ sw) * 8;
            bh8 xf[4], wf[4];
#pragma unroll
            for (int im = 0; im < 4; ++im)
                xf[im] = *(const bh8*)(Xs + (wrow + im * 16 + lm) * 64 + po);
#pragma unroll
            for (int in = 0; in < 4; ++in)
                wf[in] = *(const bh8*)(Ws + (wcol + in * 16 + lm) * 64 + po);
#pragma unroll
            for (int im = 0; im < 4; ++im)
#pragma unroll
                for (int in = 0; in < 4; ++in)
                    acc[im][in] = mfma16(wf[in], xf[im], acc[im][in]);
        }
    }
#pragma unroll
    for (int im = 0; im < 4; ++im) {
        int m = i0 + wrow + im * 16 + lm;
#pragma unroll
        for (int in = 0; in < 4; ++in) {
            int nn = j0 + wcol + in * 16 + (lq << 2);
            ushort4 b4 = *(const ushort4*)(Bias + nn);
            ushort4 x4 = *(const ushort4*)(X + (size_t)m * DMODEL + nn);
            float c0 = acc[im][in][0] + bf2f(b4.x) + bf2f(x4.x);
            float c1 = acc[im][in][1] + bf2f(b4.y) + bf2f(x4.y);
            float c2 = acc[im][in][2] + bf2f(b4.z) + bf2f(x4.z);
            float c3 = acc[im][in][3] + bf2f(b4.w) + bf2f(x4.w);
            if (isf32) {
                *(float4*)((float*)Out + (size_t)m * DMODEL + nn) = make_float4(c0, c1, c2, c3);
            } else {
                ushort4 o;
                o.x = f2bf(c0); o.y = f2bf(c1); o.z = f2bf(c2); o.w = f2bf(c3);
                *(ushort4*)((u16*)Out + (size_t)m * DMODEL + nn) = o;
            }
        }
    }
}

extern "C" void kernel_launch(void* const* d_in, const int* in_sizes, int n_in,
                              void* d_out, int out_size, void* d_ws, size_t ws_size,
                              hipStream_t stream)
{
    (void)in_sizes; (void)n_in; (void)out_size; (void)ws_size;
    char* ws = (char*)d_ws;
    u16*   Xc    = (u16*)(ws + 0);            // 33,554,432
    u16*   WqkvT = (u16*)(ws + 33554432);     //  1,572,864
    u16*   WoutT = (u16*)(ws + 35127296);     //    524,288
    u16*   Boutc = (u16*)(ws + 35651584);     //      1,024
    u16*   CWc   = (u16*)(ws + 35652608);     //      1,024
    u16*   Qb    = (u16*)(ws + 35653632);     // 33,554,432  [bh][n][d]
    u16*   Kb    = (u16*)(ws + 69208064);     // 33,554,432  [bh][n][d]; dead after attn3v
    u16*   RT    = (u16*)(ws + 69208064);     // overlays Kb post-attn3v
    u16*   VTb   = (u16*)(ws + 102762496);    // 33,554,432  [bh][d][n]
    float* QL    = (float*)(ws + 136316928);  //  2,097,152
    float* KL    = (float*)(ws + 138414080);  //  2,097,152
    u16*   QLb   = (u16*)(ws + 140511232);    //  1,048,576
    u16*   KLb   = (u16*)(ws + 141559808);    //  1,048,576
    u16*   W3VT  = (u16*)(ws + 142608384);    //  1,048,576
    u16*   WMT   = (u16*)(ws + 143656960);    //  1,048,576
    u16*   A2b   = (u16*)(ws + 144705536);    //  4,194,304
    u16*   zA    = (u16*)(ws + 148899840);    //  4,194,304
    u16*   zAT   = (u16*)(ws + 153094144);    //  4,194,304
    float* A2    = (float*)(ws + 157288448);  // overlay region
    u16*   PO    = (u16*)(ws + 157288448);
    float* ML    = (float*)(ws + 174065664);
    u16*   zB    = (u16*)(ws + 165677056);
    u16*   zBT   = (u16*)(ws + 169871360);
    u16*   xz    = (u16*)(ws + 174065664);    // overlays ML (dead after combine)
    u16*   xzT   = (u16*)(ws + 178259968);
    u16*   t2T   = (u16*)(ws + 182454272);
    u16*   t3T   = (u16*)(ws + 186648576);
    u16*   Yb    = (u16*)(ws + 157288448);
    unsigned* SCAL = (unsigned*)(ws + 190842880);
    unsigned* BARS = (unsigned*)(ws + 190846976);   // 32 groups x 32 u32 (128B apart)

    detect_kernel<<<1, 256, 0, stream>>>((const u16*)d_in[0], SCAL + 2);
    convert4_kernel<<<16384, 256, 0, stream>>>(d_in[0], Xc, 4194304, SCAL + 2);
    wtrans_kernel<<<3072, 256, 0, stream>>>(d_in[1], WqkvT, 512, 1536, SCAL + 2);
    wtrans_kernel<<<1024, 256, 0, stream>>>(d_in[2], WoutT, 512, 512, SCAL + 2);
    convert4_kernel<<<1, 256, 0, stream>>>(d_in[3], Boutc, 128, SCAL + 2);
    convert4_kernel<<<1, 256, 0, stream>>>(d_in[4], CWc, 66, SCAL + 2);

    qkv_mfma_kernel<<<dim3(256, 12), 256, 0, stream>>>(Xc, WqkvT, Qb, Kb, VTb);
    pool_kernel<<<dim3(256, BH), 64, 0, stream>>>(Qb, Kb, QL, KL, QLb, KLb);
    attn2_kernel<<<dim3(256, BH), 256, 0, stream>>>(QL, KL, A2);
    init_scal_kernel<<<1, 256, 0, stream>>>(SCAL, BARS);
    absmax_kernel<<<32, 256, 0, stream>>>(A2, SCAL);
    z0_kernel<<<8192, 256, 0, stream>>>(A2, SCAL, zA, zAT, A2b);

    // flash attn3@v (fetch-once), combine, conv into Kb slot
    attn3v_mfma_kernel<<<dim3(16, BH), 256, 0, stream>>>(QLb, Kb, VTb, PO, ML);
    combine_kernel<<<dim3(256, BH), 64, 0, stream>>>(PO, ML, W3VT);
    conv_kernel<<<dim3(4, 2048), 256, 0, stream>>>(VTb, CWc, RT);

    // whole pinv chain + final WMT GEMM: ONE persistent launch, per-bh barriers
    pinv_sync_kernel<<<256, 256, 0, stream>>>(
        A2b, zA, zAT, zB, zBT, xz, xzT, t2T, t3T, W3VT, WMT, BARS);

    outheads_mfma_kernel<<<dim3(128, BH), 256, 0, stream>>>(Qb, KLb, WMT, RT, Yb);
    final_mfma_kernel<<<dim3(256, 4), 256, 0, stream>>>(Yb, WoutT, Boutc, Xc, d_out, SCAL + 2);
}

// Round 7
// 1004.177 us; speedup vs baseline: 1.6598x; 1.0662x over previous
//
#include <hip/hip_runtime.h>

// Nystrom attention, MI355X round 13: back to multi-launch pinv (persistent
// fusion refuted twice: barrier acquire = L2 invalidate, 553 us vs ~200 us for
// launches). New: (a) Newton-Schulz restructured with carried u=x@z so the two
// tail GEMMs (z'=0.25 z@s3, u'=0.25 u@s3) batch into ONE pair launch ->
// 20 launches instead of 25; (b) bgemm register-prefetches all 4 K-chunks
// (one exposed latency instead of four). Everything else = proven round-6/9.
// b=4, n=8192, dim=512, h=8, dh=64, m=256 landmarks, pinv iters=6, conv k=33.

#define N_SEQ 8192
#define DMODEL 512
#define NHEAD 8
#define DHEAD 64
#define NLAND 256
#define BH 32

typedef unsigned short u16;
typedef __attribute__((ext_vector_type(8))) short bh8;
typedef __attribute__((ext_vector_type(4))) float fx4;

__device__ __forceinline__ float bf2f(u16 u) { return __uint_as_float(((unsigned)u) << 16); }
__device__ __forceinline__ u16 f2bf(float f) {
    unsigned x = __float_as_uint(f);
    return (u16)((x + 0x7fffu + ((x >> 16) & 1u)) >> 16);
}
__device__ __forceinline__ fx4 mfma16(bh8 a, bh8 b, fx4 c) {
    return __builtin_amdgcn_mfma_f32_16x16x32_bf16(a, b, c, 0, 0, 0);
}
__device__ __forceinline__ void gload16(u16* lds, const u16* g) {
    __builtin_amdgcn_global_load_lds(
        (const __attribute__((address_space(1))) unsigned int*)g,
        (__attribute__((address_space(3))) unsigned int*)lds, 16, 0, 0);
}

// ---------------- dtype probe -----------------------------------------------------
__global__ void detect_kernel(const u16* __restrict__ X, unsigned* flag_out)
{
    __shared__ int cnt;
    if (threadIdx.x == 0) cnt = 0;
    __syncthreads();
    u16 u = X[threadIdx.x * 2];
    int e = (u >> 7) & 0xFF;
    int insane = (u != 0) && (e < 90 || e > 140);
    atomicAdd(&cnt, insane);
    __syncthreads();
    if (threadIdx.x == 0) flag_out[0] = (cnt > 64) ? 1u : 0u;
}

// vectorized convert: n4 = elements/4 (all our sizes are /4)
__global__ __launch_bounds__(256) void convert4_kernel(
    const void* __restrict__ in, u16* __restrict__ out, int n4, const unsigned* __restrict__ flag)
{
    int i = blockIdx.x * 256 + threadIdx.x;
    if (i >= n4) return;
    if (flag[0]) {
        float4 v = ((const float4*)in)[i];
        ushort4 o;
        o.x = f2bf(v.x); o.y = f2bf(v.y); o.z = f2bf(v.z); o.w = f2bf(v.w);
        ((ushort4*)out)[i] = o;
    } else {
        ((ushort4*)out)[i] = ((const ushort4*)in)[i];
    }
}

__global__ __launch_bounds__(256) void wtrans_kernel(
    const void* __restrict__ in, u16* __restrict__ out, int rows, int cols,
    const unsigned* __restrict__ flag)
{
    int idx = blockIdx.x * 256 + threadIdx.x;
    if (idx >= rows * cols) return;
    int r = idx / cols, c = idx % cols;
    float v = flag[0] ? ((const float*)in)[idx] : bf2f(((const u16*)in)[idx]);
    out[(size_t)c * rows + r] = f2bf(v);
}

// ---------------- QKV MFMA GEMM (async staging + xor swizzle) ---------------------
__global__ __launch_bounds__(256) void qkv_mfma_kernel(
    const u16* __restrict__ X, const u16* __restrict__ WT,
    u16* __restrict__ Q, u16* __restrict__ K, u16* __restrict__ VT)
{
    __shared__ u16 Xs[128 * 64];
    __shared__ u16 Ws[128 * 64];
    const int tid = threadIdx.x;
    const int wave = tid >> 6, lane = tid & 63;
    const int wrow = (wave >> 1) * 64, wcol = (wave & 1) * 64;
    const int i0 = blockIdx.x * 128;
    const int j0 = blockIdx.y * 128;
    const int la = lane >> 3, lb = lane & 7;
    const int lm = lane & 15, lq = lane >> 4;
    const int sw = lm & 7;
    const int sc = (lb ^ la) * 8;
    fx4 acc[4][4];
#pragma unroll
    for (int a = 0; a < 4; ++a)
#pragma unroll
        for (int b = 0; b < 4; ++b) acc[a][b] = (fx4){0.f, 0.f, 0.f, 0.f};

    for (int k0 = 0; k0 < DMODEL; k0 += 64) {
        __syncthreads();
#pragma unroll
        for (int jj = 0; jj < 4; ++jj) {
            int rb = wave * 32 + jj * 8;
            gload16(Xs + rb * 64, X + (size_t)(i0 + rb + la) * DMODEL + k0 + sc);
            gload16(Ws + rb * 64, WT + (size_t)(j0 + rb + la) * DMODEL + k0 + sc);
        }
        __syncthreads();
#pragma unroll
        for (int ks = 0; ks < 2; ++ks) {
            const int po = ((ks * 4 + lq) ^ sw) * 8;
            bh8 xf[4], wf[4];
#pragma unroll
            for (int im = 0; im < 4; ++im)
                xf[im] = *(const bh8*)(Xs + (wrow + im * 16 + lm) * 64 + po);
#pragma unroll
            for (int in = 0; in < 4; ++in)
                wf[in] = *(const bh8*)(Ws + (wcol + in * 16 + lm) * 64 + po);
#pragma unroll
            for (int im = 0; im < 4; ++im)
#pragma unroll
                for (int in = 0; in < 4; ++in)
                    acc[im][in] = mfma16(wf[in], xf[im], acc[im][in]);
        }
    }
#pragma unroll
    for (int im = 0; im < 4; ++im) {
        int m = i0 + wrow + im * 16 + lm;
        int bb = m >> 13, ns = m & (N_SEQ - 1);
#pragma unroll
        for (int in = 0; in < 4; ++in) {
            int nn = j0 + wcol + in * 16 + (lq << 2);
            int which = nn >> 9;
            int h = (nn >> 6) & 7;
            int d = nn & 63;
            if (which == 2) {
                size_t vb = (size_t)(bb * NHEAD + h) * DHEAD;
#pragma unroll
                for (int cc = 0; cc < 4; ++cc)
                    VT[(vb + d + cc) * N_SEQ + ns] = f2bf(acc[im][in][cc]);
            } else {
                u16* dst = (which == 0) ? Q : K;
                float s = (which == 0) ? 0.125f : 1.f;
                ushort4 o;
                o.x = f2bf(acc[im][in][0] * s); o.y = f2bf(acc[im][in][1] * s);
                o.z = f2bf(acc[im][in][2] * s); o.w = f2bf(acc[im][in][3] * s);
                *(ushort4*)(dst + ((size_t)(bb * NHEAD + h) * N_SEQ + ns) * DHEAD + d) = o;
            }
        }
    }
}

// ---------------- landmark pooling ------------------------------------------------
__global__ __launch_bounds__(64) void pool_kernel(
    const u16* __restrict__ Q, const u16* __restrict__ K,
    float* __restrict__ QL, float* __restrict__ KL,
    u16* __restrict__ QLb, u16* __restrict__ KLb)
{
    int m = blockIdx.x, bh = blockIdx.y, d = threadIdx.x;
    size_t base = ((size_t)bh * N_SEQ + m * 32) * DHEAD + d;
    float sq = 0.f, sk = 0.f;
#pragma unroll
    for (int i = 0; i < 32; ++i) {
        sq += bf2f(Q[base + i * DHEAD]);
        sk += bf2f(K[base + i * DHEAD]);
    }
    size_t ob = ((size_t)bh * NLAND + m) * DHEAD + d;
    sq *= (1.f / 32.f); sk *= (1.f / 32.f);
    QL[ob] = sq; KL[ob] = sk;
    QLb[ob] = f2bf(sq); KLb[ob] = f2bf(sk);
}

// ---------------- attn2 = softmax(q_l @ k_l^T) ------------------------------------
__global__ __launch_bounds__(256) void attn2_kernel(
    const float* __restrict__ QL, const float* __restrict__ KL, float* __restrict__ A2)
{
    __shared__ float qrow[64];
    __shared__ float red[256];
    int i = blockIdx.x, bh = blockIdx.y, j = threadIdx.x;
    if (j < 64) qrow[j] = QL[((size_t)bh * NLAND + i) * DHEAD + j];
    __syncthreads();
    const float* kr = KL + ((size_t)bh * NLAND + j) * DHEAD;
    float lg = 0.f;
#pragma unroll
    for (int d = 0; d < 64; ++d) lg += qrow[d] * kr[d];
    red[j] = lg; __syncthreads();
    for (int s = 128; s > 0; s >>= 1) { if (j < s) red[j] = fmaxf(red[j], red[j + s]); __syncthreads(); }
    float mx = red[0]; __syncthreads();
    float p = __expf(lg - mx);
    red[j] = p; __syncthreads();
    for (int s = 128; s > 0; s >>= 1) { if (j < s) red[j] += red[j + s]; __syncthreads(); }
    float sum = red[0];
    A2[((size_t)bh * NLAND + i) * NLAND + j] = p / sum;
}

__global__ void init_scal_kernel(unsigned* scal) { if (threadIdx.x < 2) scal[threadIdx.x] = 0u; }

__global__ __launch_bounds__(256) void absmax_kernel(const float* __restrict__ A2, unsigned* scal)
{
    __shared__ float red[256];
    int bh = blockIdx.x, t = threadIdx.x;
    const float* Ab = A2 + (size_t)bh * 65536;
    float cs = 0.f, rs = 0.f;
    for (int j = 0; j < 256; ++j) cs += fabsf(Ab[t * 256 + j]);
    for (int i = 0; i < 256; ++i) rs += fabsf(Ab[i * 256 + t]);
    red[t] = cs; __syncthreads();
    for (int s = 128; s > 0; s >>= 1) { if (t < s) red[t] = fmaxf(red[t], red[t + s]); __syncthreads(); }
    if (t == 0) atomicMax(scal + 0, __float_as_uint(red[0]));
    __syncthreads();
    red[t] = rs; __syncthreads();
    for (int s = 128; s > 0; s >>= 1) { if (t < s) red[t] = fmaxf(red[t], red[t + s]); __syncthreads(); }
    if (t == 0) atomicMax(scal + 1, __float_as_uint(red[0]));
}

// z0 + A2->bf16 in one pass
__global__ __launch_bounds__(256) void z0_kernel(
    const float* __restrict__ A2, const unsigned* __restrict__ scal,
    u16* __restrict__ zb, u16* __restrict__ zbT, u16* __restrict__ A2b)
{
    float inv = 1.f / (__uint_as_float(scal[0]) * __uint_as_float(scal[1]));
    size_t idx = (size_t)blockIdx.x * 256 + threadIdx.x;
    size_t bh = idx >> 16;
    int r = (int)(idx & 65535);
    int i = r >> 8, j = r & 255;
    float a = A2[idx];
    zb[idx]  = f2bf(A2[(bh << 16) + (size_t)j * 256 + i] * inv);
    zbT[idx] = f2bf(a * inv);
    A2b[idx] = f2bf(a);
}

// ---------------- batched MFMA GEMM for pinv (LDS-staged, 4-chunk prefetch) -------
__global__ __launch_bounds__(256) void bgemm_mfma_kernel(
    const u16* __restrict__ A, const u16* __restrict__ BT,
    u16* __restrict__ Cn, u16* __restrict__ Ct, const u16* __restrict__ E,
    int N, long sB, long sCn, long sCt, float sc, float alpha, float beta, int wn, int wt)
{
    __shared__ u16 As[64 * 72];
    __shared__ u16 Bs[64 * 72];
    const int tid = threadIdx.x;
    const int wave = tid >> 6, lane = tid & 63;
    const int wm = (wave >> 1) * 32, wnn = (wave & 1) * 32;
    const int i0 = blockIdx.x * 64, j0 = blockIdx.y * 64, bh = blockIdx.z;
    const u16* Ab = A + (size_t)bh * 65536;
    const u16* Bb = BT + (size_t)bh * sB;
    const int srow = tid >> 2, scol = (tid & 3) * 16;
    const int lm = lane & 15, lq = lane >> 4;

    // prefetch all 4 K-chunks (one exposed latency instead of four)
    uint4 ra[4][2], rb[4][2];
#pragma unroll
    for (int kc = 0; kc < 4; ++kc) {
        const u16* ap = Ab + (size_t)(i0 + srow) * 256 + kc * 64 + scol;
        const u16* bp = Bb + (size_t)(j0 + srow) * 256 + kc * 64 + scol;
        ra[kc][0] = *(const uint4*)(ap);
        ra[kc][1] = *(const uint4*)(ap + 8);
        rb[kc][0] = *(const uint4*)(bp);
        rb[kc][1] = *(const uint4*)(bp + 8);
    }
    fx4 acc[2][2];
#pragma unroll
    for (int a = 0; a < 2; ++a)
#pragma unroll
        for (int b = 0; b < 2; ++b) acc[a][b] = (fx4){0.f, 0.f, 0.f, 0.f};

#pragma unroll
    for (int kc = 0; kc < 4; ++kc) {
        __syncthreads();
        *(uint4*)(As + srow * 72 + scol) = ra[kc][0];
        *(uint4*)(As + srow * 72 + scol + 8) = ra[kc][1];
        *(uint4*)(Bs + srow * 72 + scol) = rb[kc][0];
        *(uint4*)(Bs + srow * 72 + scol + 8) = rb[kc][1];
        __syncthreads();
#pragma unroll
        for (int ks = 0; ks < 2; ++ks) {
            bh8 lf[2], rf[2];
#pragma unroll
            for (int im = 0; im < 2; ++im)
                lf[im] = *(const bh8*)(As + (wm + im * 16 + lm) * 72 + ks * 32 + lq * 8);
#pragma unroll
            for (int in = 0; in < 2; ++in)
                rf[in] = *(const bh8*)(Bs + (wnn + in * 16 + lm) * 72 + ks * 32 + lq * 8);
#pragma unroll
            for (int im = 0; im < 2; ++im)
#pragma unroll
                for (int in = 0; in < 2; ++in)
                    acc[im][in] = mfma16(lf[im], rf[in], acc[im][in]);
        }
    }
#pragma unroll
    for (int im = 0; im < 2; ++im) {
#pragma unroll
        for (int in = 0; in < 2; ++in) {
            int n = j0 + wnn + in * 16 + lm;
            int m0 = i0 + wm + im * 16 + (lq << 2);
            float c[4];
#pragma unroll
            for (int r = 0; r < 4; ++r) {
                int m = m0 + r;
                float x = beta * acc[im][in][r];
                if (alpha != 0.f)
                    x += alpha * bf2f(E[(size_t)bh * 65536 + (size_t)m * 256 + n]);
                if (m == n) x += sc;
                c[r] = x;
            }
            if (wn) {
#pragma unroll
                for (int r = 0; r < 4; ++r)
                    Cn[(size_t)bh * sCn + (size_t)(m0 + r) * N + n] = f2bf(c[r]);
            }
            if (wt) {
                ushort4 o;
                o.x = f2bf(c[0]); o.y = f2bf(c[1]); o.z = f2bf(c[2]); o.w = f2bf(c[3]);
                *(ushort4*)(Ct + (size_t)bh * sCt + (size_t)n * 256 + m0) = o;
            }
        }
    }
}

// paired tail GEMM: bz<32 -> z' = 0.25 z@t3 (rows); bz>=32 -> u' = 0.25 u@t3
// (rows + transpose). Both read the same BT = t3T.
__global__ __launch_bounds__(256) void bgemm_pair_kernel(
    const u16* __restrict__ Az, const u16* __restrict__ Au, const u16* __restrict__ BT,
    u16* __restrict__ Czn, u16* __restrict__ Cun, u16* __restrict__ CunT)
{
    __shared__ u16 As[64 * 72];
    __shared__ u16 Bs[64 * 72];
    const int tid = threadIdx.x;
    const int wave = tid >> 6, lane = tid & 63;
    const int wm = (wave >> 1) * 32, wnn = (wave & 1) * 32;
    const int i0 = blockIdx.x * 64, j0 = blockIdx.y * 64;
    const int bz = blockIdx.z;
    const int bh = bz & 31;
    const int isU = bz >> 5;
    const u16* Ab = (isU ? Au : Az) + (size_t)bh * 65536;
    const u16* Bb = BT + (size_t)bh * 65536;
    const int srow = tid >> 2, scol = (tid & 3) * 16;
    const int lm = lane & 15, lq = lane >> 4;

    uint4 ra[4][2], rb[4][2];
#pragma unroll
    for (int kc = 0; kc < 4; ++kc) {
        const u16* ap = Ab + (size_t)(i0 + srow) * 256 + kc * 64 + scol;
        const u16* bp = Bb + (size_t)(j0 + srow) * 256 + kc * 64 + scol;
        ra[kc][0] = *(const uint4*)(ap);
        ra[kc][1] = *(const uint4*)(ap + 8);
        rb[kc][0] = *(const uint4*)(bp);
        rb[kc][1] = *(const uint4*)(bp + 8);
    }
    fx4 acc[2][2];
#pragma unroll
    for (int a = 0; a < 2; ++a)
#pragma unroll
        for (int b = 0; b < 2; ++b) acc[a][b] = (fx4){0.f, 0.f, 0.f, 0.f};

#pragma unroll
    for (int kc = 0; kc < 4; ++kc) {
        __syncthreads();
        *(uint4*)(As + srow * 72 + scol) = ra[kc][0];
        *(uint4*)(As + srow * 72 + scol + 8) = ra[kc][1];
        *(uint4*)(Bs + srow * 72 + scol) = rb[kc][0];
        *(uint4*)(Bs + srow * 72 + scol + 8) = rb[kc][1];
        __syncthreads();
#pragma unroll
        for (int ks = 0; ks < 2; ++ks) {
            bh8 lf[2], rf[2];
#pragma unroll
            for (int im = 0; im < 2; ++im)
                lf[im] = *(const bh8*)(As + (wm + im * 16 + lm) * 72 + ks * 32 + lq * 8);
#pragma unroll
            for (int in = 0; in < 2; ++in)
                rf[in] = *(const bh8*)(Bs + (wnn + in * 16 + lm) * 72 + ks * 32 + lq * 8);
#pragma unroll
            for (int im = 0; im < 2; ++im)
#pragma unroll
                for (int in = 0; in < 2; ++in)
                    acc[im][in] = mfma16(lf[im], rf[in], acc[im][in]);
        }
    }
#pragma unroll
    for (int im = 0; im < 2; ++im) {
#pragma unroll
        for (int in = 0; in < 2; ++in) {
            int n = j0 + wnn + in * 16 + lm;
            int m0 = i0 + wm + im * 16 + (lq << 2);
            float c[4];
#pragma unroll
            for (int r = 0; r < 4; ++r) c[r] = 0.25f * acc[im][in][r];
            u16* rows = isU ? Cun : Czn;
#pragma unroll
            for (int r = 0; r < 4; ++r)
                rows[(size_t)bh * 65536 + (size_t)(m0 + r) * 256 + n] = f2bf(c[r]);
            if (isU) {
                ushort4 o;
                o.x = f2bf(c[0]); o.y = f2bf(c[1]); o.z = f2bf(c[2]); o.w = f2bf(c[3]);
                *(ushort4*)(CunT + (size_t)bh * 65536 + (size_t)n * 256 + m0) = o;
            }
        }
    }
}

// ---------------- attn3@v flash MFMA: fetch-once, 4 waves share K/VT chunks -------
__global__ __launch_bounds__(256, 2) void attn3v_mfma_kernel(
    const u16* __restrict__ QLb, const u16* __restrict__ Kb,
    const u16* __restrict__ VTb, u16* __restrict__ PO, float* __restrict__ ML)
{
    __shared__ u16 Ks[64 * 72];
    __shared__ u16 Vs[64 * 72];
    __shared__ u16 Pw[4][64 * 72];
    const int tid = threadIdx.x;
    const int wave = tid >> 6, lane = tid & 63;
    const int q = lane >> 4, l15 = lane & 15;
    const int part = blockIdx.x;
    const int bh = blockIdx.y;
    const int nbase = part * 512;
    const int srow = tid >> 2, scol = (tid & 3) * 16;
    u16* Pp = Pw[wave];
    bh8 qf[4][2];
#pragma unroll
    for (int mt = 0; mt < 4; ++mt)
#pragma unroll
        for (int ks = 0; ks < 2; ++ks)
            qf[mt][ks] = *(const bh8*)(QLb + ((size_t)bh * NLAND + wave * 64 + mt * 16 + l15) * DHEAD + ks * 32 + q * 8);
    float M[4] = {-1e30f, -1e30f, -1e30f, -1e30f};
    float L[4] = {0.f, 0.f, 0.f, 0.f};
    fx4 O[4][4];
#pragma unroll
    for (int mt = 0; mt < 4; ++mt)
#pragma unroll
        for (int dt = 0; dt < 4; ++dt) O[mt][dt] = (fx4){0.f, 0.f, 0.f, 0.f};

    for (int c = 0; c < 8; ++c) {
        const int n0 = nbase + c * 64;
        uint4 k0v = *(const uint4*)(Kb + ((size_t)bh * N_SEQ + n0 + srow) * DHEAD + scol);
        uint4 k1v = *(const uint4*)(Kb + ((size_t)bh * N_SEQ + n0 + srow) * DHEAD + scol + 8);
        uint4 v0v = *(const uint4*)(VTb + ((size_t)bh * DHEAD + srow) * N_SEQ + n0 + scol);
        uint4 v1v = *(const uint4*)(VTb + ((size_t)bh * DHEAD + srow) * N_SEQ + n0 + scol + 8);
        __syncthreads();
        *(uint4*)(Ks + srow * 72 + scol) = k0v;
        *(uint4*)(Ks + srow * 72 + scol + 8) = k1v;
        *(uint4*)(Vs + srow * 72 + scol) = v0v;
        *(uint4*)(Vs + srow * 72 + scol + 8) = v1v;
        __syncthreads();
        fx4 S[4][4];   // [nt][mt]
#pragma unroll
        for (int nt = 0; nt < 4; ++nt)
#pragma unroll
            for (int mt = 0; mt < 4; ++mt) S[nt][mt] = (fx4){0.f, 0.f, 0.f, 0.f};
#pragma unroll
        for (int ks = 0; ks < 2; ++ks) {
            bh8 kf[4];
#pragma unroll
            for (int nt = 0; nt < 4; ++nt)
                kf[nt] = *(const bh8*)(Ks + (nt * 16 + l15) * 72 + ks * 32 + q * 8);
#pragma unroll
            for (int nt = 0; nt < 4; ++nt)
#pragma unroll
                for (int mt = 0; mt < 4; ++mt)
                    S[nt][mt] = mfma16(kf[nt], qf[mt][ks], S[nt][mt]);   // D[n][m]
        }
#pragma unroll
        for (int mt = 0; mt < 4; ++mt) {
            float cm = -1e30f;
#pragma unroll
            for (int nt = 0; nt < 4; ++nt)
#pragma unroll
                for (int r = 0; r < 4; ++r) cm = fmaxf(cm, S[nt][mt][r]);
            cm = fmaxf(cm, __shfl_xor(cm, 16));
            cm = fmaxf(cm, __shfl_xor(cm, 32));
            float Mn = fmaxf(M[mt], cm);
            float al = __expf(M[mt] - Mn);
            M[mt] = Mn;
            L[mt] *= al;
#pragma unroll
            for (int dt = 0; dt < 4; ++dt) {
                O[mt][dt][0] *= al; O[mt][dt][1] *= al;
                O[mt][dt][2] *= al; O[mt][dt][3] *= al;
            }
            float ps = 0.f;
#pragma unroll
            for (int nt = 0; nt < 4; ++nt)
#pragma unroll
                for (int r = 0; r < 4; ++r) {
                    float p = __expf(S[nt][mt][r] - Mn);
                    ps += p;
                    Pp[(mt * 16 + l15) * 72 + nt * 16 + q * 4 + r] = f2bf(p);
                }
            ps += __shfl_xor(ps, 16);
            ps += __shfl_xor(ps, 32);
            L[mt] += ps;
        }
#pragma unroll
        for (int ks = 0; ks < 2; ++ks) {
            bh8 pf[4];
#pragma unroll
            for (int mt = 0; mt < 4; ++mt)
                pf[mt] = *(const bh8*)(Pp + (mt * 16 + l15) * 72 + ks * 32 + q * 8);
#pragma unroll
            for (int dt = 0; dt < 4; ++dt) {
                bh8 vf = *(const bh8*)(Vs + (dt * 16 + l15) * 72 + ks * 32 + q * 8);
#pragma unroll
                for (int mt = 0; mt < 4; ++mt)
                    O[mt][dt] = mfma16(vf, pf[mt], O[mt][dt]);   // D[d][m]
            }
        }
    }
#pragma unroll
    for (int mt = 0; mt < 4; ++mt) {
        size_t mrow = (size_t)(bh * 16 + part) * NLAND + wave * 64 + mt * 16 + l15;
#pragma unroll
        for (int dt = 0; dt < 4; ++dt) {
            ushort4 o;
            o.x = f2bf(O[mt][dt][0]); o.y = f2bf(O[mt][dt][1]);
            o.z = f2bf(O[mt][dt][2]); o.w = f2bf(O[mt][dt][3]);
            *(ushort4*)(PO + mrow * DHEAD + dt * 16 + q * 4) = o;
        }
        if (q == 0) { ML[mrow * 2] = M[mt]; ML[mrow * 2 + 1] = L[mt]; }
    }
}

__global__ __launch_bounds__(64) void combine_kernel(
    const u16* __restrict__ PO, const float* __restrict__ ML, u16* __restrict__ W3VT)
{
    int m = blockIdx.x, bh = blockIdx.y, d = threadIdx.x;
    float Mg = -1e30f;
#pragma unroll
    for (int p = 0; p < 16; ++p)
        Mg = fmaxf(Mg, ML[((size_t)(bh * 16 + p) * NLAND + m) * 2]);
    float denom = 0.f, o = 0.f;
#pragma unroll
    for (int p = 0; p < 16; ++p) {
        size_t ix = (size_t)(bh * 16 + p) * NLAND + m;
        float w = __expf(ML[ix * 2] - Mg);
        denom += ML[ix * 2 + 1] * w;
        o += bf2f(PO[ix * DHEAD + d]) * w;
    }
    W3VT[((size_t)bh * DHEAD + d) * NLAND + m] = f2bf(o / denom);
}

// ---------------- depthwise conv residual: RT[bh*64+d][n] from VT -----------------
__global__ __launch_bounds__(256) void conv_kernel(
    const u16* __restrict__ VT, const u16* __restrict__ CW, u16* __restrict__ RT)
{
    __shared__ float vl[2080];
    __shared__ float cws[33];
    const int tid = threadIdx.x;
    const int c0 = blockIdx.x * 2048;
    const int row = blockIdx.y;
    const int h = (row >> 6) & 7;
    const u16* src = VT + (size_t)row * N_SEQ;
    for (int i = tid; i < 2080; i += 256) {
        int gn = c0 - 16 + i;
        vl[i] = (gn >= 0 && gn < N_SEQ) ? bf2f(src[gn]) : 0.f;
    }
    if (tid < 33) cws[tid] = bf2f(CW[h * 33 + tid]);
    __syncthreads();
    float v[40];
    const int base = tid * 8;
#pragma unroll
    for (int i = 0; i < 40; ++i) v[i] = vl[base + i];
    float s[8];
#pragma unroll
    for (int j = 0; j < 8; ++j) {
        float a = 0.f;
#pragma unroll
        for (int t = 0; t < 33; ++t) a += cws[t] * v[j + t];
        s[j] = a;
    }
    u16* dst = RT + (size_t)row * N_SEQ + c0 + base;
    ushort4 o0, o1;
    o0.x = f2bf(s[0]); o0.y = f2bf(s[1]); o0.z = f2bf(s[2]); o0.w = f2bf(s[3]);
    o1.x = f2bf(s[4]); o1.y = f2bf(s[5]); o1.z = f2bf(s[6]); o1.w = f2bf(s[7]);
    *(ushort4*)dst = o0;
    *(ushort4*)(dst + 4) = o1;
}

// ---------------- outheads: attn1 softmax + @WM + RT residual, 64 n/block ---------
__global__ __launch_bounds__(256) void outheads_mfma_kernel(
    const u16* __restrict__ Qb, const u16* __restrict__ KLb,
    const u16* __restrict__ WMT, const u16* __restrict__ RT,
    u16* __restrict__ Y)
{
    __shared__ u16 Pl[64 * 264];
    __shared__ float wmax[4][64];
    __shared__ float wsum[4][64];
    const int tid = threadIdx.x;
    const int wave = tid >> 6, lane = tid & 63;
    const int q = lane >> 4, l15 = lane & 15;
    const int bh = blockIdx.y;
    const int bb = bh >> 3, h = bh & 7;
    const int n0 = blockIdx.x * 64;
    fx4 S[4][4];
#pragma unroll
    for (int a = 0; a < 4; ++a)
#pragma unroll
        for (int b = 0; b < 4; ++b) S[a][b] = (fx4){0.f, 0.f, 0.f, 0.f};
#pragma unroll
    for (int ks = 0; ks < 2; ++ks) {
        bh8 qfr[4];
#pragma unroll
        for (int nt = 0; nt < 4; ++nt)
            qfr[nt] = *(const bh8*)(Qb + ((size_t)bh * N_SEQ + n0 + nt * 16 + l15) * DHEAD + ks * 32 + q * 8);
#pragma unroll
        for (int mt = 0; mt < 4; ++mt) {
            bh8 kf = *(const bh8*)(KLb + ((size_t)bh * NLAND + wave * 64 + mt * 16 + l15) * DHEAD + ks * 32 + q * 8);
#pragma unroll
            for (int nt = 0; nt < 4; ++nt)
                S[nt][mt] = mfma16(qfr[nt], kf, S[nt][mt]);
        }
    }
#pragma unroll
    for (int nt = 0; nt < 4; ++nt)
#pragma unroll
        for (int r = 0; r < 4; ++r) {
            float pm = fmaxf(fmaxf(S[nt][0][r], S[nt][1][r]), fmaxf(S[nt][2][r], S[nt][3][r]));
            pm = fmaxf(pm, __shfl_xor(pm, 1));
            pm = fmaxf(pm, __shfl_xor(pm, 2));
            pm = fmaxf(pm, __shfl_xor(pm, 4));
            pm = fmaxf(pm, __shfl_xor(pm, 8));
            if (l15 == 0) wmax[wave][nt * 16 + q * 4 + r] = pm;
        }
    __syncthreads();
#pragma unroll
    for (int nt = 0; nt < 4; ++nt)
#pragma unroll
        for (int r = 0; r < 4; ++r) {
            int nl = nt * 16 + q * 4 + r;
            float Mf = fmaxf(fmaxf(wmax[0][nl], wmax[1][nl]), fmaxf(wmax[2][nl], wmax[3][nl]));
            float ps = 0.f;
#pragma unroll
            for (int mt = 0; mt < 4; ++mt) {
                float p = __expf(S[nt][mt][r] - Mf);
                ps += p;
                Pl[nl * 264 + wave * 64 + mt * 16 + l15] = f2bf(p);
            }
            ps += __shfl_xor(ps, 1);
            ps += __shfl_xor(ps, 2);
            ps += __shfl_xor(ps, 4);
            ps += __shfl_xor(ps, 8);
            if (l15 == 0) wsum[wave][nl] = ps;
        }
    __syncthreads();
    fx4 O[4];
#pragma unroll
    for (int nt = 0; nt < 4; ++nt) O[nt] = (fx4){0.f, 0.f, 0.f, 0.f};
#pragma unroll
    for (int ks = 0; ks < 8; ++ks) {
        bh8 af = *(const bh8*)(WMT + ((size_t)bh * DHEAD + wave * 16 + l15) * NLAND + ks * 32 + q * 8);
#pragma unroll
        for (int nt = 0; nt < 4; ++nt) {
            bh8 pf = *(const bh8*)(Pl + (size_t)(nt * 16 + l15) * 264 + ks * 32 + q * 8);
            O[nt] = mfma16(af, pf, O[nt]);
        }
    }
#pragma unroll
    for (int nt = 0; nt < 4; ++nt) {
        int nl = nt * 16 + l15;
        float inv = 1.f / (wsum[0][nl] + wsum[1][nl] + wsum[2][nl] + wsum[3][nl]);
        int d0 = wave * 16 + (q << 2);
        fx4 v = O[nt];
#pragma unroll
        for (int c = 0; c < 4; ++c)
            v[c] = v[c] * inv + bf2f(RT[(size_t)(bh * DHEAD + d0 + c) * N_SEQ + n0 + nl]);
        ushort4 o;
        o.x = f2bf(v[0]); o.y = f2bf(v[1]); o.z = f2bf(v[2]); o.w = f2bf(v[3]);
        *(ushort4*)(Y + ((size_t)bb * N_SEQ + n0 + nl) * DMODEL + h * DHEAD + d0) = o;
    }
}

// ---------------- final MFMA GEMM (async staging + swizzle) -----------------------
__global__ __launch_bounds__(256) void final_mfma_kernel(
    const u16* __restrict__ Y, const u16* __restrict__ WT,
    const u16* __restrict__ Bias, const u16* __restrict__ X, void* __restrict__ Out,
    const unsigned* __restrict__ flag)
{
    __shared__ u16 Xs[128 * 64];
    __shared__ u16 Ws[128 * 64];
    const int tid = threadIdx.x;
    const int wave = tid >> 6, lane = tid & 63;
    const int wrow = (wave >> 1) * 64, wcol = (wave & 1) * 64;
    const int i0 = blockIdx.x * 128;
    const int j0 = blockIdx.y * 128;
    const int la = lane >> 3, lb = lane & 7;
    const int lm = lane & 15, lq = lane >> 4;
    const int sw = lm & 7;
    const int sc = (lb ^ la) * 8;
    const unsigned isf32 = flag[0];
    fx4 acc[4][4];
#pragma unroll
    for (int a = 0; a < 4; ++a)
#pragma unroll
        for (int b = 0; b < 4; ++b) acc[a][b] = (fx4){0.f, 0.f, 0.f, 0.f};

    for (int k0 = 0; k0 < DMODEL; k0 += 64) {
        __syncthreads();
#pragma unroll
        for (int jj = 0; jj < 4; ++jj) {
            int rb = wave * 32 + jj * 8;
            gload16(Xs + rb * 64, Y + (size_t)(i0 + rb + la) * DMODEL + k0 + sc);
            gload16(Ws + rb * 64, WT + (size_t)(j0 + rb + la) * DMODEL + k0 + sc);
        }
        __syncthreads();
#pragma unroll
        for (int ks = 0; ks < 2; ++ks) {
            const int po = ((ks * 4 + lq) ^ sw) * 8;
            bh8 xf[4], wf[4];
#pragma unroll
            for (int im = 0; im < 4; ++im)
                xf[im] = *(const bh8*)(Xs + (wrow + im * 16 + lm) * 64 + po);
#pragma unroll
            for (int in = 0; in < 4; ++in)
                wf[in] = *(const bh8*)(Ws + (wcol + in * 16 + lm) * 64 + po);
#pragma unroll
            for (int im = 0; im < 4; ++im)
#pragma unroll
                for (int in = 0; in < 4; ++in)
                    acc[im][in] = mfma16(wf[in], xf[im], acc[im][in]);
        }
    }
#pragma unroll
    for (int im = 0; im < 4; ++im) {
        int m = i0 + wrow + im * 16 + lm;
#pragma unroll
        for (int in = 0; in < 4; ++in) {
            int nn = j0 + wcol + in * 16 + (lq << 2);
            ushort4 b4 = *(const ushort4*)(Bias + nn);
            ushort4 x4 = *(const ushort4*)(X + (size_t)m * DMODEL + nn);
            float c0 = acc[im][in][0] + bf2f(b4.x) + bf2f(x4.x);
            float c1 = acc[im][in][1] + bf2f(b4.y) + bf2f(x4.y);
            float c2 = acc[im][in][2] + bf2f(b4.z) + bf2f(x4.z);
            float c3 = acc[im][in][3] + bf2f(b4.w) + bf2f(x4.w);
            if (isf32) {
                *(float4*)((float*)Out + (size_t)m * DMODEL + nn) = make_float4(c0, c1, c2, c3);
            } else {
                ushort4 o;
                o.x = f2bf(c0); o.y = f2bf(c1); o.z = f2bf(c2); o.w = f2bf(c3);
                *(ushort4*)((u16*)Out + (size_t)m * DMODEL + nn) = o;
            }
        }
    }
}

extern "C" void kernel_launch(void* const* d_in, const int* in_sizes, int n_in,
                              void* d_out, int out_size, void* d_ws, size_t ws_size,
                              hipStream_t stream)
{
    (void)in_sizes; (void)n_in; (void)out_size; (void)ws_size;
    char* ws = (char*)d_ws;
    u16*   Xc    = (u16*)(ws + 0);            // 33,554,432
    u16*   WqkvT = (u16*)(ws + 33554432);     //  1,572,864
    u16*   WoutT = (u16*)(ws + 35127296);     //    524,288
    u16*   Boutc = (u16*)(ws + 35651584);     //      1,024
    u16*   CWc   = (u16*)(ws + 35652608);     //      1,024
    u16*   Qb    = (u16*)(ws + 35653632);     // 33,554,432  [bh][n][d]
    u16*   Kb    = (u16*)(ws + 69208064);     // 33,554,432  [bh][n][d]; dead after attn3v
    u16*   RT    = (u16*)(ws + 69208064);     // overlays Kb post-attn3v
    u16*   VTb   = (u16*)(ws + 102762496);    // 33,554,432  [bh][d][n]
    float* QL    = (float*)(ws + 136316928);  //  2,097,152
    float* KL    = (float*)(ws + 138414080);  //  2,097,152
    u16*   QLb   = (u16*)(ws + 140511232);    //  1,048,576
    u16*   KLb   = (u16*)(ws + 141559808);    //  1,048,576
    u16*   W3VT  = (u16*)(ws + 142608384);    //  1,048,576
    u16*   WMT   = (u16*)(ws + 143656960);    //  1,048,576
    u16*   A2b   = (u16*)(ws + 144705536);    //  4,194,304
    u16*   zA    = (u16*)(ws + 148899840);    //  4,194,304  z rows (ping)
    u16*   zAT   = (u16*)(ws + 153094144);    //  4,194,304  z0T at init; then u rows (pong)
    float* A2    = (float*)(ws + 157288448);  // overlay region
    u16*   PO    = (u16*)(ws + 157288448);
    float* ML    = (float*)(ws + 174065664);
    u16*   zB    = (u16*)(ws + 165677056);    //  z rows (pong)
    u16*   zBT   = (u16*)(ws + 169871360);    //  uT (pong)
    u16*   xz    = (u16*)(ws + 174065664);    //  u rows (ping; overlays ML, dead after combine)
    u16*   xzT   = (u16*)(ws + 178259968);    //  uT (ping)
    u16*   t2T   = (u16*)(ws + 182454272);
    u16*   t3T   = (u16*)(ws + 186648576);
    u16*   Yb    = (u16*)(ws + 157288448);
    unsigned* SCAL = (unsigned*)(ws + 190842880);

    detect_kernel<<<1, 256, 0, stream>>>((const u16*)d_in[0], SCAL + 2);
    convert4_kernel<<<16384, 256, 0, stream>>>(d_in[0], Xc, 4194304, SCAL + 2);
    wtrans_kernel<<<3072, 256, 0, stream>>>(d_in[1], WqkvT, 512, 1536, SCAL + 2);
    wtrans_kernel<<<1024, 256, 0, stream>>>(d_in[2], WoutT, 512, 512, SCAL + 2);
    convert4_kernel<<<1, 256, 0, stream>>>(d_in[3], Boutc, 128, SCAL + 2);
    convert4_kernel<<<1, 256, 0, stream>>>(d_in[4], CWc, 66, SCAL + 2);

    qkv_mfma_kernel<<<dim3(256, 12), 256, 0, stream>>>(Xc, WqkvT, Qb, Kb, VTb);
    pool_kernel<<<dim3(256, BH), 64, 0, stream>>>(Qb, Kb, QL, KL, QLb, KLb);
    attn2_kernel<<<dim3(256, BH), 256, 0, stream>>>(QL, KL, A2);
    init_scal_kernel<<<1, 64, 0, stream>>>(SCAL);
    absmax_kernel<<<32, 256, 0, stream>>>(A2, SCAL);
    z0_kernel<<<8192, 256, 0, stream>>>(A2, SCAL, zA, zAT, A2b);

    // flash attn3@v (fetch-once), combine, conv into Kb slot
    attn3v_mfma_kernel<<<dim3(16, BH), 256, 0, stream>>>(QLb, Kb, VTb, PO, ML);
    combine_kernel<<<dim3(256, BH), 64, 0, stream>>>(PO, ML, W3VT);
    conv_kernel<<<dim3(4, 2048), 256, 0, stream>>>(VTb, CWc, RT);

    // pinv chain with carried u = x@z: 20 launches (1 init + 6x3 + 1 final).
    //   init : u0 = x @ z0                       (rows + T)
    //   G1   : t2 = u@u - 7u + 15I               (T only)
    //   G2   : t3 = 13I - u@t2                   (T only)
    //   G3   : pair{ z' = 0.25 z@t3 ; u' = 0.25 u@t3 (rows+T) }
    u16 *z = zA, *zn = zB;
    u16 *u = xz, *uT = xzT, *un = zAT, *unT = zBT;
    bgemm_mfma_kernel<<<dim3(4, 4, 32), 256, 0, stream>>>(
        A2b, zAT, u, uT, A2b, 256, 65536, 65536, 65536, 0.f, 0.f, 1.f, 1, 1);
    for (int it = 0; it < 6; ++it) {
        bgemm_mfma_kernel<<<dim3(4, 4, 32), 256, 0, stream>>>(
            u, uT, u, t2T, u, 256, 65536, 65536, 65536, 15.f, -7.f, 1.f, 0, 1);
        bgemm_mfma_kernel<<<dim3(4, 4, 32), 256, 0, stream>>>(
            u, t2T, u, t3T, u, 256, 65536, 65536, 65536, 13.f, 0.f, -1.f, 0, 1);
        bgemm_pair_kernel<<<dim3(4, 4, 64), 256, 0, stream>>>(
            z, u, t3T, zn, un, unT);
        u16* tp;
        tp = z;  z = zn;  zn = tp;
        tp = u;  u = un;  un = tp;
        tp = uT; uT = unT; unT = tp;
    }
    bgemm_mfma_kernel<<<dim3(4, 1, 32), 256, 0, stream>>>(
        z, W3VT, WMT, WMT, A2b, 64, 16384, 16384, 16384, 0.f, 0.f, 1.f, 0, 1);

    outheads_mfma_kernel<<<dim3(128, BH), 256, 0, stream>>>(Qb, KLb, WMT, RT, Yb);
    final_mfma_kernel<<<dim3(256, 4), 256, 0, stream>>>(Yb, WoutT, Boutc, Xc, d_out, SCAL + 2);
}

// Round 8
// 696.679 us; speedup vs baseline: 2.3924x; 1.4414x over previous
//
#include <hip/hip_runtime.h>

// Nystrom attention, MI355X round 14: round-6 proven bgemm body restored
// (round-13's 4-chunk register prefetch reverted: 64 extra live VGPRs +
// serialized vmcnt wait in a latency-bound kernel; session clock confound
// identified via outheads canary 83->98us on identical code).
// Kept: carried-u Newton-Schulz (20 chain launches vs 25). New: tiny-launch
// merges (init_scal into detect; bias+convw converts into one launch).
// b=4, n=8192, dim=512, h=8, dh=64, m=256 landmarks, pinv iters=6, conv k=33.

#define N_SEQ 8192
#define DMODEL 512
#define NHEAD 8
#define DHEAD 64
#define NLAND 256
#define BH 32

typedef unsigned short u16;
typedef __attribute__((ext_vector_type(8))) short bh8;
typedef __attribute__((ext_vector_type(4))) float fx4;

__device__ __forceinline__ float bf2f(u16 u) { return __uint_as_float(((unsigned)u) << 16); }
__device__ __forceinline__ u16 f2bf(float f) {
    unsigned x = __float_as_uint(f);
    return (u16)((x + 0x7fffu + ((x >> 16) & 1u)) >> 16);
}
__device__ __forceinline__ fx4 mfma16(bh8 a, bh8 b, fx4 c) {
    return __builtin_amdgcn_mfma_f32_16x16x32_bf16(a, b, c, 0, 0, 0);
}
__device__ __forceinline__ void gload16(u16* lds, const u16* g) {
    __builtin_amdgcn_global_load_lds(
        (const __attribute__((address_space(1))) unsigned int*)g,
        (__attribute__((address_space(3))) unsigned int*)lds, 16, 0, 0);
}

// ---------------- dtype probe + SCAL zero (merged init_scal) ----------------------
__global__ void detect_kernel(const u16* __restrict__ X, unsigned* scal)
{
    __shared__ int cnt;
    if (threadIdx.x == 0) cnt = 0;
    if (threadIdx.x < 2) scal[threadIdx.x] = 0u;   // absmax accumulators
    __syncthreads();
    u16 u = X[threadIdx.x * 2];
    int e = (u >> 7) & 0xFF;
    int insane = (u != 0) && (e < 90 || e > 140);
    atomicAdd(&cnt, insane);
    __syncthreads();
    if (threadIdx.x == 0) scal[2] = (cnt > 64) ? 1u : 0u;
}

// vectorized convert: n4 = elements/4 (all our sizes are /4)
__global__ __launch_bounds__(256) void convert4_kernel(
    const void* __restrict__ in, u16* __restrict__ out, int n4, const unsigned* __restrict__ flag)
{
    int i = blockIdx.x * 256 + threadIdx.x;
    if (i >= n4) return;
    if (flag[0]) {
        float4 v = ((const float4*)in)[i];
        ushort4 o;
        o.x = f2bf(v.x); o.y = f2bf(v.y); o.z = f2bf(v.z); o.w = f2bf(v.w);
        ((ushort4*)out)[i] = o;
    } else {
        ((ushort4*)out)[i] = ((const ushort4*)in)[i];
    }
}

// merged tiny converts: bias (128 x4) + conv weights (66 x4), one block
__global__ void small_convert_kernel(
    const void* __restrict__ b_in, u16* __restrict__ b_out,
    const void* __restrict__ c_in, u16* __restrict__ c_out,
    const unsigned* __restrict__ flag)
{
    int t = threadIdx.x;
    unsigned f = flag[0];
    const void* in; u16* out; int i;
    if (t < 128)       { in = b_in; out = b_out; i = t; }
    else if (t < 194)  { in = c_in; out = c_out; i = t - 128; }
    else return;
    if (f) {
        float4 v = ((const float4*)in)[i];
        ushort4 o;
        o.x = f2bf(v.x); o.y = f2bf(v.y); o.z = f2bf(v.z); o.w = f2bf(v.w);
        ((ushort4*)out)[i] = o;
    } else {
        ((ushort4*)out)[i] = ((const ushort4*)in)[i];
    }
}

__global__ __launch_bounds__(256) void wtrans_kernel(
    const void* __restrict__ in, u16* __restrict__ out, int rows, int cols,
    const unsigned* __restrict__ flag)
{
    int idx = blockIdx.x * 256 + threadIdx.x;
    if (idx >= rows * cols) return;
    int r = idx / cols, c = idx % cols;
    float v = flag[0] ? ((const float*)in)[idx] : bf2f(((const u16*)in)[idx]);
    out[(size_t)c * rows + r] = f2bf(v);
}

// ---------------- QKV MFMA GEMM (async staging + xor swizzle) ---------------------
__global__ __launch_bounds__(256) void qkv_mfma_kernel(
    const u16* __restrict__ X, const u16* __restrict__ WT,
    u16* __restrict__ Q, u16* __restrict__ K, u16* __restrict__ VT)
{
    __shared__ u16 Xs[128 * 64];
    __shared__ u16 Ws[128 * 64];
    const int tid = threadIdx.x;
    const int wave = tid >> 6, lane = tid & 63;
    const int wrow = (wave >> 1) * 64, wcol = (wave & 1) * 64;
    const int i0 = blockIdx.x * 128;
    const int j0 = blockIdx.y * 128;
    const int la = lane >> 3, lb = lane & 7;
    const int lm = lane & 15, lq = lane >> 4;
    const int sw = lm & 7;
    const int sc = (lb ^ la) * 8;
    fx4 acc[4][4];
#pragma unroll
    for (int a = 0; a < 4; ++a)
#pragma unroll
        for (int b = 0; b < 4; ++b) acc[a][b] = (fx4){0.f, 0.f, 0.f, 0.f};

    for (int k0 = 0; k0 < DMODEL; k0 += 64) {
        __syncthreads();
#pragma unroll
        for (int jj = 0; jj < 4; ++jj) {
            int rb = wave * 32 + jj * 8;
            gload16(Xs + rb * 64, X + (size_t)(i0 + rb + la) * DMODEL + k0 + sc);
            gload16(Ws + rb * 64, WT + (size_t)(j0 + rb + la) * DMODEL + k0 + sc);
        }
        __syncthreads();
#pragma unroll
        for (int ks = 0; ks < 2; ++ks) {
            const int po = ((ks * 4 + lq) ^ sw) * 8;
            bh8 xf[4], wf[4];
#pragma unroll
            for (int im = 0; im < 4; ++im)
                xf[im] = *(const bh8*)(Xs + (wrow + im * 16 + lm) * 64 + po);
#pragma unroll
            for (int in = 0; in < 4; ++in)
                wf[in] = *(const bh8*)(Ws + (wcol + in * 16 + lm) * 64 + po);
#pragma unroll
            for (int im = 0; im < 4; ++im)
#pragma unroll
                for (int in = 0; in < 4; ++in)
                    acc[im][in] = mfma16(wf[in], xf[im], acc[im][in]);
        }
    }
#pragma unroll
    for (int im = 0; im < 4; ++im) {
        int m = i0 + wrow + im * 16 + lm;
        int bb = m >> 13, ns = m & (N_SEQ - 1);
#pragma unroll
        for (int in = 0; in < 4; ++in) {
            int nn = j0 + wcol + in * 16 + (lq << 2);
            int which = nn >> 9;
            int h = (nn >> 6) & 7;
            int d = nn & 63;
            if (which == 2) {
                size_t vb = (size_t)(bb * NHEAD + h) * DHEAD;
#pragma unroll
                for (int cc = 0; cc < 4; ++cc)
                    VT[(vb + d + cc) * N_SEQ + ns] = f2bf(acc[im][in][cc]);
            } else {
                u16* dst = (which == 0) ? Q : K;
                float s = (which == 0) ? 0.125f : 1.f;
                ushort4 o;
                o.x = f2bf(acc[im][in][0] * s); o.y = f2bf(acc[im][in][1] * s);
                o.z = f2bf(acc[im][in][2] * s); o.w = f2bf(acc[im][in][3] * s);
                *(ushort4*)(dst + ((size_t)(bb * NHEAD + h) * N_SEQ + ns) * DHEAD + d) = o;
            }
        }
    }
}

// ---------------- landmark pooling ------------------------------------------------
__global__ __launch_bounds__(64) void pool_kernel(
    const u16* __restrict__ Q, const u16* __restrict__ K,
    float* __restrict__ QL, float* __restrict__ KL,
    u16* __restrict__ QLb, u16* __restrict__ KLb)
{
    int m = blockIdx.x, bh = blockIdx.y, d = threadIdx.x;
    size_t base = ((size_t)bh * N_SEQ + m * 32) * DHEAD + d;
    float sq = 0.f, sk = 0.f;
#pragma unroll
    for (int i = 0; i < 32; ++i) {
        sq += bf2f(Q[base + i * DHEAD]);
        sk += bf2f(K[base + i * DHEAD]);
    }
    size_t ob = ((size_t)bh * NLAND + m) * DHEAD + d;
    sq *= (1.f / 32.f); sk *= (1.f / 32.f);
    QL[ob] = sq; KL[ob] = sk;
    QLb[ob] = f2bf(sq); KLb[ob] = f2bf(sk);
}

// ---------------- attn2 = softmax(q_l @ k_l^T) ------------------------------------
__global__ __launch_bounds__(256) void attn2_kernel(
    const float* __restrict__ QL, const float* __restrict__ KL, float* __restrict__ A2)
{
    __shared__ float qrow[64];
    __shared__ float red[256];
    int i = blockIdx.x, bh = blockIdx.y, j = threadIdx.x;
    if (j < 64) qrow[j] = QL[((size_t)bh * NLAND + i) * DHEAD + j];
    __syncthreads();
    const float* kr = KL + ((size_t)bh * NLAND + j) * DHEAD;
    float lg = 0.f;
#pragma unroll
    for (int d = 0; d < 64; ++d) lg += qrow[d] * kr[d];
    red[j] = lg; __syncthreads();
    for (int s = 128; s > 0; s >>= 1) { if (j < s) red[j] = fmaxf(red[j], red[j + s]); __syncthreads(); }
    float mx = red[0]; __syncthreads();
    float p = __expf(lg - mx);
    red[j] = p; __syncthreads();
    for (int s = 128; s > 0; s >>= 1) { if (j < s) red[j] += red[j + s]; __syncthreads(); }
    float sum = red[0];
    A2[((size_t)bh * NLAND + i) * NLAND + j] = p / sum;
}

__global__ __launch_bounds__(256) void absmax_kernel(const float* __restrict__ A2, unsigned* scal)
{
    __shared__ float red[256];
    int bh = blockIdx.x, t = threadIdx.x;
    const float* Ab = A2 + (size_t)bh * 65536;
    float cs = 0.f, rs = 0.f;
    for (int j = 0; j < 256; ++j) cs += fabsf(Ab[t * 256 + j]);
    for (int i = 0; i < 256; ++i) rs += fabsf(Ab[i * 256 + t]);
    red[t] = cs; __syncthreads();
    for (int s = 128; s > 0; s >>= 1) { if (t < s) red[t] = fmaxf(red[t], red[t + s]); __syncthreads(); }
    if (t == 0) atomicMax(scal + 0, __float_as_uint(red[0]));
    __syncthreads();
    red[t] = rs; __syncthreads();
    for (int s = 128; s > 0; s >>= 1) { if (t < s) red[t] = fmaxf(red[t], red[t + s]); __syncthreads(); }
    if (t == 0) atomicMax(scal + 1, __float_as_uint(red[0]));
}

// z0 + A2->bf16 in one pass
__global__ __launch_bounds__(256) void z0_kernel(
    const float* __restrict__ A2, const unsigned* __restrict__ scal,
    u16* __restrict__ zb, u16* __restrict__ zbT, u16* __restrict__ A2b)
{
    float inv = 1.f / (__uint_as_float(scal[0]) * __uint_as_float(scal[1]));
    size_t idx = (size_t)blockIdx.x * 256 + threadIdx.x;
    size_t bh = idx >> 16;
    int r = (int)(idx & 65535);
    int i = r >> 8, j = r & 255;
    float a = A2[idx];
    zb[idx]  = f2bf(A2[(bh << 16) + (size_t)j * 256 + i] * inv);
    zbT[idx] = f2bf(a * inv);
    A2b[idx] = f2bf(a);
}

// ---------------- batched MFMA GEMM for pinv (round-6 proven body) ----------------
__global__ __launch_bounds__(256) void bgemm_mfma_kernel(
    const u16* __restrict__ A, const u16* __restrict__ BT,
    u16* __restrict__ Cn, u16* __restrict__ Ct, const u16* __restrict__ E,
    int N, long sB, long sCn, long sCt, float sc, float alpha, float beta, int wn, int wt)
{
    __shared__ u16 As[64 * 72];
    __shared__ u16 Bs[64 * 72];
    const int tid = threadIdx.x;
    const int wave = tid >> 6, lane = tid & 63;
    const int wm = (wave >> 1) * 32, wnn = (wave & 1) * 32;
    const int i0 = blockIdx.x * 64, j0 = blockIdx.y * 64, bh = blockIdx.z;
    const u16* Ab = A + (size_t)bh * 65536;
    const u16* Bb = BT + (size_t)bh * sB;
    const int srow = tid >> 2, scol = (tid & 3) * 16;
    const int lm = lane & 15, lq = lane >> 4;
    fx4 acc[2][2];
#pragma unroll
    for (int a = 0; a < 2; ++a)
#pragma unroll
        for (int b = 0; b < 2; ++b) acc[a][b] = (fx4){0.f, 0.f, 0.f, 0.f};

    for (int k0 = 0; k0 < 256; k0 += 64) {
        uint4 a0 = *(const uint4*)(Ab + (size_t)(i0 + srow) * 256 + k0 + scol);
        uint4 a1 = *(const uint4*)(Ab + (size_t)(i0 + srow) * 256 + k0 + scol + 8);
        uint4 b0 = *(const uint4*)(Bb + (size_t)(j0 + srow) * 256 + k0 + scol);
        uint4 b1 = *(const uint4*)(Bb + (size_t)(j0 + srow) * 256 + k0 + scol + 8);
        __syncthreads();
        *(uint4*)(As + srow * 72 + scol) = a0;
        *(uint4*)(As + srow * 72 + scol + 8) = a1;
        *(uint4*)(Bs + srow * 72 + scol) = b0;
        *(uint4*)(Bs + srow * 72 + scol + 8) = b1;
        __syncthreads();
#pragma unroll
        for (int ks = 0; ks < 2; ++ks) {
            bh8 lf[2], rf[2];
#pragma unroll
            for (int im = 0; im < 2; ++im)
                lf[im] = *(const bh8*)(As + (wm + im * 16 + lm) * 72 + ks * 32 + lq * 8);
#pragma unroll
            for (int in = 0; in < 2; ++in)
                rf[in] = *(const bh8*)(Bs + (wnn + in * 16 + lm) * 72 + ks * 32 + lq * 8);
#pragma unroll
            for (int im = 0; im < 2; ++im)
#pragma unroll
                for (int in = 0; in < 2; ++in)
                    acc[im][in] = mfma16(lf[im], rf[in], acc[im][in]);
        }
    }
#pragma unroll
    for (int im = 0; im < 2; ++im) {
#pragma unroll
        for (int in = 0; in < 2; ++in) {
            int n = j0 + wnn + in * 16 + lm;
            int m0 = i0 + wm + im * 16 + (lq << 2);
            float c[4];
#pragma unroll
            for (int r = 0; r < 4; ++r) {
                int m = m0 + r;
                float x = beta * acc[im][in][r];
                if (alpha != 0.f)
                    x += alpha * bf2f(E[(size_t)bh * 65536 + (size_t)m * 256 + n]);
                if (m == n) x += sc;
                c[r] = x;
            }
            if (wn) {
#pragma unroll
                for (int r = 0; r < 4; ++r)
                    Cn[(size_t)bh * sCn + (size_t)(m0 + r) * N + n] = f2bf(c[r]);
            }
            if (wt) {
                ushort4 o;
                o.x = f2bf(c[0]); o.y = f2bf(c[1]); o.z = f2bf(c[2]); o.w = f2bf(c[3]);
                *(ushort4*)(Ct + (size_t)bh * sCt + (size_t)n * 256 + m0) = o;
            }
        }
    }
}

// paired tail GEMM: bz<32 -> z' = 0.25 z@t3 (rows); bz>=32 -> u' = 0.25 u@t3
// (rows + transpose). Both read the same BT = t3T. Round-6 staging body.
__global__ __launch_bounds__(256) void bgemm_pair_kernel(
    const u16* __restrict__ Az, const u16* __restrict__ Au, const u16* __restrict__ BT,
    u16* __restrict__ Czn, u16* __restrict__ Cun, u16* __restrict__ CunT)
{
    __shared__ u16 As[64 * 72];
    __shared__ u16 Bs[64 * 72];
    const int tid = threadIdx.x;
    const int wave = tid >> 6, lane = tid & 63;
    const int wm = (wave >> 1) * 32, wnn = (wave & 1) * 32;
    const int i0 = blockIdx.x * 64, j0 = blockIdx.y * 64;
    const int bz = blockIdx.z;
    const int bh = bz & 31;
    const int isU = bz >> 5;
    const u16* Ab = (isU ? Au : Az) + (size_t)bh * 65536;
    const u16* Bb = BT + (size_t)bh * 65536;
    const int srow = tid >> 2, scol = (tid & 3) * 16;
    const int lm = lane & 15, lq = lane >> 4;
    fx4 acc[2][2];
#pragma unroll
    for (int a = 0; a < 2; ++a)
#pragma unroll
        for (int b = 0; b < 2; ++b) acc[a][b] = (fx4){0.f, 0.f, 0.f, 0.f};

    for (int k0 = 0; k0 < 256; k0 += 64) {
        uint4 a0 = *(const uint4*)(Ab + (size_t)(i0 + srow) * 256 + k0 + scol);
        uint4 a1 = *(const uint4*)(Ab + (size_t)(i0 + srow) * 256 + k0 + scol + 8);
        uint4 b0 = *(const uint4*)(Bb + (size_t)(j0 + srow) * 256 + k0 + scol);
        uint4 b1 = *(const uint4*)(Bb + (size_t)(j0 + srow) * 256 + k0 + scol + 8);
        __syncthreads();
        *(uint4*)(As + srow * 72 + scol) = a0;
        *(uint4*)(As + srow * 72 + scol + 8) = a1;
        *(uint4*)(Bs + srow * 72 + scol) = b0;
        *(uint4*)(Bs + srow * 72 + scol + 8) = b1;
        __syncthreads();
#pragma unroll
        for (int ks = 0; ks < 2; ++ks) {
            bh8 lf[2], rf[2];
#pragma unroll
            for (int im = 0; im < 2; ++im)
                lf[im] = *(const bh8*)(As + (wm + im * 16 + lm) * 72 + ks * 32 + lq * 8);
#pragma unroll
            for (int in = 0; in < 2; ++in)
                rf[in] = *(const bh8*)(Bs + (wnn + in * 16 + lm) * 72 + ks * 32 + lq * 8);
#pragma unroll
            for (int im = 0; im < 2; ++im)
#pragma unroll
                for (int in = 0; in < 2; ++in)
                    acc[im][in] = mfma16(lf[im], rf[in], acc[im][in]);
        }
    }
#pragma unroll
    for (int im = 0; im < 2; ++im) {
#pragma unroll
        for (int in = 0; in < 2; ++in) {
            int n = j0 + wnn + in * 16 + lm;
            int m0 = i0 + wm + im * 16 + (lq << 2);
            float c[4];
#pragma unroll
            for (int r = 0; r < 4; ++r) c[r] = 0.25f * acc[im][in][r];
            u16* rows = isU ? Cun : Czn;
#pragma unroll
            for (int r = 0; r < 4; ++r)
                rows[(size_t)bh * 65536 + (size_t)(m0 + r) * 256 + n] = f2bf(c[r]);
            if (isU) {
                ushort4 o;
                o.x = f2bf(c[0]); o.y = f2bf(c[1]); o.z = f2bf(c[2]); o.w = f2bf(c[3]);
                *(ushort4*)(CunT + (size_t)bh * 65536 + (size_t)n * 256 + m0) = o;
            }
        }
    }
}

// ---------------- attn3@v flash MFMA: fetch-once, 4 waves share K/VT chunks -------
__global__ __launch_bounds__(256, 2) void attn3v_mfma_kernel(
    const u16* __restrict__ QLb, const u16* __restrict__ Kb,
    const u16* __restrict__ VTb, u16* __restrict__ PO, float* __restrict__ ML)
{
    __shared__ u16 Ks[64 * 72];
    __shared__ u16 Vs[64 * 72];
    __shared__ u16 Pw[4][64 * 72];
    const int tid = threadIdx.x;
    const int wave = tid >> 6, lane = tid & 63;
    const int q = lane >> 4, l15 = lane & 15;
    const int part = blockIdx.x;
    const int bh = blockIdx.y;
    const int nbase = part * 512;
    const int srow = tid >> 2, scol = (tid & 3) * 16;
    u16* Pp = Pw[wave];
    bh8 qf[4][2];
#pragma unroll
    for (int mt = 0; mt < 4; ++mt)
#pragma unroll
        for (int ks = 0; ks < 2; ++ks)
            qf[mt][ks] = *(const bh8*)(QLb + ((size_t)bh * NLAND + wave * 64 + mt * 16 + l15) * DHEAD + ks * 32 + q * 8);
    float M[4] = {-1e30f, -1e30f, -1e30f, -1e30f};
    float L[4] = {0.f, 0.f, 0.f, 0.f};
    fx4 O[4][4];
#pragma unroll
    for (int mt = 0; mt < 4; ++mt)
#pragma unroll
        for (int dt = 0; dt < 4; ++dt) O[mt][dt] = (fx4){0.f, 0.f, 0.f, 0.f};

    for (int c = 0; c < 8; ++c) {
        const int n0 = nbase + c * 64;
        uint4 k0v = *(const uint4*)(Kb + ((size_t)bh * N_SEQ + n0 + srow) * DHEAD + scol);
        uint4 k1v = *(const uint4*)(Kb + ((size_t)bh * N_SEQ + n0 + srow) * DHEAD + scol + 8);
        uint4 v0v = *(const uint4*)(VTb + ((size_t)bh * DHEAD + srow) * N_SEQ + n0 + scol);
        uint4 v1v = *(const uint4*)(VTb + ((size_t)bh * DHEAD + srow) * N_SEQ + n0 + scol + 8);
        __syncthreads();
        *(uint4*)(Ks + srow * 72 + scol) = k0v;
        *(uint4*)(Ks + srow * 72 + scol + 8) = k1v;
        *(uint4*)(Vs + srow * 72 + scol) = v0v;
        *(uint4*)(Vs + srow * 72 + scol + 8) = v1v;
        __syncthreads();
        fx4 S[4][4];   // [nt][mt]
#pragma unroll
        for (int nt = 0; nt < 4; ++nt)
#pragma unroll
            for (int mt = 0; mt < 4; ++mt) S[nt][mt] = (fx4){0.f, 0.f, 0.f, 0.f};
#pragma unroll
        for (int ks = 0; ks < 2; ++ks) {
            bh8 kf[4];
#pragma unroll
            for (int nt = 0; nt < 4; ++nt)
                kf[nt] = *(const bh8*)(Ks + (nt * 16 + l15) * 72 + ks * 32 + q * 8);
#pragma unroll
            for (int nt = 0; nt < 4; ++nt)
#pragma unroll
                for (int mt = 0; mt < 4; ++mt)
                    S[nt][mt] = mfma16(kf[nt], qf[mt][ks], S[nt][mt]);   // D[n][m]
        }
#pragma unroll
        for (int mt = 0; mt < 4; ++mt) {
            float cm = -1e30f;
#pragma unroll
            for (int nt = 0; nt < 4; ++nt)
#pragma unroll
                for (int r = 0; r < 4; ++r) cm = fmaxf(cm, S[nt][mt][r]);
            cm = fmaxf(cm, __shfl_xor(cm, 16));
            cm = fmaxf(cm, __shfl_xor(cm, 32));
            float Mn = fmaxf(M[mt], cm);
            float al = __expf(M[mt] - Mn);
            M[mt] = Mn;
            L[mt] *= al;
#pragma unroll
            for (int dt = 0; dt < 4; ++dt) {
                O[mt][dt][0] *= al; O[mt][dt][1] *= al;
                O[mt][dt][2] *= al; O[mt][dt][3] *= al;
            }
            float ps = 0.f;
#pragma unroll
            for (int nt = 0; nt < 4; ++nt)
#pragma unroll
                for (int r = 0; r < 4; ++r) {
                    float p = __expf(S[nt][mt][r] - Mn);
                    ps += p;
                    Pp[(mt * 16 + l15) * 72 + nt * 16 + q * 4 + r] = f2bf(p);
                }
            ps += __shfl_xor(ps, 16);
            ps += __shfl_xor(ps, 32);
            L[mt] += ps;
        }
#pragma unroll
        for (int ks = 0; ks < 2; ++ks) {
            bh8 pf[4];
#pragma unroll
            for (int mt = 0; mt < 4; ++mt)
                pf[mt] = *(const bh8*)(Pp + (mt * 16 + l15) * 72 + ks * 32 + q * 8);
#pragma unroll
            for (int dt = 0; dt < 4; ++dt) {
                bh8 vf = *(const bh8*)(Vs + (dt * 16 + l15) * 72 + ks * 32 + q * 8);
#pragma unroll
                for (int mt = 0; mt < 4; ++mt)
                    O[mt][dt] = mfma16(vf, pf[mt], O[mt][dt]);   // D[d][m]
            }
        }
    }
#pragma unroll
    for (int mt = 0; mt < 4; ++mt) {
        size_t mrow = (size_t)(bh * 16 + part) * NLAND + wave * 64 + mt * 16 + l15;
#pragma unroll
        for (int dt = 0; dt < 4; ++dt) {
            ushort4 o;
            o.x = f2bf(O[mt][dt][0]); o.y = f2bf(O[mt][dt][1]);
            o.z = f2bf(O[mt][dt][2]); o.w = f2bf(O[mt][dt][3]);
            *(ushort4*)(PO + mrow * DHEAD + dt * 16 + q * 4) = o;
        }
        if (q == 0) { ML[mrow * 2] = M[mt]; ML[mrow * 2 + 1] = L[mt]; }
    }
}

__global__ __launch_bounds__(64) void combine_kernel(
    const u16* __restrict__ PO, const float* __restrict__ ML, u16* __restrict__ W3VT)
{
    int m = blockIdx.x, bh = blockIdx.y, d = threadIdx.x;
    float Mg = -1e30f;
#pragma unroll
    for (int p = 0; p < 16; ++p)
        Mg = fmaxf(Mg, ML[((size_t)(bh * 16 + p) * NLAND + m) * 2]);
    float denom = 0.f, o = 0.f;
#pragma unroll
    for (int p = 0; p < 16; ++p) {
        size_t ix = (size_t)(bh * 16 + p) * NLAND + m;
        float w = __expf(ML[ix * 2] - Mg);
        denom += ML[ix * 2 + 1] * w;
        o += bf2f(PO[ix * DHEAD + d]) * w;
    }
    W3VT[((size_t)bh * DHEAD + d) * NLAND + m] = f2bf(o / denom);
}

// ---------------- depthwise conv residual: RT[bh*64+d][n] from VT -----------------
__global__ __launch_bounds__(256) void conv_kernel(
    const u16* __restrict__ VT, const u16* __restrict__ CW, u16* __restrict__ RT)
{
    __shared__ float vl[2080];
    __shared__ float cws[33];
    const int tid = threadIdx.x;
    const int c0 = blockIdx.x * 2048;
    const int row = blockIdx.y;
    const int h = (row >> 6) & 7;
    const u16* src = VT + (size_t)row * N_SEQ;
    for (int i = tid; i < 2080; i += 256) {
        int gn = c0 - 16 + i;
        vl[i] = (gn >= 0 && gn < N_SEQ) ? bf2f(src[gn]) : 0.f;
    }
    if (tid < 33) cws[tid] = bf2f(CW[h * 33 + tid]);
    __syncthreads();
    float v[40];
    const int base = tid * 8;
#pragma unroll
    for (int i = 0; i < 40; ++i) v[i] = vl[base + i];
    float s[8];
#pragma unroll
    for (int j = 0; j < 8; ++j) {
        float a = 0.f;
#pragma unroll
        for (int t = 0; t < 33; ++t) a += cws[t] * v[j + t];
        s[j] = a;
    }
    u16* dst = RT + (size_t)row * N_SEQ + c0 + base;
    ushort4 o0, o1;
    o0.x = f2bf(s[0]); o0.y = f2bf(s[1]); o0.z = f2bf(s[2]); o0.w = f2bf(s[3]);
    o1.x = f2bf(s[4]); o1.y = f2bf(s[5]); o1.z = f2bf(s[6]); o1.w = f2bf(s[7]);
    *(ushort4*)dst = o0;
    *(ushort4*)(dst + 4) = o1;
}

// ---------------- outheads: attn1 softmax + @WM + RT residual, 64 n/block ---------
__global__ __launch_bounds__(256) void outheads_mfma_kernel(
    const u16* __restrict__ Qb, const u16* __restrict__ KLb,
    const u16* __restrict__ WMT, const u16* __restrict__ RT,
    u16* __restrict__ Y)
{
    __shared__ u16 Pl[64 * 264];
    __shared__ float wmax[4][64];
    __shared__ float wsum[4][64];
    const int tid = threadIdx.x;
    const int wave = tid >> 6, lane = tid & 63;
    const int q = lane >> 4, l15 = lane & 15;
    const int bh = blockIdx.y;
    const int bb = bh >> 3, h = bh & 7;
    const int n0 = blockIdx.x * 64;
    fx4 S[4][4];
#pragma unroll
    for (int a = 0; a < 4; ++a)
#pragma unroll
        for (int b = 0; b < 4; ++b) S[a][b] = (fx4){0.f, 0.f, 0.f, 0.f};
#pragma unroll
    for (int ks = 0; ks < 2; ++ks) {
        bh8 qfr[4];
#pragma unroll
        for (int nt = 0; nt < 4; ++nt)
            qfr[nt] = *(const bh8*)(Qb + ((size_t)bh * N_SEQ + n0 + nt * 16 + l15) * DHEAD + ks * 32 + q * 8);
#pragma unroll
        for (int mt = 0; mt < 4; ++mt) {
            bh8 kf = *(const bh8*)(KLb + ((size_t)bh * NLAND + wave * 64 + mt * 16 + l15) * DHEAD + ks * 32 + q * 8);
#pragma unroll
            for (int nt = 0; nt < 4; ++nt)
                S[nt][mt] = mfma16(qfr[nt], kf, S[nt][mt]);
        }
    }
#pragma unroll
    for (int nt = 0; nt < 4; ++nt)
#pragma unroll
        for (int r = 0; r < 4; ++r) {
            float pm = fmaxf(fmaxf(S[nt][0][r], S[nt][1][r]), fmaxf(S[nt][2][r], S[nt][3][r]));
            pm = fmaxf(pm, __shfl_xor(pm, 1));
            pm = fmaxf(pm, __shfl_xor(pm, 2));
            pm = fmaxf(pm, __shfl_xor(pm, 4));
            pm = fmaxf(pm, __shfl_xor(pm, 8));
            if (l15 == 0) wmax[wave][nt * 16 + q * 4 + r] = pm;
        }
    __syncthreads();
#pragma unroll
    for (int nt = 0; nt < 4; ++nt)
#pragma unroll
        for (int r = 0; r < 4; ++r) {
            int nl = nt * 16 + q * 4 + r;
            float Mf = fmaxf(fmaxf(wmax[0][nl], wmax[1][nl]), fmaxf(wmax[2][nl], wmax[3][nl]));
            float ps = 0.f;
#pragma unroll
            for (int mt = 0; mt < 4; ++mt) {
                float p = __expf(S[nt][mt][r] - Mf);
                ps += p;
                Pl[nl * 264 + wave * 64 + mt * 16 + l15] = f2bf(p);
            }
            ps += __shfl_xor(ps, 1);
            ps += __shfl_xor(ps, 2);
            ps += __shfl_xor(ps, 4);
            ps += __shfl_xor(ps, 8);
            if (l15 == 0) wsum[wave][nl] = ps;
        }
    __syncthreads();
    fx4 O[4];
#pragma unroll
    for (int nt = 0; nt < 4; ++nt) O[nt] = (fx4){0.f, 0.f, 0.f, 0.f};
#pragma unroll
    for (int ks = 0; ks < 8; ++ks) {
        bh8 af = *(const bh8*)(WMT + ((size_t)bh * DHEAD + wave * 16 + l15) * NLAND + ks * 32 + q * 8);
#pragma unroll
        for (int nt = 0; nt < 4; ++nt) {
            bh8 pf = *(const bh8*)(Pl + (size_t)(nt * 16 + l15) * 264 + ks * 32 + q * 8);
            O[nt] = mfma16(af, pf, O[nt]);
        }
    }
#pragma unroll
    for (int nt = 0; nt < 4; ++nt) {
        int nl = nt * 16 + l15;
        float inv = 1.f / (wsum[0][nl] + wsum[1][nl] + wsum[2][nl] + wsum[3][nl]);
        int d0 = wave * 16 + (q << 2);
        fx4 v = O[nt];
#pragma unroll
        for (int c = 0; c < 4; ++c)
            v[c] = v[c] * inv + bf2f(RT[(size_t)(bh * DHEAD + d0 + c) * N_SEQ + n0 + nl]);
        ushort4 o;
        o.x = f2bf(v[0]); o.y = f2bf(v[1]); o.z = f2bf(v[2]); o.w = f2bf(v[3]);
        *(ushort4*)(Y + ((size_t)bb * N_SEQ + n0 + nl) * DMODEL + h * DHEAD + d0) = o;
    }
}

// ---------------- final MFMA GEMM (async staging + swizzle) -----------------------
__global__ __launch_bounds__(256) void final_mfma_kernel(
    const u16* __restrict__ Y, const u16* __restrict__ WT,
    const u16* __restrict__ Bias, const u16* __restrict__ X, void* __restrict__ Out,
    const unsigned* __restrict__ flag)
{
    __shared__ u16 Xs[128 * 64];
    __shared__ u16 Ws[128 * 64];
    const int tid = threadIdx.x;
    const int wave = tid >> 6, lane = tid & 63;
    const int wrow = (wave >> 1) * 64, wcol = (wave & 1) * 64;
    const int i0 = blockIdx.x * 128;
    const int j0 = blockIdx.y * 128;
    const int la = lane >> 3, lb = lane & 7;
    const int lm = lane & 15, lq = lane >> 4;
    const int sw = lm & 7;
    const int sc = (lb ^ la) * 8;
    const unsigned isf32 = flag[0];
    fx4 acc[4][4];
#pragma unroll
    for (int a = 0; a < 4; ++a)
#pragma unroll
        for (int b = 0; b < 4; ++b) acc[a][b] = (fx4){0.f, 0.f, 0.f, 0.f};

    for (int k0 = 0; k0 < DMODEL; k0 += 64) {
        __syncthreads();
#pragma unroll
        for (int jj = 0; jj < 4; ++jj) {
            int rb = wave * 32 + jj * 8;
            gload16(Xs + rb * 64, Y + (size_t)(i0 + rb + la) * DMODEL + k0 + sc);
            gload16(Ws + rb * 64, WT + (size_t)(j0 + rb + la) * DMODEL + k0 + sc);
        }
        __syncthreads();
#pragma unroll
        for (int ks = 0; ks < 2; ++ks) {
            const int po = ((ks * 4 + lq) ^ sw) * 8;
            bh8 xf[4], wf[4];
#pragma unroll
            for (int im = 0; im < 4; ++im)
                xf[im] = *(const bh8*)(Xs + (wrow + im * 16 + lm) * 64 + po);
#pragma unroll
            for (int in = 0; in < 4; ++in)
                wf[in] = *(const bh8*)(Ws + (wcol + in * 16 + lm) * 64 + po);
#pragma unroll
            for (int im = 0; im < 4; ++im)
#pragma unroll
                for (int in = 0; in < 4; ++in)
                    acc[im][in] = mfma16(wf[in], xf[im], acc[im][in]);
        }
    }
#pragma unroll
    for (int im = 0; im < 4; ++im) {
        int m = i0 + wrow + im * 16 + lm;
#pragma unroll
        for (int in = 0; in < 4; ++in) {
            int nn = j0 + wcol + in * 16 + (lq << 2);
            ushort4 b4 = *(const ushort4*)(Bias + nn);
            ushort4 x4 = *(const ushort4*)(X + (size_t)m * DMODEL + nn);
            float c0 = acc[im][in][0] + bf2f(b4.x) + bf2f(x4.x);
            float c1 = acc[im][in][1] + bf2f(b4.y) + bf2f(x4.y);
            float c2 = acc[im][in][2] + bf2f(b4.z) + bf2f(x4.z);
            float c3 = acc[im][in][3] + bf2f(b4.w) + bf2f(x4.w);
            if (isf32) {
                *(float4*)((float*)Out + (size_t)m * DMODEL + nn) = make_float4(c0, c1, c2, c3);
            } else {
                ushort4 o;
                o.x = f2bf(c0); o.y = f2bf(c1); o.z = f2bf(c2); o.w = f2bf(c3);
                *(ushort4*)((u16*)Out + (size_t)m * DMODEL + nn) = o;
            }
        }
    }
}

extern "C" void kernel_launch(void* const* d_in, const int* in_sizes, int n_in,
                              void* d_out, int out_size, void* d_ws, size_t ws_size,
                              hipStream_t stream)
{
    (void)in_sizes; (void)n_in; (void)out_size; (void)ws_size;
    char* ws = (char*)d_ws;
    u16*   Xc    = (u16*)(ws + 0);            // 33,554,432
    u16*   WqkvT = (u16*)(ws + 33554432);     //  1,572,864
    u16*   WoutT = (u16*)(ws + 35127296);     //    524,288
    u16*   Boutc = (u16*)(ws + 35651584);     //      1,024
    u16*   CWc   = (u16*)(ws + 35652608);     //      1,024
    u16*   Qb    = (u16*)(ws + 35653632);     // 33,554,432  [bh][n][d]
    u16*   Kb    = (u16*)(ws + 69208064);     // 33,554,432  [bh][n][d]; dead after attn3v
    u16*   RT    = (u16*)(ws + 69208064);     // overlays Kb post-attn3v
    u16*   VTb   = (u16*)(ws + 102762496);    // 33,554,432  [bh][d][n]
    float* QL    = (float*)(ws + 136316928);  //  2,097,152
    float* KL    = (float*)(ws + 138414080);  //  2,097,152
    u16*   QLb   = (u16*)(ws + 140511232);    //  1,048,576
    u16*   KLb   = (u16*)(ws + 141559808);    //  1,048,576
    u16*   W3VT  = (u16*)(ws + 142608384);    //  1,048,576
    u16*   WMT   = (u16*)(ws + 143656960);    //  1,048,576
    u16*   A2b   = (u16*)(ws + 144705536);    //  4,194,304
    u16*   zA    = (u16*)(ws + 148899840);    //  4,194,304  z rows (ping)
    u16*   zAT   = (u16*)(ws + 153094144);    //  4,194,304  z0T at init; then u rows (pong)
    float* A2    = (float*)(ws + 157288448);  // overlay region
    u16*   PO    = (u16*)(ws + 157288448);
    float* ML    = (float*)(ws + 174065664);
    u16*   zB    = (u16*)(ws + 165677056);    //  z rows (pong)
    u16*   zBT   = (u16*)(ws + 169871360);    //  uT (pong)
    u16*   xz    = (u16*)(ws + 174065664);    //  u rows (ping; overlays ML, dead after combine)
    u16*   xzT   = (u16*)(ws + 178259968);    //  uT (ping)
    u16*   t2T   = (u16*)(ws + 182454272);
    u16*   t3T   = (u16*)(ws + 186648576);
    u16*   Yb    = (u16*)(ws + 157288448);
    unsigned* SCAL = (unsigned*)(ws + 190842880);

    detect_kernel<<<1, 256, 0, stream>>>((const u16*)d_in[0], SCAL);
    convert4_kernel<<<16384, 256, 0, stream>>>(d_in[0], Xc, 4194304, SCAL + 2);
    wtrans_kernel<<<3072, 256, 0, stream>>>(d_in[1], WqkvT, 512, 1536, SCAL + 2);
    wtrans_kernel<<<1024, 256, 0, stream>>>(d_in[2], WoutT, 512, 512, SCAL + 2);
    small_convert_kernel<<<1, 256, 0, stream>>>(d_in[3], Boutc, d_in[4], CWc, SCAL + 2);

    qkv_mfma_kernel<<<dim3(256, 12), 256, 0, stream>>>(Xc, WqkvT, Qb, Kb, VTb);
    pool_kernel<<<dim3(256, BH), 64, 0, stream>>>(Qb, Kb, QL, KL, QLb, KLb);
    attn2_kernel<<<dim3(256, BH), 256, 0, stream>>>(QL, KL, A2);
    absmax_kernel<<<32, 256, 0, stream>>>(A2, SCAL);
    z0_kernel<<<8192, 256, 0, stream>>>(A2, SCAL, zA, zAT, A2b);

    // flash attn3@v (fetch-once), combine, conv into Kb slot
    attn3v_mfma_kernel<<<dim3(16, BH), 256, 0, stream>>>(QLb, Kb, VTb, PO, ML);
    combine_kernel<<<dim3(256, BH), 64, 0, stream>>>(PO, ML, W3VT);
    conv_kernel<<<dim3(4, 2048), 256, 0, stream>>>(VTb, CWc, RT);

    // pinv chain with carried u = x@z: 20 launches (1 init + 6x3 + 1 final).
    //   init : u0 = x @ z0                       (rows + T)
    //   G1   : t2 = u@u - 7u + 15I               (T only)
    //   G2   : t3 = 13I - u@t2                   (T only)
    //   G3   : pair{ z' = 0.25 z@t3 ; u' = 0.25 u@t3 (rows+T) }
    u16 *z = zA, *zn = zB;
    u16 *u = xz, *uT = xzT, *un = zAT, *unT = zBT;
    bgemm_mfma_kernel<<<dim3(4, 4, 32), 256, 0, stream>>>(
        A2b, zAT, u, uT, A2b, 256, 65536, 65536, 65536, 0.f, 0.f, 1.f, 1, 1);
    for (int it = 0; it < 6; ++it) {
        bgemm_mfma_kernel<<<dim3(4, 4, 32), 256, 0, stream>>>(
            u, uT, u, t2T, u, 256, 65536, 65536, 65536, 15.f, -7.f, 1.f, 0, 1);
        bgemm_mfma_kernel<<<dim3(4, 4, 32), 256, 0, stream>>>(
            u, t2T, u, t3T, u, 256, 65536, 65536, 65536, 13.f, 0.f, -1.f, 0, 1);
        bgemm_pair_kernel<<<dim3(4, 4, 64), 256, 0, stream>>>(
            z, u, t3T, zn, un, unT);
        u16* tp;
        tp = z;  z = zn;  zn = tp;
        tp = u;  u = un;  un = tp;
        tp = uT; uT = unT; unT = tp;
    }
    bgemm_mfma_kernel<<<dim3(4, 1, 32), 256, 0, stream>>>(
        z, W3VT, WMT, WMT, A2b, 64, 16384, 16384, 16384, 0.f, 0.f, 1.f, 0, 1);

    outheads_mfma_kernel<<<dim3(128, BH), 256, 0, stream>>>(Qb, KLb, WMT, RT, Yb);
    final_mfma_kernel<<<dim3(256, 4), 256, 0, stream>>>(Yb, WoutT, Boutc, Xc, d_out, SCAL + 2);
}